// Round 7
// baseline (768.878 us; speedup 1.0000x reference)
//
#include <hip/hip_runtime.h>
#include <hip/hip_bf16.h>

#define GG 128   // graphs total (2 branches x 64)
#define LLN 128
#define DDIM 300
#define NH 4

typedef float4 f4;
typedef __attribute__((ext_vector_type(4))) float f32x4;
typedef __attribute__((ext_vector_type(8))) short s16x8;

__device__ __forceinline__ float wsum(float v) {
  #pragma unroll
  for (int o = 32; o > 0; o >>= 1) v += __shfl_xor(v, o, 64);
  return v;
}
__device__ __forceinline__ float wmax(float v) {
  #pragma unroll
  for (int o = 32; o > 0; o >>= 1) v = fmaxf(v, __shfl_xor(v, o, 64));
  return v;
}
__device__ __forceinline__ f4 add4(f4 a, f4 b) {
  return make_float4(a.x+b.x, a.y+b.y, a.z+b.z, a.w+b.w);
}
__device__ __forceinline__ f4 scale4(f4 a, float s) {
  return make_float4(a.x*s, a.y*s, a.z*s, a.w*s);
}
#define FMA4(acc, v, s) { (acc).x += (s)*(v).x; (acc).y += (s)*(v).y; (acc).z += (s)*(v).z; (acc).w += (s)*(v).w; }

__device__ __forceinline__ unsigned short f2bf(float x) {
  unsigned int u = __float_as_uint(x);
  return (unsigned short)((u + 0x7fffu + ((u >> 16) & 1u)) >> 16);
}
__device__ __forceinline__ float bf2f(unsigned short b) {
  return __uint_as_float(((unsigned int)b) << 16);
}
__device__ __forceinline__ int swzq(int row, int q) { return q ^ ((row >> 1) & 3); }
__device__ __forceinline__ float sigm(float x) { return 1.f / (1.f + __expf(-x)); }

__device__ __forceinline__ f32x4 mfma3(s16x8 ah, s16x8 al, s16x8 bh, s16x8 bl, f32x4 c) {
  c = __builtin_amdgcn_mfma_f32_16x16x32_bf16(ah, bh, c, 0, 0, 0);
  c = __builtin_amdgcn_mfma_f32_16x16x32_bf16(ah, bl, c, 0, 0, 0);
  c = __builtin_amdgcn_mfma_f32_16x16x32_bf16(al, bh, c, 0, 0, 0);
  return c;
}
__device__ __forceinline__ f32x4 mfma4(s16x8 ah, s16x8 al, s16x8 bh, s16x8 bl, f32x4 c) {
  c = __builtin_amdgcn_mfma_f32_16x16x32_bf16(ah, bh, c, 0, 0, 0);
  c = __builtin_amdgcn_mfma_f32_16x16x32_bf16(ah, bl, c, 0, 0, 0);
  c = __builtin_amdgcn_mfma_f32_16x16x32_bf16(al, bh, c, 0, 0, 0);
  c = __builtin_amdgcn_mfma_f32_16x16x32_bf16(al, bl, c, 0, 0, 0);
  return c;
}

__device__ __forceinline__ void gld16(const void* g, void* l) {
  __builtin_amdgcn_global_load_lds(
      (const __attribute__((address_space(1))) void*)g,
      (__attribute__((address_space(3))) void*)l, 16, 0, 0);
}

__device__ __forceinline__ void xcd_decode8(int id, int& g, int& it) {
  int x = id & 7, t = id >> 3;
  it = t & 7; g = x + 8 * (t >> 3);
}

// ---------------- embedding gather
__global__ __launch_bounds__(256) void gather_kernel(
    const float* __restrict__ emb, const int* __restrict__ s1,
    const int* __restrict__ s2, float* __restrict__ h) {
  int gl = blockIdx.x;
  int g = gl >> 7, l = gl & 127;
  const int* s = (g >= 64) ? s2 : s1;
  int tok = s[l * 64 + (g & 63)];
  const float* src = emb + (size_t)tok * DDIM;
  float* dst = h + (size_t)gl * DDIM;
  for (int d = threadIdx.x; d < DDIM; d += 256) dst[d] = src[d];
}

// ---------------- hsplit: h -> split bf16 hi/lo tile images in LDS byte order
__global__ __launch_bounds__(256) void hsplit_kernel(
    const float* __restrict__ h,
    unsigned short* __restrict__ hh, unsigned short* __restrict__ hl) {
  int b = blockIdx.x;                    // g*10 + kc
  int g = b / 10, kc = b - g * 10;
  int tid = threadIdx.x;
  int m = tid >> 1, half = tid & 1;
  const float* hp = h + ((size_t)g * LLN + m) * DDIM;
  int kb = kc * 32 + half * 16;
  float v[16];
  if (kb + 15 < 300) {
    f4 x0 = *(const f4*)(hp + kb);
    f4 x1 = *(const f4*)(hp + kb + 4);
    f4 x2 = *(const f4*)(hp + kb + 8);
    f4 x3 = *(const f4*)(hp + kb + 12);
    v[0]=x0.x; v[1]=x0.y; v[2]=x0.z; v[3]=x0.w;
    v[4]=x1.x; v[5]=x1.y; v[6]=x1.z; v[7]=x1.w;
    v[8]=x2.x; v[9]=x2.y; v[10]=x2.z; v[11]=x2.w;
    v[12]=x3.x; v[13]=x3.y; v[14]=x3.z; v[15]=x3.w;
  } else {
    #pragma unroll
    for (int e = 0; e < 16; ++e) { int k = kb + e; v[e] = (k < 300) ? hp[k] : 0.f; }
  }
  unsigned short* oh = hh + (size_t)b * 4096;
  unsigned short* ol = hl + (size_t)b * 4096;
  #pragma unroll
  for (int g4 = 0; g4 < 4; ++g4) {
    int klocal = half * 16 + g4 * 4;
    int q = klocal >> 3, wb = klocal & 7;
    int idx = m * 32 + swzq(m, q) * 8 + wb;
    ushort4 hv, lv;
    hv.x = f2bf(v[g4*4+0]); lv.x = f2bf(v[g4*4+0] - bf2f(hv.x));
    hv.y = f2bf(v[g4*4+1]); lv.y = f2bf(v[g4*4+1] - bf2f(hv.y));
    hv.z = f2bf(v[g4*4+2]); lv.z = f2bf(v[g4*4+2] - bf2f(hv.z));
    hv.w = f2bf(v[g4*4+3]); lv.w = f2bf(v[g4*4+3] - bf2f(hv.w));
    *(ushort4*)&oh[idx] = hv;
    *(ushort4*)&ol[idx] = lv;
  }
}

// ---------------- adjmm: both adjacencies via 4-term split-bf16 MFMA (V.V^T, symmetric)
__global__ __launch_bounds__(256) void adjmm_kernel(
    const float* __restrict__ h, const float* __restrict__ simw1,
    const float* __restrict__ simw2, unsigned char* __restrict__ Agat,
    unsigned char* __restrict__ Asag) {
  __shared__ __align__(16) unsigned short Vh[128 * 32], Vl[128 * 32];
  __shared__ float wv[320];
  int x = blockIdx.x & 7, t = blockIdx.x >> 3;
  int u = t & 1, g = x + 8 * (t >> 1);
  const float* w = u ? simw1 : simw2;
  unsigned char* A = (u ? Asag : Agat) + (size_t)g * LLN * LLN;
  int tid = threadIdx.x, wid = tid >> 6, lane = tid & 63;
  int lq = lane >> 4, lr = lane & 15;
  for (int k = tid; k < 320; k += 256) wv[k] = (k < 300) ? w[k] : 0.f;
  f32x4 acc[2][8];
  #pragma unroll
  for (int fr = 0; fr < 2; ++fr)
    #pragma unroll
    for (int nf = 0; nf < 8; ++nf) acc[fr][nf] = (f32x4){0.f, 0.f, 0.f, 0.f};
  const float* hg = h + (size_t)g * LLN * DDIM;

  for (int kc = 0; kc < 10; ++kc) {
    __syncthreads();
    {
      int m = tid >> 1, halfk = tid & 1;
      int kb = kc * 32 + halfk * 16;
      const float* hp = hg + (size_t)m * DDIM;
      float v[16];
      if (kb + 15 < 300) {
        f4 x0 = *(const f4*)(hp + kb);
        f4 x1 = *(const f4*)(hp + kb + 4);
        f4 x2 = *(const f4*)(hp + kb + 8);
        f4 x3 = *(const f4*)(hp + kb + 12);
        v[0]=x0.x; v[1]=x0.y; v[2]=x0.z; v[3]=x0.w;
        v[4]=x1.x; v[5]=x1.y; v[6]=x1.z; v[7]=x1.w;
        v[8]=x2.x; v[9]=x2.y; v[10]=x2.z; v[11]=x2.w;
        v[12]=x3.x; v[13]=x3.y; v[14]=x3.z; v[15]=x3.w;
        #pragma unroll
        for (int e = 0; e < 16; ++e) v[e] = fmaxf(v[e] * wv[kb + e], 0.f);
      } else {
        #pragma unroll
        for (int e = 0; e < 16; ++e) {
          int k = kb + e;
          v[e] = (k < 300) ? fmaxf(hp[k] * wv[k], 0.f) : 0.f;
        }
      }
      #pragma unroll
      for (int g4 = 0; g4 < 4; ++g4) {
        int klocal = halfk * 16 + g4 * 4;
        int q = klocal >> 3, wb = klocal & 7;
        int idx = m * 32 + swzq(m, q) * 8 + wb;
        ushort4 hv, lv;
        hv.x = f2bf(v[g4*4+0]); lv.x = f2bf(v[g4*4+0] - bf2f(hv.x));
        hv.y = f2bf(v[g4*4+1]); lv.y = f2bf(v[g4*4+1] - bf2f(hv.y));
        hv.z = f2bf(v[g4*4+2]); lv.z = f2bf(v[g4*4+2] - bf2f(hv.z));
        hv.w = f2bf(v[g4*4+3]); lv.w = f2bf(v[g4*4+3] - bf2f(hv.w));
        *(ushort4*)&Vh[idx] = hv;
        *(ushort4*)&Vl[idx] = lv;
      }
    }
    __syncthreads();
    #pragma unroll
    for (int fr = 0; fr < 2; ++fr) {
      int ra = wid * 32 + fr * 16 + lr;
      int ai = ra * 32 + swzq(ra, lq) * 8;
      s16x8 ah = *(const s16x8*)&Vh[ai];
      s16x8 al = *(const s16x8*)&Vl[ai];
      #pragma unroll
      for (int nf = 0; nf < 8; ++nf) {
        int rb = nf * 16 + lr;
        int bi = rb * 32 + swzq(rb, lq) * 8;
        s16x8 bh = *(const s16x8*)&Vh[bi];
        s16x8 bl = *(const s16x8*)&Vl[bi];
        acc[fr][nf] = mfma4(ah, al, bh, bl, acc[fr][nf]);
      }
    }
  }
  __syncthreads();
  unsigned char* Au8 = (unsigned char*)Vh;   // 16 KB reuse (Vh+Vl)
  #pragma unroll
  for (int fr = 0; fr < 2; ++fr) {
    #pragma unroll
    for (int nf = 0; nf < 8; ++nf) {
      int j = nf * 16 + lr;
      #pragma unroll
      for (int t2 = 0; t2 < 4; ++t2) {
        int i = wid * 32 + fr * 16 + 4 * lq + t2;
        Au8[i * 128 + j] = (acc[fr][nf][t2] >= 0.1f || i == j) ? 1 : 0;
      }
    }
  }
  __syncthreads();
  for (int c = tid; c < 1024; c += 256) {
    int r = c >> 3, q = c & 7;
    uint4 val = *(const uint4*)&Au8[r * 128 + q * 16];
    *(uint4*)&A[(size_t)r * 128 + q * 16] = val;
  }
}

// ---------------- prepW: gatW -> split bf16 tile images; sageW -> row-major split
__global__ __launch_bounds__(256) void prepw_kernel(
    const float* __restrict__ gatW, const float* __restrict__ sageW,
    unsigned short* __restrict__ gWTtH, unsigned short* __restrict__ gWTtL,
    unsigned short* __restrict__ sWTh, unsigned short* __restrict__ sWTl) {
  int idx = blockIdx.x * 256 + threadIdx.x;
  if (idx < 1280 * 320) {
    int n = idx / 320, katt = idx - (idx / 320) * 320;
    int nt = n >> 7, nl = n & 127;
    int kc = katt >> 5, klocal = katt & 31;
    int q = klocal >> 3, wb = klocal & 7;
    size_t pos = ((size_t)(nt * 10 + kc) * 128 + nl) * 32 + swzq(nl, q) * 8 + wb;
    float v = (n < 1200 && katt < 300) ? gatW[(size_t)katt * 1200 + n] : 0.f;
    unsigned short hv = f2bf(v);
    gWTtH[pos] = hv;
    gWTtL[pos] = f2bf(v - bf2f(hv));
  } else if (idx < 1280 * 320 + 320 * 320) {
    int i2 = idx - 1280 * 320;
    int n = i2 / 320, k = i2 % 320;
    float v = (n < 300 && k < 300) ? sageW[(size_t)k * 300 + n] : 0.f;
    unsigned short hv = f2bf(v);
    sWTh[i2] = hv;
    sWTl[i2] = f2bf(v - bf2f(hv));
  }
}

// ---------------- zmm: z = h @ gatW via split-bf16 MFMA; gld16 staging from tile images.
// el/er partials per 64-col band -> unique slot (deterministic, no atomics).
// part layout: [g][head][slot(6)][side(2)][j(128)] floats.
__global__ __launch_bounds__(256) void zmm_mfma(
    const unsigned short* __restrict__ hsplH, const unsigned short* __restrict__ hsplL,
    const unsigned short* __restrict__ gWTtH, const unsigned short* __restrict__ gWTtL,
    const float* __restrict__ attn_l, const float* __restrict__ attn_r,
    unsigned short* __restrict__ zTh, unsigned short* __restrict__ zTl,
    float* __restrict__ part) {
  __shared__ __align__(16) unsigned short smem[128 * 136];   // 34816 B
  unsigned short* Ah = smem;
  unsigned short* Al = smem + 4096;
  unsigned short* Bh = smem + 8192;
  unsigned short* Bl = smem + 12288;
  int x = blockIdx.x & 7, tb = blockIdx.x >> 3;
  int gi = tb / 10, nt = tb - gi * 10;
  int g = x + 8 * gi;
  int n0 = nt * 128;
  int tid = threadIdx.x, w = tid >> 6, lane = tid & 63;
  int lq = lane >> 4, lr = lane & 15, wr = w >> 1, wc = w & 1;
  f32x4 acc[4][4];
  #pragma unroll
  for (int a = 0; a < 4; ++a)
    #pragma unroll
    for (int b = 0; b < 4; ++b) acc[a][b] = (f32x4){0.f, 0.f, 0.f, 0.f};

  for (int kc = 0; kc < 10; ++kc) {
    {
      const unsigned short* ah_g = hsplH + (size_t)(g * 10 + kc) * 4096;
      const unsigned short* al_g = hsplL + (size_t)(g * 10 + kc) * 4096;
      const unsigned short* bh_g = gWTtH + (size_t)(nt * 10 + kc) * 4096;
      const unsigned short* bl_g = gWTtL + (size_t)(nt * 10 + kc) * 4096;
      int o = tid * 8;
      gld16(ah_g + o, Ah + o); gld16(ah_g + o + 2048, Ah + o + 2048);
      gld16(al_g + o, Al + o); gld16(al_g + o + 2048, Al + o + 2048);
      gld16(bh_g + o, Bh + o); gld16(bh_g + o + 2048, Bh + o + 2048);
      gld16(bl_g + o, Bl + o); gld16(bl_g + o + 2048, Bl + o + 2048);
    }
    __syncthreads();   // drains vmcnt (global_load_lds) before reads
    s16x8 ah[4], alo[4];
    #pragma unroll
    for (int mf = 0; mf < 4; ++mf) {
      int row = wr * 64 + mf * 16 + lr;
      int ai = row * 32 + swzq(row, lq) * 8;
      ah[mf] = *(const s16x8*)&Ah[ai];
      alo[mf] = *(const s16x8*)&Al[ai];
    }
    #pragma unroll
    for (int nf = 0; nf < 4; ++nf) {
      int rn = wc * 64 + nf * 16 + lr;
      int bi = rn * 32 + swzq(rn, lq) * 8;
      s16x8 bhv = *(const s16x8*)&Bh[bi];
      s16x8 blv = *(const s16x8*)&Bl[bi];
      #pragma unroll
      for (int mf = 0; mf < 4; ++mf)
        acc[mf][nf] = mfma3(ah[mf], alo[mf], bhv, blv, acc[mf][nf]);
    }
    __syncthreads();
  }

  // ---- el/er partial dots -> unique (g, head, slot) slots; no atomics ----
  {
    int cbase = n0 + wc * 64;
    if (cbase < 1200) {
      int b = cbase >> 6;                 // band 0..18
      int h_base = cbase / 300;
      int fb = (h_base == 0) ? 0 : (h_base == 1) ? 5 : (h_base == 2) ? 10 : 15;
      int slot = b - fb + 1;              // 1..5
      int h_last = (cbase + 63 < 1200 ? cbase + 63 : 1199) / 300;
      bool has_alt = (h_last != h_base);
      float aLv[4], aRv[4]; int alt[4];
      #pragma unroll
      for (int nf = 0; nf < 4; ++nf) {
        int cg = cbase + nf * 16 + lr;
        bool ok = cg < 1200;
        aLv[nf] = ok ? attn_l[cg] : 0.f;
        aRv[nf] = ok ? attn_r[cg] : 0.f;
        alt[nf] = (ok && (cg / 300) != h_base) ? 1 : 0;
      }
      float* p0 = part + (((size_t)(g * 4 + h_base) * 6 + slot) * 2) * 128;
      float* p1 = part + (((size_t)(g * 4 + h_base + 1) * 6 + 0) * 2) * 128;
      #pragma unroll
      for (int mf = 0; mf < 4; ++mf) {
        #pragma unroll
        for (int t2 = 0; t2 < 4; ++t2) {
          float s0l = 0.f, s0r = 0.f, s1l = 0.f, s1r = 0.f;
          #pragma unroll
          for (int nf = 0; nf < 4; ++nf) {
            float v = acc[mf][nf][t2];
            float cl = v * aLv[nf], cr = v * aRv[nf];
            s0l += alt[nf] ? 0.f : cl; s1l += alt[nf] ? cl : 0.f;
            s0r += alt[nf] ? 0.f : cr; s1r += alt[nf] ? cr : 0.f;
          }
          #pragma unroll
          for (int mm = 1; mm < 16; mm <<= 1) {
            s0l += __shfl_xor(s0l, mm, 64);
            s0r += __shfl_xor(s0r, mm, 64);
          }
          if (has_alt) {
            #pragma unroll
            for (int mm = 1; mm < 16; mm <<= 1) {
              s1l += __shfl_xor(s1l, mm, 64);
              s1r += __shfl_xor(s1r, mm, 64);
            }
          }
          if (lr == 0) {
            int j = wr * 64 + mf * 16 + 4 * lq + t2;
            p0[j] = s0l; p0[128 + j] = s0r;
            if (has_alt) { p1[j] = s1l; p1[128 + j] = s1r; }
          }
        }
      }
    }
  }

  // ---- transposed coalesced zT store: pass 0 = hi, pass 1 = lo ----
  for (int pass = 0; pass < 2; ++pass) {
    __syncthreads();
    #pragma unroll
    for (int mf = 0; mf < 4; ++mf) {
      #pragma unroll
      for (int nf = 0; nf < 4; ++nf) {
        int cl = wc * 64 + nf * 16 + lr;
        int j0 = wr * 64 + mf * 16 + 4 * lq;
        f32x4 a = acc[mf][nf];
        ushort4 pv;
        if (pass == 0) {
          pv.x = f2bf(a[0]); pv.y = f2bf(a[1]); pv.z = f2bf(a[2]); pv.w = f2bf(a[3]);
        } else {
          unsigned short hx;
          hx = f2bf(a[0]); pv.x = f2bf(a[0] - bf2f(hx));
          hx = f2bf(a[1]); pv.y = f2bf(a[1] - bf2f(hx));
          hx = f2bf(a[2]); pv.z = f2bf(a[2] - bf2f(hx));
          hx = f2bf(a[3]); pv.w = f2bf(a[3] - bf2f(hx));
        }
        *(ushort4*)&smem[cl * 136 + j0] = pv;
      }
    }
    __syncthreads();
    unsigned short* dst = pass ? zTl : zTh;
    #pragma unroll
    for (int p = 0; p < 8; ++p) {
      int c = tid + p * 256;
      int r = c >> 4, q = c & 15;
      int cg = n0 + r;
      if (cg < 1200) {
        int head = cg / 300, d = cg - head * 300;
        uint4 val = *(const uint4*)&smem[r * 136 + q * 8];
        *(uint4*)(dst + ((size_t)(g * 4 + head) * 300 + d) * 128 + q * 8) = val;
      }
    }
  }
}

// ---------------- alphaP: reduce el/er partials (fixed order), then softmax max & 1/sum; dinv
__global__ __launch_bounds__(256) void alphap_kernel(
    const unsigned char* __restrict__ Agat, const unsigned char* __restrict__ Asag,
    const float* __restrict__ part,
    float* __restrict__ el, float* __restrict__ er,
    float* __restrict__ mx, float* __restrict__ sinv, float* __restrict__ dinv) {
  int g = blockIdx.x, u = blockIdx.y;
  int tid = threadIdx.x, ww = tid >> 6, lane = tid & 63;
  if (u < 4) {
    __shared__ float elsm[128], ersm[128];
    {
      int j = tid & 127, side = tid >> 7;
      int s0 = (u == 0) ? 1 : 0;
      int s1e = (u == 3) ? 4 : 5;
      float v = 0.f;
      for (int s = s0; s <= s1e; ++s)
        v += part[(((size_t)(g * 4 + u) * 6 + s) * 2 + side) * 128 + j];
      if (side == 0) { elsm[j] = v; el[(size_t)(g * 4 + u) * 128 + j] = v; }
      else           { ersm[j] = v; er[(size_t)(g * 4 + u) * 128 + j] = v; }
    }
    __syncthreads();
    float el0 = elsm[lane], el1 = elsm[64 + lane];
    for (int i = ww; i < 128; i += 4) {
      const unsigned char* row = Agat + ((size_t)g * 128 + i) * 128;
      int m0 = row[lane], m1 = row[64 + lane];
      float eri = ersm[i];
      float e0 = eri + el0; e0 = e0 >= 0.f ? e0 : 0.2f * e0;
      float e1 = eri + el1; e1 = e1 >= 0.f ? e1 : 0.2f * e1;
      float x0 = m0 ? e0 : -3.0e38f;
      float x1 = m1 ? e1 : -3.0e38f;
      float m_ = wmax(fmaxf(x0, x1));
      float p0 = m0 ? __expf(e0 - m_) : 0.f;
      float p1 = m1 ? __expf(e1 - m_) : 0.f;
      float s = wsum(p0 + p1);
      if (lane == 0) {
        mx[(size_t)(g * 4 + u) * 128 + i] = m_;
        sinv[(size_t)(g * 4 + u) * 128 + i] = 1.f / s;
      }
    }
  } else {
    for (int i = ww; i < 128; i += 4) {
      const unsigned char* row = Asag + ((size_t)g * 128 + i) * 128;
      float d = (float)(row[lane] + row[64 + lane]);
      d = wsum(d);
      if (lane == 0) dinv[(size_t)g * 128 + i] = 1.f / (d + 1.f);
    }
  }
}

// ---------------- gat_fuse: 4 GAT heads via MFMA + head weights + residual (XCD-swizzled)
__global__ __launch_bounds__(256) void gat_fuse(
    const float* __restrict__ h, const unsigned char* __restrict__ Agat,
    const unsigned short* __restrict__ zTh, const unsigned short* __restrict__ zTl,
    const float* __restrict__ el, const float* __restrict__ er,
    const float* __restrict__ mx, const float* __restrict__ sinv,
    const float* __restrict__ gat_b, const float* __restrict__ headW,
    const float* __restrict__ head_b, float* __restrict__ out) {
  __shared__ __align__(16) unsigned short Bh[320 * 32], Bl[320 * 32];
  __shared__ __align__(16) unsigned short Ah[32 * 32], Al[32 * 32];
  __shared__ float hwred[2][32];
  __shared__ float wgts[32];
  int xb = blockIdx.x & 7, tb = blockIdx.x >> 3;
  int it = tb & 3, g = xb + 8 * (tb >> 2);
  int i0 = it * 32;
  int tid = threadIdx.x, w = tid >> 6, lane = tid & 63;
  int lq = lane >> 4, lr = lane & 15, wi = w & 1, wn = w >> 1;
  float hb = head_b[0];
  float outacc[10][4];
  #pragma unroll
  for (int nf = 0; nf < 10; ++nf)
    #pragma unroll
    for (int t = 0; t < 4; ++t) outacc[nf][t] = 0.f;

  for (int s = 0; s < 4; ++s) {
    f32x4 acc[10];
    #pragma unroll
    for (int nf = 0; nf < 10; ++nf) acc[nf] = (f32x4){0.f, 0.f, 0.f, 0.f};
    const float* els = el + (size_t)(g * 4 + s) * 128;
    const float* ers = er + (size_t)(g * 4 + s) * 128;
    const float* mxs = mx + (size_t)(g * 4 + s) * 128;
    const unsigned short* zsh = zTh + (size_t)(g * 4 + s) * 300 * 128;
    const unsigned short* zsl = zTl + (size_t)(g * 4 + s) * 300 * 128;

    for (int kc = 0; kc < 4; ++kc) {
      int j0 = kc * 32;
      {
        int m = tid >> 3, j4 = (tid & 7) * 4;
        int i = i0 + m;
        float eri = ers[i], mxi = mxs[i];
        const unsigned char* mrow = Agat + ((size_t)g * 128 + i) * 128 + j0 + j4;
        uchar4 msk = *(const uchar4*)mrow;
        f4 elv = *(const f4*)(els + j0 + j4);
        float p[4];
        {
          float e = eri + elv.x; e = e >= 0.f ? e : 0.2f * e; p[0] = msk.x ? __expf(e - mxi) : 0.f;
          e = eri + elv.y; e = e >= 0.f ? e : 0.2f * e; p[1] = msk.y ? __expf(e - mxi) : 0.f;
          e = eri + elv.z; e = e >= 0.f ? e : 0.2f * e; p[2] = msk.z ? __expf(e - mxi) : 0.f;
          e = eri + elv.w; e = e >= 0.f ? e : 0.2f * e; p[3] = msk.w ? __expf(e - mxi) : 0.f;
        }
        int q = j4 >> 3, wb = j4 & 7;
        int idx = m * 32 + swzq(m, q) * 8 + wb;
        ushort4 hv, lv;
        hv.x = f2bf(p[0]); lv.x = f2bf(p[0] - bf2f(hv.x));
        hv.y = f2bf(p[1]); lv.y = f2bf(p[1] - bf2f(hv.y));
        hv.z = f2bf(p[2]); lv.z = f2bf(p[2] - bf2f(hv.z));
        hv.w = f2bf(p[3]); lv.w = f2bf(p[3] - bf2f(hv.w));
        *(ushort4*)&Ah[idx] = hv;
        *(ushort4*)&Al[idx] = lv;
      }
      {
        #pragma unroll
        for (int rep = 0; rep < 2; ++rep) {
          int n = rep == 0 ? tid : 256 + tid;
          if (rep == 1 && tid >= 64) break;
          if (n < 300) {
            const unsigned short* src_h = zsh + (size_t)n * 128 + j0;
            const unsigned short* src_l = zsl + (size_t)n * 128 + j0;
            #pragma unroll
            for (int q = 0; q < 4; ++q) {
              int idx = n * 32 + swzq(n, q) * 8;
              *(s16x8*)&Bh[idx] = *(const s16x8*)(src_h + q * 8);
              *(s16x8*)&Bl[idx] = *(const s16x8*)(src_l + q * 8);
            }
          } else {
            s16x8 z8 = (s16x8){0,0,0,0,0,0,0,0};
            #pragma unroll
            for (int q = 0; q < 4; ++q) {
              int idx = n * 32 + swzq(n, q) * 8;
              *(s16x8*)&Bh[idx] = z8;
              *(s16x8*)&Bl[idx] = z8;
            }
          }
        }
      }
      __syncthreads();
      int rowa = wi * 16 + lr;
      int ai = rowa * 32 + swzq(rowa, lq) * 8;
      s16x8 ah = *(const s16x8*)&Ah[ai];
      s16x8 alv = *(const s16x8*)&Al[ai];
      #pragma unroll
      for (int nf = 0; nf < 10; ++nf) {
        int rn = wn * 160 + nf * 16 + lr;
        int bi = rn * 32 + swzq(rn, lq) * 8;
        s16x8 bhv = *(const s16x8*)&Bh[bi];
        s16x8 blv = *(const s16x8*)&Bl[bi];
        acc[nf] = mfma3(ah, alv, bhv, blv, acc[nf]);
      }
      __syncthreads();
    }
    f4 sv4 = *(const f4*)(sinv + (size_t)(g * 4 + s) * 128 + i0 + wi * 16 + 4 * lq);
    float svf[4] = {sv4.x, sv4.y, sv4.z, sv4.w};
    float pt[4] = {0.f, 0.f, 0.f, 0.f};
    #pragma unroll
    for (int nf = 0; nf < 10; ++nf) {
      int c = wn * 160 + nf * 16 + lr;
      bool val = c < 300;
      float gb = val ? gat_b[s * 300 + c] : 0.f;
      float hwv = val ? headW[c] : 0.f;
      #pragma unroll
      for (int t = 0; t < 4; ++t) {
        float gvv = acc[nf][t] * svf[t] + gb;
        acc[nf][t] = gvv;
        pt[t] += gvv * hwv;
      }
    }
    #pragma unroll
    for (int t = 0; t < 4; ++t) {
      #pragma unroll
      for (int mm = 1; mm < 16; mm <<= 1) pt[t] += __shfl_xor(pt[t], mm, 64);
    }
    if (lr == 0) {
      #pragma unroll
      for (int t = 0; t < 4; ++t) hwred[wn][wi * 16 + 4 * lq + t] = pt[t];
    }
    __syncthreads();
    if (tid < 32) wgts[tid] = sigm(hwred[0][tid] + hwred[1][tid] + hb);
    __syncthreads();
    #pragma unroll
    for (int nf = 0; nf < 10; ++nf) {
      #pragma unroll
      for (int t = 0; t < 4; ++t) {
        int r = wi * 16 + 4 * lq + t;
        outacc[nf][t] += wgts[r] * acc[nf][t];
      }
    }
    __syncthreads();
  }
  #pragma unroll
  for (int nf = 0; nf < 10; ++nf) {
    int c = wn * 160 + nf * 16 + lr;
    if (c < 300) {
      #pragma unroll
      for (int t = 0; t < 4; ++t) {
        int r = wi * 16 + 4 * lq + t;
        size_t o = ((size_t)(g * 128 + i0 + r)) * 300 + c;
        out[o] = h[o] + outacc[nf][t];
      }
    }
  }
}

// ---------------- neigh (fp32): n = (Asag@h + h)*dinv -> split bf16 (XCD-swizzled)
__global__ __launch_bounds__(256) void neigh_kernel(
    const float* __restrict__ h, const unsigned char* __restrict__ Asag,
    const float* __restrict__ dinv,
    unsigned short* __restrict__ nh, unsigned short* __restrict__ nl) {
  __shared__ float As[16][128];
  int g, it; xcd_decode8(blockIdx.x, g, it);
  int i0 = it * 16;
  int tid = threadIdx.x, ii = tid >> 6, lane = tid & 63;
  for (int idx = tid; idx < 16 * 128; idx += 256)
    As[idx >> 7][idx & 127] = (float)Asag[((size_t)g * 128 + i0 + (idx >> 7)) * 128 + (idx & 127)];
  __syncthreads();
  int dq0 = lane, dq1 = lane + 64;
  bool ok1 = dq1 < 75;
  const f4 zero4 = make_float4(0.f, 0.f, 0.f, 0.f);
  const f4* h4 = (const f4*)(h + (size_t)g * LLN * DDIM);
  f4 acc0[4], acc1[4];
  #pragma unroll
  for (int r = 0; r < 4; ++r) { acc0[r] = zero4; acc1[r] = zero4; }
  for (int j = 0; j < 128; ++j) {
    float a0 = As[ii*4+0][j], a1 = As[ii*4+1][j], a2 = As[ii*4+2][j], a3 = As[ii*4+3][j];
    f4 hv0 = h4[j * 75 + dq0];
    f4 hv1 = ok1 ? h4[j * 75 + dq1] : zero4;
    FMA4(acc0[0], hv0, a0); FMA4(acc0[1], hv0, a1); FMA4(acc0[2], hv0, a2); FMA4(acc0[3], hv0, a3);
    FMA4(acc1[0], hv1, a0); FMA4(acc1[1], hv1, a1); FMA4(acc1[2], hv1, a2); FMA4(acc1[3], hv1, a3);
  }
  #pragma unroll
  for (int r = 0; r < 4; ++r) {
    int i = i0 + ii * 4 + r;
    float dv = dinv[(size_t)g * 128 + i];
    f4 n0v = scale4(add4(acc0[r], h4[i * 75 + dq0]), dv);
    size_t base = (size_t)(g * 128 + i) * 320;
    ushort4 hv, lv;
    hv.x = f2bf(n0v.x); lv.x = f2bf(n0v.x - bf2f(hv.x));
    hv.y = f2bf(n0v.y); lv.y = f2bf(n0v.y - bf2f(hv.y));
    hv.z = f2bf(n0v.z); lv.z = f2bf(n0v.z - bf2f(hv.z));
    hv.w = f2bf(n0v.w); lv.w = f2bf(n0v.w - bf2f(hv.w));
    *(ushort4*)&nh[base + dq0 * 4] = hv;
    *(ushort4*)&nl[base + dq0 * 4] = lv;
    if (ok1) {
      f4 n1v = scale4(add4(acc1[r], h4[i * 75 + dq1]), dv);
      hv.x = f2bf(n1v.x); lv.x = f2bf(n1v.x - bf2f(hv.x));
      hv.y = f2bf(n1v.y); lv.y = f2bf(n1v.y - bf2f(hv.y));
      hv.z = f2bf(n1v.z); lv.z = f2bf(n1v.z - bf2f(hv.z));
      hv.w = f2bf(n1v.w); lv.w = f2bf(n1v.w - bf2f(hv.w));
      *(ushort4*)&nh[base + dq1 * 4] = hv;
      *(ushort4*)&nl[base + dq1 * 4] = lv;
    }
    if (lane < 5) {
      ushort4 z4u = {0, 0, 0, 0};
      *(ushort4*)&nh[base + 300 + lane * 4] = z4u;
      *(ushort4*)&nl[base + 300 + lane * 4] = z4u;
    }
  }
}

// ---------------- sage_fuse: sage = neigh@sageW + b; out += sigmoid(dot)*sage
__global__ __launch_bounds__(256) void sage_fuse(
    const unsigned short* __restrict__ nh, const unsigned short* __restrict__ nl,
    const unsigned short* __restrict__ sWTh, const unsigned short* __restrict__ sWTl,
    const float* __restrict__ sage_b, const float* __restrict__ headW,
    const float* __restrict__ head_b, float* __restrict__ out) {
  __shared__ __align__(16) unsigned short Bh[320 * 32], Bl[320 * 32];
  __shared__ __align__(16) unsigned short Ah[32 * 32], Al[32 * 32];
  __shared__ float hwred[2][32];
  __shared__ float wgts[32];
  int m0 = blockIdx.x * 32;
  int tid = threadIdx.x, w = tid >> 6, lane = tid & 63;
  int lq = lane >> 4, lr = lane & 15, wi = w & 1, wn = w >> 1;
  float hb = head_b[0];
  f32x4 acc[10];
  #pragma unroll
  for (int nf = 0; nf < 10; ++nf) acc[nf] = (f32x4){0.f, 0.f, 0.f, 0.f};

  for (int kc = 0; kc < 10; ++kc) {
    {
      int t = tid & 127;
      int rowm = t >> 2, qq = t & 3;
      int idx = rowm * 32 + swzq(rowm, qq) * 8;
      if (tid < 128) {
        const unsigned short* src = nh + (size_t)(m0 + rowm) * 320 + kc * 32 + qq * 8;
        *(s16x8*)&Ah[idx] = *(const s16x8*)src;
      } else {
        const unsigned short* src = nl + (size_t)(m0 + rowm) * 320 + kc * 32 + qq * 8;
        *(s16x8*)&Al[idx] = *(const s16x8*)src;
      }
    }
    {
      #pragma unroll
      for (int rep = 0; rep < 2; ++rep) {
        int n = rep == 0 ? tid : 256 + tid;
        if (rep == 1 && tid >= 64) break;
        const unsigned short* src_h = sWTh + (size_t)n * 320 + kc * 32;
        const unsigned short* src_l = sWTl + (size_t)n * 320 + kc * 32;
        #pragma unroll
        for (int q = 0; q < 4; ++q) {
          int idx = n * 32 + swzq(n, q) * 8;
          *(s16x8*)&Bh[idx] = *(const s16x8*)(src_h + q * 8);
          *(s16x8*)&Bl[idx] = *(const s16x8*)(src_l + q * 8);
        }
      }
    }
    __syncthreads();
    int rowa = wi * 16 + lr;
    int ai = rowa * 32 + swzq(rowa, lq) * 8;
    s16x8 ah = *(const s16x8*)&Ah[ai];
    s16x8 alv = *(const s16x8*)&Al[ai];
    #pragma unroll
    for (int nf = 0; nf < 10; ++nf) {
      int rn = wn * 160 + nf * 16 + lr;
      int bi = rn * 32 + swzq(rn, lq) * 8;
      s16x8 bhv = *(const s16x8*)&Bh[bi];
      s16x8 blv = *(const s16x8*)&Bl[bi];
      acc[nf] = mfma3(ah, alv, bhv, blv, acc[nf]);
    }
    __syncthreads();
  }
  float pt[4] = {0.f, 0.f, 0.f, 0.f};
  #pragma unroll
  for (int nf = 0; nf < 10; ++nf) {
    int c = wn * 160 + nf * 16 + lr;
    bool val = c < 300;
    float sb = val ? sage_b[c] : 0.f;
    float hwv = val ? headW[c] : 0.f;
    #pragma unroll
    for (int t = 0; t < 4; ++t) {
      float gvv = acc[nf][t] + sb;
      acc[nf][t] = gvv;
      pt[t] += gvv * hwv;
    }
  }
  #pragma unroll
  for (int t = 0; t < 4; ++t) {
    #pragma unroll
    for (int mm = 1; mm < 16; mm <<= 1) pt[t] += __shfl_xor(pt[t], mm, 64);
  }
  if (lr == 0) {
    #pragma unroll
    for (int t = 0; t < 4; ++t) hwred[wn][wi * 16 + 4 * lq + t] = pt[t];
  }
  __syncthreads();
  if (tid < 32) wgts[tid] = sigm(hwred[0][tid] + hwred[1][tid] + hb);
  __syncthreads();
  #pragma unroll
  for (int nf = 0; nf < 10; ++nf) {
    int c = wn * 160 + nf * 16 + lr;
    if (c < 300) {
      #pragma unroll
      for (int t = 0; t < 4; ++t) {
        int r = wi * 16 + 4 * lq + t;
        size_t o = ((size_t)(m0 + r)) * 300 + c;
        out[o] = out[o] + wgts[r] * acc[nf][t];
      }
    }
  }
}

// ---------------- WeightAndSum pool
__global__ __launch_bounds__(256) void pool_kernel(
    const float* __restrict__ h, const float* __restrict__ poolW,
    const float* __restrict__ pool_b, float* __restrict__ gvec) {
  __shared__ float ws_[128];
  int g = blockIdx.x, tid = threadIdx.x, ii = tid >> 6, lane = tid & 63;
  const float* hg = h + (size_t)g * LLN * DDIM;
  float pb = pool_b[0];
  for (int m = 0; m < 32; ++m) {
    int l = ii * 32 + m;
    float p = 0.f;
    for (int d = lane; d < DDIM; d += 64) p += hg[l * DDIM + d] * poolW[d];
    p = wsum(p);
    if (lane == 0) ws_[l] = 1.f / (1.f + __expf(-(p + pb)));
  }
  __syncthreads();
  for (int d = tid; d < DDIM; d += 256) {
    float acc = 0.f;
    for (int l = 0; l < 128; ++l) acc += hg[l * DDIM + d] * ws_[l];
    gvec[(size_t)g * DDIM + d] = acc;
  }
}

// ---------------- pearson
__global__ __launch_bounds__(64) void pearson_kernel(
    const float* __restrict__ gvec, float* __restrict__ out) {
  int b = blockIdx.x, lane = threadIdx.x;
  const float* g1 = gvec + (size_t)b * DDIM;
  const float* g2 = gvec + (size_t)(64 + b) * DDIM;
  float v1[5], v2[5];
  float s1 = 0.f, s2 = 0.f;
  #pragma unroll
  for (int q = 0; q < 5; ++q) {
    int d = lane + 64 * q;
    v1[q] = (d < DDIM) ? g1[d] : 0.f;
    v2[q] = (d < DDIM) ? g2[d] : 0.f;
    s1 += v1[q]; s2 += v2[q];
  }
  s1 = wsum(s1); s2 = wsum(s2);
  float m1 = s1 / 300.f, m2 = s2 / 300.f;
  float a = 0.f, bb = 0.f, c = 0.f;
  #pragma unroll
  for (int q = 0; q < 5; ++q) {
    int d = lane + 64 * q;
    if (d < DDIM) {
      float x = v1[q] - m1, y = v2[q] - m2;
      a += x * y; bb += x * x; c += y * y;
    }
  }
  a = wsum(a); bb = wsum(bb); c = wsum(c);
  if (lane == 0) out[b] = 5.f * a / (sqrtf(bb) * sqrtf(c));
}

extern "C" void kernel_launch(void* const* d_in, const int* in_sizes, int n_in,
                              void* d_out, int out_size, void* d_ws, size_t ws_size,
                              hipStream_t stream) {
  (void)in_sizes; (void)n_in; (void)out_size; (void)ws_size;
  const float* emb   = (const float*)d_in[0];
  const float* simw1 = (const float*)d_in[1];
  const float* simw2 = (const float*)d_in[2];
  const float* LP[2][8];
  for (int l = 0; l < 2; ++l)
    for (int p = 0; p < 8; ++p) LP[l][p] = (const float*)d_in[3 + l * 8 + p];
  const float* poolW  = (const float*)d_in[19];
  const float* pool_b = (const float*)d_in[20];
  const int* s1 = (const int*)d_in[21];
  const int* s2 = (const int*)d_in[22];
  float* out = (float*)d_out;

  char* ws = (char*)d_ws;
  float* hA  = (float*)(ws + 0);                         // 19,660,800
  float* hB  = (float*)(ws + 19660800);                  // 19,660,800
  unsigned short* zTh = (unsigned short*)(ws + 39321600);   // 39,321,600
  unsigned short* zTl = (unsigned short*)(ws + 78643200);   // 39,321,600
  unsigned short* nh = (unsigned short*)(ws + 39321600); // alias zTh
  unsigned short* nl = (unsigned short*)(ws + 78643200); // alias zTl
  unsigned char* Agat = (unsigned char*)(ws + 117964800); // 2,097,152
  unsigned char* Asag = (unsigned char*)(ws + 120061952); // 2,097,152
  float* elb  = (float*)(ws + 122159104);                // 262,144
  float* erb  = (float*)(ws + 122421248);                // 262,144
  float* mxb  = (float*)(ws + 122683392);                // 262,144
  float* sinvb= (float*)(ws + 122945536);                // 262,144
  float* dinvb= (float*)(ws + 123207680);                // 65,536
  unsigned short* sWTh = (unsigned short*)(ws + 123273216); // 204,800
  unsigned short* sWTl = (unsigned short*)(ws + 123478016); // 204,800
  float* gv   = (float*)(ws + 123682816);                // 153,600
  unsigned short* hsplL = (unsigned short*)(ws + 123836416); // 10,485,760 -> ends 134,322,176

  gather_kernel<<<GG * LLN, 256, 0, stream>>>(emb, s1, s2, hA);

  float* hin = hA; float* hout = hB;
  for (int l = 0; l < 2; ++l) {
    // split images + weight tiles + el/er partials live in the (currently dead) hout region
    unsigned short* hsplH = (unsigned short*)hout;                        // 10,485,760
    unsigned short* gWTtH = (unsigned short*)((char*)hout + 10485760);    //    819,200
    unsigned short* gWTtL = (unsigned short*)((char*)hout + 11304960);    //    819,200
    float*          partb = (float*)((char*)hout + 12124160);             //  3,145,728 -> 15,269,888 < 19.6MB

    adjmm_kernel<<<256, 256, 0, stream>>>(hin, simw1, simw2, Agat, Asag);
    prepw_kernel<<<2000, 256, 0, stream>>>(LP[l][0], LP[l][4], gWTtH, gWTtL, sWTh, sWTl);
    hsplit_kernel<<<1280, 256, 0, stream>>>(hin, hsplH, hsplL);
    zmm_mfma<<<1280, 256, 0, stream>>>(hsplH, hsplL, gWTtH, gWTtL,
                                       LP[l][1], LP[l][2], zTh, zTl, partb);
    alphap_kernel<<<dim3(GG, 5), 256, 0, stream>>>(Agat, Asag, partb,
                                                   elb, erb, mxb, sinvb, dinvb);
    gat_fuse<<<512, 256, 0, stream>>>(hin, Agat, zTh, zTl, elb, erb, mxb, sinvb,
        LP[l][3], LP[l][6], LP[l][7], hout);
    neigh_kernel<<<1024, 256, 0, stream>>>(hin, Asag, dinvb, nh, nl);
    sage_fuse<<<512, 256, 0, stream>>>(nh, nl, sWTh, sWTl, LP[l][5], LP[l][6], LP[l][7], hout);
    float* t = hin; hin = hout; hout = t;
  }

  pool_kernel<<<GG, 256, 0, stream>>>(hin, poolW, pool_b, gv);
  pearson_kernel<<<64, 64, 0, stream>>>(gv, out);
}

// Round 8
// 678.312 us; speedup vs baseline: 1.1335x; 1.1335x over previous
//
#include <hip/hip_runtime.h>
#include <hip/hip_bf16.h>

#define GG 128   // graphs total (2 branches x 64)
#define LLN 128
#define DDIM 300
#define NH 4

typedef float4 f4;
typedef __attribute__((ext_vector_type(4))) float f32x4;
typedef __attribute__((ext_vector_type(8))) short s16x8;

__device__ __forceinline__ float wsum(float v) {
  #pragma unroll
  for (int o = 32; o > 0; o >>= 1) v += __shfl_xor(v, o, 64);
  return v;
}
__device__ __forceinline__ float wmax(float v) {
  #pragma unroll
  for (int o = 32; o > 0; o >>= 1) v = fmaxf(v, __shfl_xor(v, o, 64));
  return v;
}
__device__ __forceinline__ f4 add4(f4 a, f4 b) {
  return make_float4(a.x+b.x, a.y+b.y, a.z+b.z, a.w+b.w);
}
__device__ __forceinline__ f4 scale4(f4 a, float s) {
  return make_float4(a.x*s, a.y*s, a.z*s, a.w*s);
}
#define FMA4(acc, v, s) { (acc).x += (s)*(v).x; (acc).y += (s)*(v).y; (acc).z += (s)*(v).z; (acc).w += (s)*(v).w; }

__device__ __forceinline__ unsigned short f2bf(float x) {
  unsigned int u = __float_as_uint(x);
  return (unsigned short)((u + 0x7fffu + ((u >> 16) & 1u)) >> 16);
}
__device__ __forceinline__ float bf2f(unsigned short b) {
  return __uint_as_float(((unsigned int)b) << 16);
}
__device__ __forceinline__ int swzq(int row, int q) { return q ^ ((row >> 1) & 3); }
__device__ __forceinline__ float sigm(float x) { return 1.f / (1.f + __expf(-x)); }

__device__ __forceinline__ f32x4 mfma3(s16x8 ah, s16x8 al, s16x8 bh, s16x8 bl, f32x4 c) {
  c = __builtin_amdgcn_mfma_f32_16x16x32_bf16(ah, bh, c, 0, 0, 0);
  c = __builtin_amdgcn_mfma_f32_16x16x32_bf16(ah, bl, c, 0, 0, 0);
  c = __builtin_amdgcn_mfma_f32_16x16x32_bf16(al, bh, c, 0, 0, 0);
  return c;
}
__device__ __forceinline__ f32x4 mfma4(s16x8 ah, s16x8 al, s16x8 bh, s16x8 bl, f32x4 c) {
  c = __builtin_amdgcn_mfma_f32_16x16x32_bf16(ah, bh, c, 0, 0, 0);
  c = __builtin_amdgcn_mfma_f32_16x16x32_bf16(ah, bl, c, 0, 0, 0);
  c = __builtin_amdgcn_mfma_f32_16x16x32_bf16(al, bh, c, 0, 0, 0);
  c = __builtin_amdgcn_mfma_f32_16x16x32_bf16(al, bl, c, 0, 0, 0);
  return c;
}

__device__ __forceinline__ void gld16(const void* g, void* l) {
  __builtin_amdgcn_global_load_lds(
      (const __attribute__((address_space(1))) void*)g,
      (__attribute__((address_space(3))) void*)l, 16, 0, 0);
}

__device__ __forceinline__ void xcd_decode8(int id, int& g, int& it) {
  int x = id & 7, t = id >> 3;
  it = t & 7; g = x + 8 * (t >> 3);
}

// ---------------- embedding gather
__global__ __launch_bounds__(256) void gather_kernel(
    const float* __restrict__ emb, const int* __restrict__ s1,
    const int* __restrict__ s2, float* __restrict__ h) {
  int gl = blockIdx.x;
  int g = gl >> 7, l = gl & 127;
  const int* s = (g >= 64) ? s2 : s1;
  int tok = s[l * 64 + (g & 63)];
  const float* src = emb + (size_t)tok * DDIM;
  float* dst = h + (size_t)gl * DDIM;
  for (int d = threadIdx.x; d < DDIM; d += 256) dst[d] = src[d];
}

// ---------------- adjmm: both adjacencies via 4-term split-bf16 MFMA (V.V^T, symmetric)
// u==0 blocks additionally emit the raw-h split tile images (fused hsplit).
__global__ __launch_bounds__(256) void adjmm_kernel(
    const float* __restrict__ h, const float* __restrict__ simw1,
    const float* __restrict__ simw2, unsigned char* __restrict__ Agat,
    unsigned char* __restrict__ Asag,
    unsigned short* __restrict__ hh, unsigned short* __restrict__ hl) {
  __shared__ __align__(16) unsigned short Vh[128 * 32], Vl[128 * 32];
  __shared__ float wv[320];
  int x = blockIdx.x & 7, t = blockIdx.x >> 3;
  int u = t & 1, g = x + 8 * (t >> 1);
  const float* w = u ? simw1 : simw2;
  unsigned char* A = (u ? Asag : Agat) + (size_t)g * LLN * LLN;
  int tid = threadIdx.x, wid = tid >> 6, lane = tid & 63;
  int lq = lane >> 4, lr = lane & 15;
  for (int k = tid; k < 320; k += 256) wv[k] = (k < 300) ? w[k] : 0.f;
  f32x4 acc[2][8];
  #pragma unroll
  for (int fr = 0; fr < 2; ++fr)
    #pragma unroll
    for (int nf = 0; nf < 8; ++nf) acc[fr][nf] = (f32x4){0.f, 0.f, 0.f, 0.f};
  const float* hg = h + (size_t)g * LLN * DDIM;

  for (int kc = 0; kc < 10; ++kc) {
    __syncthreads();
    {
      int m = tid >> 1, halfk = tid & 1;
      int kb = kc * 32 + halfk * 16;
      const float* hp = hg + (size_t)m * DDIM;
      float v[16];
      if (kb + 15 < 300) {
        f4 x0 = *(const f4*)(hp + kb);
        f4 x1 = *(const f4*)(hp + kb + 4);
        f4 x2 = *(const f4*)(hp + kb + 8);
        f4 x3 = *(const f4*)(hp + kb + 12);
        v[0]=x0.x; v[1]=x0.y; v[2]=x0.z; v[3]=x0.w;
        v[4]=x1.x; v[5]=x1.y; v[6]=x1.z; v[7]=x1.w;
        v[8]=x2.x; v[9]=x2.y; v[10]=x2.z; v[11]=x2.w;
        v[12]=x3.x; v[13]=x3.y; v[14]=x3.z; v[15]=x3.w;
      } else {
        #pragma unroll
        for (int e = 0; e < 16; ++e) { int k = kb + e; v[e] = (k < 300) ? hp[k] : 0.f; }
      }
      // fused hsplit: raw-h split images (u==0 writer only; bitwise == old hsplit)
      if (u == 0) {
        unsigned short* oh = hh + (size_t)(g * 10 + kc) * 4096;
        unsigned short* ol = hl + (size_t)(g * 10 + kc) * 4096;
        #pragma unroll
        for (int g4 = 0; g4 < 4; ++g4) {
          int klocal = halfk * 16 + g4 * 4;
          int q = klocal >> 3, wb = klocal & 7;
          int idx = m * 32 + swzq(m, q) * 8 + wb;
          ushort4 hv, lv;
          hv.x = f2bf(v[g4*4+0]); lv.x = f2bf(v[g4*4+0] - bf2f(hv.x));
          hv.y = f2bf(v[g4*4+1]); lv.y = f2bf(v[g4*4+1] - bf2f(hv.y));
          hv.z = f2bf(v[g4*4+2]); lv.z = f2bf(v[g4*4+2] - bf2f(hv.z));
          hv.w = f2bf(v[g4*4+3]); lv.w = f2bf(v[g4*4+3] - bf2f(hv.w));
          *(ushort4*)&oh[idx] = hv;
          *(ushort4*)&ol[idx] = lv;
        }
      }
      #pragma unroll
      for (int e = 0; e < 16; ++e) v[e] = fmaxf(v[e] * wv[kb + e], 0.f);
      #pragma unroll
      for (int g4 = 0; g4 < 4; ++g4) {
        int klocal = halfk * 16 + g4 * 4;
        int q = klocal >> 3, wb = klocal & 7;
        int idx = m * 32 + swzq(m, q) * 8 + wb;
        ushort4 hv, lv;
        hv.x = f2bf(v[g4*4+0]); lv.x = f2bf(v[g4*4+0] - bf2f(hv.x));
        hv.y = f2bf(v[g4*4+1]); lv.y = f2bf(v[g4*4+1] - bf2f(hv.y));
        hv.z = f2bf(v[g4*4+2]); lv.z = f2bf(v[g4*4+2] - bf2f(hv.z));
        hv.w = f2bf(v[g4*4+3]); lv.w = f2bf(v[g4*4+3] - bf2f(hv.w));
        *(ushort4*)&Vh[idx] = hv;
        *(ushort4*)&Vl[idx] = lv;
      }
    }
    __syncthreads();
    #pragma unroll
    for (int fr = 0; fr < 2; ++fr) {
      int ra = wid * 32 + fr * 16 + lr;
      int ai = ra * 32 + swzq(ra, lq) * 8;
      s16x8 ah = *(const s16x8*)&Vh[ai];
      s16x8 al = *(const s16x8*)&Vl[ai];
      #pragma unroll
      for (int nf = 0; nf < 8; ++nf) {
        int rb = nf * 16 + lr;
        int bi = rb * 32 + swzq(rb, lq) * 8;
        s16x8 bh = *(const s16x8*)&Vh[bi];
        s16x8 bl = *(const s16x8*)&Vl[bi];
        acc[fr][nf] = mfma4(ah, al, bh, bl, acc[fr][nf]);
      }
    }
  }
  __syncthreads();
  unsigned char* Au8 = (unsigned char*)Vh;   // 16 KB reuse (Vh+Vl)
  #pragma unroll
  for (int fr = 0; fr < 2; ++fr) {
    #pragma unroll
    for (int nf = 0; nf < 8; ++nf) {
      int j = nf * 16 + lr;
      #pragma unroll
      for (int t2 = 0; t2 < 4; ++t2) {
        int i = wid * 32 + fr * 16 + 4 * lq + t2;
        Au8[i * 128 + j] = (acc[fr][nf][t2] >= 0.1f || i == j) ? 1 : 0;
      }
    }
  }
  __syncthreads();
  for (int c = tid; c < 1024; c += 256) {
    int r = c >> 3, q = c & 7;
    uint4 val = *(const uint4*)&Au8[r * 128 + q * 16];
    *(uint4*)&A[(size_t)r * 128 + q * 16] = val;
  }
}

// ---------------- prepW: gatW -> split bf16 tile images; sageW -> row-major split
__global__ __launch_bounds__(256) void prepw_kernel(
    const float* __restrict__ gatW, const float* __restrict__ sageW,
    unsigned short* __restrict__ gWTtH, unsigned short* __restrict__ gWTtL,
    unsigned short* __restrict__ sWTh, unsigned short* __restrict__ sWTl) {
  int idx = blockIdx.x * 256 + threadIdx.x;
  if (idx < 1280 * 320) {
    int n = idx / 320, katt = idx - (idx / 320) * 320;
    int nt = n >> 7, nl = n & 127;
    int kc = katt >> 5, klocal = katt & 31;
    int q = klocal >> 3, wb = klocal & 7;
    size_t pos = ((size_t)(nt * 10 + kc) * 128 + nl) * 32 + swzq(nl, q) * 8 + wb;
    float v = (n < 1200 && katt < 300) ? gatW[(size_t)katt * 1200 + n] : 0.f;
    unsigned short hv = f2bf(v);
    gWTtH[pos] = hv;
    gWTtL[pos] = f2bf(v - bf2f(hv));
  } else if (idx < 1280 * 320 + 320 * 320) {
    int i2 = idx - 1280 * 320;
    int n = i2 / 320, k = i2 % 320;
    float v = (n < 300 && k < 300) ? sageW[(size_t)k * 300 + n] : 0.f;
    unsigned short hv = f2bf(v);
    sWTh[i2] = hv;
    sWTl[i2] = f2bf(v - bf2f(hv));
  }
}

// ---------------- zmm: z = h @ gatW via split-bf16 MFMA; gld16 staging from tile images.
// el/er partials per 64-col band -> unique slot (deterministic, no atomics).
__global__ __launch_bounds__(256) void zmm_mfma(
    const unsigned short* __restrict__ hsplH, const unsigned short* __restrict__ hsplL,
    const unsigned short* __restrict__ gWTtH, const unsigned short* __restrict__ gWTtL,
    const float* __restrict__ attn_l, const float* __restrict__ attn_r,
    unsigned short* __restrict__ zTh, unsigned short* __restrict__ zTl,
    float* __restrict__ part) {
  __shared__ __align__(16) unsigned short smem[128 * 136];   // 34816 B
  unsigned short* Ah = smem;
  unsigned short* Al = smem + 4096;
  unsigned short* Bh = smem + 8192;
  unsigned short* Bl = smem + 12288;
  int x = blockIdx.x & 7, tb = blockIdx.x >> 3;
  int gi = tb / 10, nt = tb - gi * 10;
  int g = x + 8 * gi;
  int n0 = nt * 128;
  int tid = threadIdx.x, w = tid >> 6, lane = tid & 63;
  int lq = lane >> 4, lr = lane & 15, wr = w >> 1, wc = w & 1;
  f32x4 acc[4][4];
  #pragma unroll
  for (int a = 0; a < 4; ++a)
    #pragma unroll
    for (int b = 0; b < 4; ++b) acc[a][b] = (f32x4){0.f, 0.f, 0.f, 0.f};

  for (int kc = 0; kc < 10; ++kc) {
    {
      const unsigned short* ah_g = hsplH + (size_t)(g * 10 + kc) * 4096;
      const unsigned short* al_g = hsplL + (size_t)(g * 10 + kc) * 4096;
      const unsigned short* bh_g = gWTtH + (size_t)(nt * 10 + kc) * 4096;
      const unsigned short* bl_g = gWTtL + (size_t)(nt * 10 + kc) * 4096;
      int o = tid * 8;
      gld16(ah_g + o, Ah + o); gld16(ah_g + o + 2048, Ah + o + 2048);
      gld16(al_g + o, Al + o); gld16(al_g + o + 2048, Al + o + 2048);
      gld16(bh_g + o, Bh + o); gld16(bh_g + o + 2048, Bh + o + 2048);
      gld16(bl_g + o, Bl + o); gld16(bl_g + o + 2048, Bl + o + 2048);
    }
    __syncthreads();   // drains vmcnt (global_load_lds) before reads
    s16x8 ah[4], alo[4];
    #pragma unroll
    for (int mf = 0; mf < 4; ++mf) {
      int row = wr * 64 + mf * 16 + lr;
      int ai = row * 32 + swzq(row, lq) * 8;
      ah[mf] = *(const s16x8*)&Ah[ai];
      alo[mf] = *(const s16x8*)&Al[ai];
    }
    #pragma unroll
    for (int nf = 0; nf < 4; ++nf) {
      int rn = wc * 64 + nf * 16 + lr;
      int bi = rn * 32 + swzq(rn, lq) * 8;
      s16x8 bhv = *(const s16x8*)&Bh[bi];
      s16x8 blv = *(const s16x8*)&Bl[bi];
      #pragma unroll
      for (int mf = 0; mf < 4; ++mf)
        acc[mf][nf] = mfma3(ah[mf], alo[mf], bhv, blv, acc[mf][nf]);
    }
    __syncthreads();
  }

  // ---- el/er partial dots -> unique (g, head, slot) slots; no atomics ----
  {
    int cbase = n0 + wc * 64;
    if (cbase < 1200) {
      int b = cbase >> 6;                 // band 0..18
      int h_base = cbase / 300;
      int fb = (h_base == 0) ? 0 : (h_base == 1) ? 5 : (h_base == 2) ? 10 : 15;
      int slot = b - fb + 1;              // 1..5
      int h_last = (cbase + 63 < 1200 ? cbase + 63 : 1199) / 300;
      bool has_alt = (h_last != h_base);
      float aLv[4], aRv[4]; int alt[4];
      #pragma unroll
      for (int nf = 0; nf < 4; ++nf) {
        int cg = cbase + nf * 16 + lr;
        bool ok = cg < 1200;
        aLv[nf] = ok ? attn_l[cg] : 0.f;
        aRv[nf] = ok ? attn_r[cg] : 0.f;
        alt[nf] = (ok && (cg / 300) != h_base) ? 1 : 0;
      }
      float* p0 = part + (((size_t)(g * 4 + h_base) * 6 + slot) * 2) * 128;
      float* p1 = part + (((size_t)(g * 4 + h_base + 1) * 6 + 0) * 2) * 128;
      #pragma unroll
      for (int mf = 0; mf < 4; ++mf) {
        #pragma unroll
        for (int t2 = 0; t2 < 4; ++t2) {
          float s0l = 0.f, s0r = 0.f, s1l = 0.f, s1r = 0.f;
          #pragma unroll
          for (int nf = 0; nf < 4; ++nf) {
            float v = acc[mf][nf][t2];
            float cl = v * aLv[nf], cr = v * aRv[nf];
            s0l += alt[nf] ? 0.f : cl; s1l += alt[nf] ? cl : 0.f;
            s0r += alt[nf] ? 0.f : cr; s1r += alt[nf] ? cr : 0.f;
          }
          #pragma unroll
          for (int mm = 1; mm < 16; mm <<= 1) {
            s0l += __shfl_xor(s0l, mm, 64);
            s0r += __shfl_xor(s0r, mm, 64);
          }
          if (has_alt) {
            #pragma unroll
            for (int mm = 1; mm < 16; mm <<= 1) {
              s1l += __shfl_xor(s1l, mm, 64);
              s1r += __shfl_xor(s1r, mm, 64);
            }
          }
          if (lr == 0) {
            int j = wr * 64 + mf * 16 + 4 * lq + t2;
            p0[j] = s0l; p0[128 + j] = s0r;
            if (has_alt) { p1[j] = s1l; p1[128 + j] = s1r; }
          }
        }
      }
    }
  }

  // ---- transposed coalesced zT store: pass 0 = hi, pass 1 = lo ----
  for (int pass = 0; pass < 2; ++pass) {
    __syncthreads();
    #pragma unroll
    for (int mf = 0; mf < 4; ++mf) {
      #pragma unroll
      for (int nf = 0; nf < 4; ++nf) {
        int cl = wc * 64 + nf * 16 + lr;
        int j0 = wr * 64 + mf * 16 + 4 * lq;
        f32x4 a = acc[mf][nf];
        ushort4 pv;
        if (pass == 0) {
          pv.x = f2bf(a[0]); pv.y = f2bf(a[1]); pv.z = f2bf(a[2]); pv.w = f2bf(a[3]);
        } else {
          unsigned short hx;
          hx = f2bf(a[0]); pv.x = f2bf(a[0] - bf2f(hx));
          hx = f2bf(a[1]); pv.y = f2bf(a[1] - bf2f(hx));
          hx = f2bf(a[2]); pv.z = f2bf(a[2] - bf2f(hx));
          hx = f2bf(a[3]); pv.w = f2bf(a[3] - bf2f(hx));
        }
        *(ushort4*)&smem[cl * 136 + j0] = pv;
      }
    }
    __syncthreads();
    unsigned short* dst = pass ? zTl : zTh;
    #pragma unroll
    for (int p = 0; p < 8; ++p) {
      int c = tid + p * 256;
      int r = c >> 4, q = c & 15;
      int cg = n0 + r;
      if (cg < 1200) {
        int head = cg / 300, d = cg - head * 300;
        uint4 val = *(const uint4*)&smem[r * 136 + q * 8];
        *(uint4*)(dst + ((size_t)(g * 4 + head) * 300 + d) * 128 + q * 8) = val;
      }
    }
  }
}

// ---------------- elr_lite: reduce el/er partials in fixed slot order (deterministic)
__global__ __launch_bounds__(256) void elr_lite(
    const float* __restrict__ part, float* __restrict__ el, float* __restrict__ er) {
  int g = blockIdx.x, tid = threadIdx.x;
  int j = tid & 127, side = tid >> 7;
  for (int s = 0; s < 4; ++s) {
    int s0 = (s == 0) ? 1 : 0;
    int s1e = (s == 3) ? 4 : 5;
    float v = 0.f;
    for (int sl = s0; sl <= s1e; ++sl)
      v += part[(((size_t)(g * 4 + s) * 6 + sl) * 2 + side) * 128 + j];
    float* dst = side ? er : el;
    dst[(size_t)(g * 4 + s) * 128 + j] = v;
  }
}

// ---------------- gat_fuse: fused mx/sinv + 4 GAT heads via MFMA + head weights + residual
// B-stage via global_load_lds with pre-swizzled global source (q_src = q ^ ((n>>1)&3)).
__global__ __launch_bounds__(256) void gat_fuse(
    const float* __restrict__ h, const unsigned char* __restrict__ Agat,
    const unsigned short* __restrict__ zTh, const unsigned short* __restrict__ zTl,
    const float* __restrict__ el, const float* __restrict__ er,
    const float* __restrict__ gat_b, const float* __restrict__ headW,
    const float* __restrict__ head_b, const unsigned short* __restrict__ zerobuf,
    float* __restrict__ out) {
  __shared__ __align__(16) unsigned short Bh[320 * 32], Bl[320 * 32];
  __shared__ __align__(16) unsigned short Ah[32 * 32], Al[32 * 32];
  __shared__ __align__(16) unsigned char Ag8[32 * 128];
  __shared__ __align__(16) float elsm[4 * 128];
  __shared__ __align__(16) float ersl[4 * 32];
  __shared__ __align__(16) float mxl[4 * 32];
  __shared__ __align__(16) float svl[4 * 32];
  __shared__ float hwred[2][32];
  __shared__ float wgts[32];
  int xb = blockIdx.x & 7, tb = blockIdx.x >> 3;
  int it = tb & 3, g = xb + 8 * (tb >> 2);
  int i0 = it * 32;
  int tid = threadIdx.x, w = tid >> 6, lane = tid & 63;
  int lq = lane >> 4, lr = lane & 15, wi = w & 1, wn = w >> 1;
  float hb = head_b[0];

  // ---- pre-pass: stage Agat tile + el/er; compute mx/sinv for own 32 rows ----
  {
    int r = tid >> 3, o = (tid & 7) * 16;
    *(uint4*)&Ag8[r * 128 + o] = *(const uint4*)(Agat + ((size_t)g * 128 + i0 + r) * 128 + o);
    elsm[tid] = el[(size_t)(g * 4) * 128 + tid];            // s=0,1 flat
    elsm[256 + tid] = el[(size_t)(g * 4) * 128 + 256 + tid]; // s=2,3 flat
    if (tid < 128) {
      int s = tid >> 5, r2 = tid & 31;
      ersl[tid] = er[(size_t)(g * 4 + s) * 128 + i0 + r2];
    }
  }
  __syncthreads();
  for (int s = 0; s < 4; ++s) {
    float el0 = elsm[s * 128 + lane], el1 = elsm[s * 128 + 64 + lane];
    for (int r = w; r < 32; r += 4) {
      int m0 = Ag8[r * 128 + lane], m1 = Ag8[r * 128 + 64 + lane];
      float eri = ersl[s * 32 + r];
      float e0 = eri + el0; e0 = e0 >= 0.f ? e0 : 0.2f * e0;
      float e1 = eri + el1; e1 = e1 >= 0.f ? e1 : 0.2f * e1;
      float x0 = m0 ? e0 : -3.0e38f;
      float x1 = m1 ? e1 : -3.0e38f;
      float m_ = wmax(fmaxf(x0, x1));
      float p0 = m0 ? __expf(e0 - m_) : 0.f;
      float p1 = m1 ? __expf(e1 - m_) : 0.f;
      float ssum = wsum(p0 + p1);
      if (lane == 0) { mxl[s * 32 + r] = m_; svl[s * 32 + r] = 1.f / ssum; }
    }
  }
  __syncthreads();

  float outacc[10][4];
  #pragma unroll
  for (int nf = 0; nf < 10; ++nf)
    #pragma unroll
    for (int t = 0; t < 4; ++t) outacc[nf][t] = 0.f;

  for (int s = 0; s < 4; ++s) {
    f32x4 acc[10];
    #pragma unroll
    for (int nf = 0; nf < 10; ++nf) acc[nf] = (f32x4){0.f, 0.f, 0.f, 0.f};
    const unsigned short* zsh = zTh + (size_t)(g * 4 + s) * 300 * 128;
    const unsigned short* zsl = zTl + (size_t)(g * 4 + s) * 300 * 128;

    for (int kc = 0; kc < 4; ++kc) {
      int j0 = kc * 32;
      // A stage: p = mask ? exp(leaky(er_i+el_j) - mx_i) : 0, split hi/lo (LDS sources)
      {
        int m = tid >> 3, j4 = (tid & 7) * 4;
        float eri = ersl[s * 32 + m], mxi = mxl[s * 32 + m];
        const unsigned char* mrow = &Ag8[m * 128 + j0 + j4];
        uchar4 msk = *(const uchar4*)mrow;
        f4 elv = *(const f4*)&elsm[s * 128 + j0 + j4];
        float p[4];
        {
          float e = eri + elv.x; e = e >= 0.f ? e : 0.2f * e; p[0] = msk.x ? __expf(e - mxi) : 0.f;
          e = eri + elv.y; e = e >= 0.f ? e : 0.2f * e; p[1] = msk.y ? __expf(e - mxi) : 0.f;
          e = eri + elv.z; e = e >= 0.f ? e : 0.2f * e; p[2] = msk.z ? __expf(e - mxi) : 0.f;
          e = eri + elv.w; e = e >= 0.f ? e : 0.2f * e; p[3] = msk.w ? __expf(e - mxi) : 0.f;
        }
        int q = j4 >> 3, wb = j4 & 7;
        int idx = m * 32 + swzq(m, q) * 8 + wb;
        ushort4 hv, lv;
        hv.x = f2bf(p[0]); lv.x = f2bf(p[0] - bf2f(hv.x));
        hv.y = f2bf(p[1]); lv.y = f2bf(p[1] - bf2f(hv.y));
        hv.z = f2bf(p[2]); lv.z = f2bf(p[2] - bf2f(hv.z));
        hv.w = f2bf(p[3]); lv.w = f2bf(p[3] - bf2f(hv.w));
        *(ushort4*)&Ah[idx] = hv;
        *(ushort4*)&Al[idx] = lv;
      }
      // B stage: gld16 from pre-swizzled global source; rows>=300 from zerobuf
      {
        #pragma unroll
        for (int cc = 0; cc < 5; ++cc) {
          int chunk = w + cc * 4;            // 0..19
          int nb = chunk * 16;
          int n = nb + (lane >> 2);
          int q = (lane & 3) ^ ((n >> 1) & 3);
          const unsigned short* srcH = (n < 300) ? (zsh + (size_t)n * 128 + j0 + q * 8) : zerobuf;
          const unsigned short* srcL = (n < 300) ? (zsl + (size_t)n * 128 + j0 + q * 8) : zerobuf;
          gld16(srcH, Bh + chunk * 512 + lane * 8);
          gld16(srcL, Bl + chunk * 512 + lane * 8);
        }
      }
      __syncthreads();
      int rowa = wi * 16 + lr;
      int ai = rowa * 32 + swzq(rowa, lq) * 8;
      s16x8 ah = *(const s16x8*)&Ah[ai];
      s16x8 alv = *(const s16x8*)&Al[ai];
      #pragma unroll
      for (int nf = 0; nf < 10; ++nf) {
        int rn = wn * 160 + nf * 16 + lr;
        int bi = rn * 32 + swzq(rn, lq) * 8;
        s16x8 bhv = *(const s16x8*)&Bh[bi];
        s16x8 blv = *(const s16x8*)&Bl[bi];
        acc[nf] = mfma3(ah, alv, bhv, blv, acc[nf]);
      }
      __syncthreads();
    }
    // epilogue for slot s
    f4 sv4 = *(const f4*)&svl[s * 32 + wi * 16 + 4 * lq];
    float svf[4] = {sv4.x, sv4.y, sv4.z, sv4.w};
    float pt[4] = {0.f, 0.f, 0.f, 0.f};
    #pragma unroll
    for (int nf = 0; nf < 10; ++nf) {
      int c = wn * 160 + nf * 16 + lr;
      bool val = c < 300;
      float gb = val ? gat_b[s * 300 + c] : 0.f;
      float hwv = val ? headW[c] : 0.f;
      #pragma unroll
      for (int t = 0; t < 4; ++t) {
        float gvv = acc[nf][t] * svf[t] + gb;
        acc[nf][t] = gvv;
        pt[t] += gvv * hwv;
      }
    }
    #pragma unroll
    for (int t = 0; t < 4; ++t) {
      #pragma unroll
      for (int mm = 1; mm < 16; mm <<= 1) pt[t] += __shfl_xor(pt[t], mm, 64);
    }
    if (lr == 0) {
      #pragma unroll
      for (int t = 0; t < 4; ++t) hwred[wn][wi * 16 + 4 * lq + t] = pt[t];
    }
    __syncthreads();
    if (tid < 32) wgts[tid] = sigm(hwred[0][tid] + hwred[1][tid] + hb);
    __syncthreads();
    #pragma unroll
    for (int nf = 0; nf < 10; ++nf) {
      #pragma unroll
      for (int t = 0; t < 4; ++t) {
        int r = wi * 16 + 4 * lq + t;
        outacc[nf][t] += wgts[r] * acc[nf][t];
      }
    }
    __syncthreads();
  }
  #pragma unroll
  for (int nf = 0; nf < 10; ++nf) {
    int c = wn * 160 + nf * 16 + lr;
    if (c < 300) {
      #pragma unroll
      for (int t = 0; t < 4; ++t) {
        int r = wi * 16 + 4 * lq + t;
        size_t o = ((size_t)(g * 128 + i0 + r)) * 300 + c;
        out[o] = h[o] + outacc[nf][t];
      }
    }
  }
}

// ---------------- neigh (fp32): n = (Asag@h + h)*dinv -> split bf16; dinv computed locally
__global__ __launch_bounds__(256) void neigh_kernel(
    const float* __restrict__ h, const unsigned char* __restrict__ Asag,
    unsigned short* __restrict__ nh, unsigned short* __restrict__ nl) {
  __shared__ float As[16][128];
  int g, it; xcd_decode8(blockIdx.x, g, it);
  int i0 = it * 16;
  int tid = threadIdx.x, ii = tid >> 6, lane = tid & 63;
  for (int idx = tid; idx < 16 * 128; idx += 256)
    As[idx >> 7][idx & 127] = (float)Asag[((size_t)g * 128 + i0 + (idx >> 7)) * 128 + (idx & 127)];
  __syncthreads();
  float dinv_r[4];
  #pragma unroll
  for (int r = 0; r < 4; ++r) {
    int row = ii * 4 + r;
    float s_ = As[row][lane] + As[row][64 + lane];
    s_ = wsum(s_);
    dinv_r[r] = 1.f / (s_ + 1.f);
  }
  int dq0 = lane, dq1 = lane + 64;
  bool ok1 = dq1 < 75;
  const f4 zero4 = make_float4(0.f, 0.f, 0.f, 0.f);
  const f4* h4 = (const f4*)(h + (size_t)g * LLN * DDIM);
  f4 acc0[4], acc1[4];
  #pragma unroll
  for (int r = 0; r < 4; ++r) { acc0[r] = zero4; acc1[r] = zero4; }
  for (int j = 0; j < 128; ++j) {
    float a0 = As[ii*4+0][j], a1 = As[ii*4+1][j], a2 = As[ii*4+2][j], a3 = As[ii*4+3][j];
    f4 hv0 = h4[j * 75 + dq0];
    f4 hv1 = ok1 ? h4[j * 75 + dq1] : zero4;
    FMA4(acc0[0], hv0, a0); FMA4(acc0[1], hv0, a1); FMA4(acc0[2], hv0, a2); FMA4(acc0[3], hv0, a3);
    FMA4(acc1[0], hv1, a0); FMA4(acc1[1], hv1, a1); FMA4(acc1[2], hv1, a2); FMA4(acc1[3], hv1, a3);
  }
  #pragma unroll
  for (int r = 0; r < 4; ++r) {
    int i = i0 + ii * 4 + r;
    float dv = dinv_r[r];
    f4 n0v = scale4(add4(acc0[r], h4[i * 75 + dq0]), dv);
    size_t base = (size_t)(g * 128 + i) * 320;
    ushort4 hv, lv;
    hv.x = f2bf(n0v.x); lv.x = f2bf(n0v.x - bf2f(hv.x));
    hv.y = f2bf(n0v.y); lv.y = f2bf(n0v.y - bf2f(hv.y));
    hv.z = f2bf(n0v.z); lv.z = f2bf(n0v.z - bf2f(hv.z));
    hv.w = f2bf(n0v.w); lv.w = f2bf(n0v.w - bf2f(hv.w));
    *(ushort4*)&nh[base + dq0 * 4] = hv;
    *(ushort4*)&nl[base + dq0 * 4] = lv;
    if (ok1) {
      f4 n1v = scale4(add4(acc1[r], h4[i * 75 + dq1]), dv);
      hv.x = f2bf(n1v.x); lv.x = f2bf(n1v.x - bf2f(hv.x));
      hv.y = f2bf(n1v.y); lv.y = f2bf(n1v.y - bf2f(hv.y));
      hv.z = f2bf(n1v.z); lv.z = f2bf(n1v.z - bf2f(hv.z));
      hv.w = f2bf(n1v.w); lv.w = f2bf(n1v.w - bf2f(hv.w));
      *(ushort4*)&nh[base + dq1 * 4] = hv;
      *(ushort4*)&nl[base + dq1 * 4] = lv;
    }
    if (lane < 5) {
      ushort4 z4u = {0, 0, 0, 0};
      *(ushort4*)&nh[base + 300 + lane * 4] = z4u;
      *(ushort4*)&nl[base + 300 + lane * 4] = z4u;
    }
  }
}

// ---------------- sage_fuse: sage = neigh@sageW + b; out += sigmoid(dot)*sage
__global__ __launch_bounds__(256) void sage_fuse(
    const unsigned short* __restrict__ nh, const unsigned short* __restrict__ nl,
    const unsigned short* __restrict__ sWTh, const unsigned short* __restrict__ sWTl,
    const float* __restrict__ sage_b, const float* __restrict__ headW,
    const float* __restrict__ head_b, float* __restrict__ out) {
  __shared__ __align__(16) unsigned short Bh[320 * 32], Bl[320 * 32];
  __shared__ __align__(16) unsigned short Ah[32 * 32], Al[32 * 32];
  __shared__ float hwred[2][32];
  __shared__ float wgts[32];
  int m0 = blockIdx.x * 32;
  int tid = threadIdx.x, w = tid >> 6, lane = tid & 63;
  int lq = lane >> 4, lr = lane & 15, wi = w & 1, wn = w >> 1;
  float hb = head_b[0];
  f32x4 acc[10];
  #pragma unroll
  for (int nf = 0; nf < 10; ++nf) acc[nf] = (f32x4){0.f, 0.f, 0.f, 0.f};

  for (int kc = 0; kc < 10; ++kc) {
    {
      int t = tid & 127;
      int rowm = t >> 2, qq = t & 3;
      int idx = rowm * 32 + swzq(rowm, qq) * 8;
      if (tid < 128) {
        const unsigned short* src = nh + (size_t)(m0 + rowm) * 320 + kc * 32 + qq * 8;
        *(s16x8*)&Ah[idx] = *(const s16x8*)src;
      } else {
        const unsigned short* src = nl + (size_t)(m0 + rowm) * 320 + kc * 32 + qq * 8;
        *(s16x8*)&Al[idx] = *(const s16x8*)src;
      }
    }
    {
      #pragma unroll
      for (int rep = 0; rep < 2; ++rep) {
        int n = rep == 0 ? tid : 256 + tid;
        if (rep == 1 && tid >= 64) break;
        const unsigned short* src_h = sWTh + (size_t)n * 320 + kc * 32;
        const unsigned short* src_l = sWTl + (size_t)n * 320 + kc * 32;
        #pragma unroll
        for (int q = 0; q < 4; ++q) {
          int idx = n * 32 + swzq(n, q) * 8;
          *(s16x8*)&Bh[idx] = *(const s16x8*)(src_h + q * 8);
          *(s16x8*)&Bl[idx] = *(const s16x8*)(src_l + q * 8);
        }
      }
    }
    __syncthreads();
    int rowa = wi * 16 + lr;
    int ai = rowa * 32 + swzq(rowa, lq) * 8;
    s16x8 ah = *(const s16x8*)&Ah[ai];
    s16x8 alv = *(const s16x8*)&Al[ai];
    #pragma unroll
    for (int nf = 0; nf < 10; ++nf) {
      int rn = wn * 160 + nf * 16 + lr;
      int bi = rn * 32 + swzq(rn, lq) * 8;
      s16x8 bhv = *(const s16x8*)&Bh[bi];
      s16x8 blv = *(const s16x8*)&Bl[bi];
      acc[nf] = mfma3(ah, alv, bhv, blv, acc[nf]);
    }
    __syncthreads();
  }
  float pt[4] = {0.f, 0.f, 0.f, 0.f};
  #pragma unroll
  for (int nf = 0; nf < 10; ++nf) {
    int c = wn * 160 + nf * 16 + lr;
    bool val = c < 300;
    float sb = val ? sage_b[c] : 0.f;
    float hwv = val ? headW[c] : 0.f;
    #pragma unroll
    for (int t = 0; t < 4; ++t) {
      float gvv = acc[nf][t] + sb;
      acc[nf][t] = gvv;
      pt[t] += gvv * hwv;
    }
  }
  #pragma unroll
  for (int t = 0; t < 4; ++t) {
    #pragma unroll
    for (int mm = 1; mm < 16; mm <<= 1) pt[t] += __shfl_xor(pt[t], mm, 64);
  }
  if (lr == 0) {
    #pragma unroll
    for (int t = 0; t < 4; ++t) hwred[wn][wi * 16 + 4 * lq + t] = pt[t];
  }
  __syncthreads();
  if (tid < 32) wgts[tid] = sigm(hwred[0][tid] + hwred[1][tid] + hb);
  __syncthreads();
  #pragma unroll
  for (int nf = 0; nf < 10; ++nf) {
    int c = wn * 160 + nf * 16 + lr;
    if (c < 300) {
      #pragma unroll
      for (int t = 0; t < 4; ++t) {
        int r = wi * 16 + 4 * lq + t;
        size_t o = ((size_t)(m0 + r)) * 300 + c;
        out[o] = out[o] + wgts[r] * acc[nf][t];
      }
    }
  }
}

// ---------------- WeightAndSum pool
__global__ __launch_bounds__(256) void pool_kernel(
    const float* __restrict__ h, const float* __restrict__ poolW,
    const float* __restrict__ pool_b, float* __restrict__ gvec) {
  __shared__ float ws_[128];
  int g = blockIdx.x, tid = threadIdx.x, ii = tid >> 6, lane = tid & 63;
  const float* hg = h + (size_t)g * LLN * DDIM;
  float pb = pool_b[0];
  for (int m = 0; m < 32; ++m) {
    int l = ii * 32 + m;
    float p = 0.f;
    for (int d = lane; d < DDIM; d += 64) p += hg[l * DDIM + d] * poolW[d];
    p = wsum(p);
    if (lane == 0) ws_[l] = 1.f / (1.f + __expf(-(p + pb)));
  }
  __syncthreads();
  for (int d = tid; d < DDIM; d += 256) {
    float acc = 0.f;
    for (int l = 0; l < 128; ++l) acc += hg[l * DDIM + d] * ws_[l];
    gvec[(size_t)g * DDIM + d] = acc;
  }
}

// ---------------- pearson
__global__ __launch_bounds__(64) void pearson_kernel(
    const float* __restrict__ gvec, float* __restrict__ out) {
  int b = blockIdx.x, lane = threadIdx.x;
  const float* g1 = gvec + (size_t)b * DDIM;
  const float* g2 = gvec + (size_t)(64 + b) * DDIM;
  float v1[5], v2[5];
  float s1 = 0.f, s2 = 0.f;
  #pragma unroll
  for (int q = 0; q < 5; ++q) {
    int d = lane + 64 * q;
    v1[q] = (d < DDIM) ? g1[d] : 0.f;
    v2[q] = (d < DDIM) ? g2[d] : 0.f;
    s1 += v1[q]; s2 += v2[q];
  }
  s1 = wsum(s1); s2 = wsum(s2);
  float m1 = s1 / 300.f, m2 = s2 / 300.f;
  float a = 0.f, bb = 0.f, c = 0.f;
  #pragma unroll
  for (int q = 0; q < 5; ++q) {
    int d = lane + 64 * q;
    if (d < DDIM) {
      float x = v1[q] - m1, y = v2[q] - m2;
      a += x * y; bb += x * x; c += y * y;
    }
  }
  a = wsum(a); bb = wsum(bb); c = wsum(c);
  if (lane == 0) out[b] = 5.f * a / (sqrtf(bb) * sqrtf(c));
}

extern "C" void kernel_launch(void* const* d_in, const int* in_sizes, int n_in,
                              void* d_out, int out_size, void* d_ws, size_t ws_size,
                              hipStream_t stream) {
  (void)in_sizes; (void)n_in; (void)out_size; (void)ws_size;
  const float* emb   = (const float*)d_in[0];
  const float* simw1 = (const float*)d_in[1];
  const float* simw2 = (const float*)d_in[2];
  const float* LP[2][8];
  for (int l = 0; l < 2; ++l)
    for (int p = 0; p < 8; ++p) LP[l][p] = (const float*)d_in[3 + l * 8 + p];
  const float* poolW  = (const float*)d_in[19];
  const float* pool_b = (const float*)d_in[20];
  const int* s1 = (const int*)d_in[21];
  const int* s2 = (const int*)d_in[22];
  float* out = (float*)d_out;

  char* ws = (char*)d_ws;
  float* hA  = (float*)(ws + 0);                         // 19,660,800
  float* hB  = (float*)(ws + 19660800);                  // 19,660,800
  unsigned short* zTh = (unsigned short*)(ws + 39321600);   // 39,321,600
  unsigned short* zTl = (unsigned short*)(ws + 78643200);   // 39,321,600
  unsigned short* nh = (unsigned short*)(ws + 39321600); // alias zTh
  unsigned short* nl = (unsigned short*)(ws + 78643200); // alias zTl
  unsigned char* Agat = (unsigned char*)(ws + 117964800); // 2,097,152
  unsigned char* Asag = (unsigned char*)(ws + 120061952); // 2,097,152
  float* elb  = (float*)(ws + 122159104);                // 262,144
  float* erb  = (float*)(ws + 122421248);                // 262,144
  unsigned short* zb16 = (unsigned short*)(ws + 122683392); // 64 B zero region
  unsigned short* sWTh = (unsigned short*)(ws + 123273216); // 204,800
  unsigned short* sWTl = (unsigned short*)(ws + 123478016); // 204,800
  float* gv   = (float*)(ws + 123682816);                // 153,600
  unsigned short* hsplL = (unsigned short*)(ws + 123836416); // 10,485,760 -> ends 134,322,176

  hipMemsetAsync(zb16, 0, 64, stream);   // zero pad source for gld16 tail rows
  gather_kernel<<<GG * LLN, 256, 0, stream>>>(emb, s1, s2, hA);

  float* hin = hA; float* hout = hB;
  for (int l = 0; l < 2; ++l) {
    // split images + weight tiles + el/er partials live in the (currently dead) hout region;
    // all consumed (zmm, elr_lite) before gat_fuse writes hout.
    unsigned short* hsplH = (unsigned short*)hout;                        // 10,485,760
    unsigned short* gWTtH = (unsigned short*)((char*)hout + 10485760);    //    819,200
    unsigned short* gWTtL = (unsigned short*)((char*)hout + 11304960);    //    819,200
    float*          partb = (float*)((char*)hout + 12124160);             //  3,145,728

    adjmm_kernel<<<256, 256, 0, stream>>>(hin, simw1, simw2, Agat, Asag, hsplH, hsplL);
    prepw_kernel<<<2000, 256, 0, stream>>>(LP[l][0], LP[l][4], gWTtH, gWTtL, sWTh, sWTl);
    zmm_mfma<<<1280, 256, 0, stream>>>(hsplH, hsplL, gWTtH, gWTtL,
                                       LP[l][1], LP[l][2], zTh, zTl, partb);
    elr_lite<<<GG, 256, 0, stream>>>(partb, elb, erb);
    gat_fuse<<<512, 256, 0, stream>>>(hin, Agat, zTh, zTl, elb, erb,
        LP[l][3], LP[l][6], LP[l][7], zb16, hout);
    neigh_kernel<<<1024, 256, 0, stream>>>(hin, Asag, nh, nl);
    sage_fuse<<<512, 256, 0, stream>>>(nh, nl, sWTh, sWTl, LP[l][5], LP[l][6], LP[l][7], hout);
    float* t = hin; hin = hout; hout = t;
  }

  pool_kernel<<<GG, 256, 0, stream>>>(hin, poolW, pool_b, gv);
  pearson_kernel<<<64, 64, 0, stream>>>(gv, out);
}

// Round 9
// 643.908 us; speedup vs baseline: 1.1941x; 1.0534x over previous
//
#include <hip/hip_runtime.h>
#include <hip/hip_bf16.h>

#define GG 128   // graphs total (2 branches x 64)
#define LLN 128
#define DDIM 300
#define NH 4

typedef float4 f4;
typedef __attribute__((ext_vector_type(4))) float f32x4;
typedef __attribute__((ext_vector_type(8))) short s16x8;

__device__ __forceinline__ float wsum(float v) {
  #pragma unroll
  for (int o = 32; o > 0; o >>= 1) v += __shfl_xor(v, o, 64);
  return v;
}
__device__ __forceinline__ float wmax(float v) {
  #pragma unroll
  for (int o = 32; o > 0; o >>= 1) v = fmaxf(v, __shfl_xor(v, o, 64));
  return v;
}
__device__ __forceinline__ f4 add4(f4 a, f4 b) {
  return make_float4(a.x+b.x, a.y+b.y, a.z+b.z, a.w+b.w);
}
__device__ __forceinline__ f4 scale4(f4 a, float s) {
  return make_float4(a.x*s, a.y*s, a.z*s, a.w*s);
}
#define FMA4(acc, v, s) { (acc).x += (s)*(v).x; (acc).y += (s)*(v).y; (acc).z += (s)*(v).z; (acc).w += (s)*(v).w; }

__device__ __forceinline__ unsigned short f2bf(float x) {
  unsigned int u = __float_as_uint(x);
  return (unsigned short)((u + 0x7fffu + ((u >> 16) & 1u)) >> 16);
}
__device__ __forceinline__ float bf2f(unsigned short b) {
  return __uint_as_float(((unsigned int)b) << 16);
}
__device__ __forceinline__ int swzq(int row, int q) { return q ^ ((row >> 1) & 3); }
__device__ __forceinline__ float sigm(float x) { return 1.f / (1.f + __expf(-x)); }

__device__ __forceinline__ f32x4 mfma3(s16x8 ah, s16x8 al, s16x8 bh, s16x8 bl, f32x4 c) {
  c = __builtin_amdgcn_mfma_f32_16x16x32_bf16(ah, bh, c, 0, 0, 0);
  c = __builtin_amdgcn_mfma_f32_16x16x32_bf16(ah, bl, c, 0, 0, 0);
  c = __builtin_amdgcn_mfma_f32_16x16x32_bf16(al, bh, c, 0, 0, 0);
  return c;
}
__device__ __forceinline__ f32x4 mfma4(s16x8 ah, s16x8 al, s16x8 bh, s16x8 bl, f32x4 c) {
  c = __builtin_amdgcn_mfma_f32_16x16x32_bf16(ah, bh, c, 0, 0, 0);
  c = __builtin_amdgcn_mfma_f32_16x16x32_bf16(ah, bl, c, 0, 0, 0);
  c = __builtin_amdgcn_mfma_f32_16x16x32_bf16(al, bh, c, 0, 0, 0);
  c = __builtin_amdgcn_mfma_f32_16x16x32_bf16(al, bl, c, 0, 0, 0);
  return c;
}

__device__ __forceinline__ void gld16(const void* g, void* l) {
  __builtin_amdgcn_global_load_lds(
      (const __attribute__((address_space(1))) void*)g,
      (__attribute__((address_space(3))) void*)l, 16, 0, 0);
}

__device__ __forceinline__ void xcd_decode8(int id, int& g, int& it) {
  int x = id & 7, t = id >> 3;
  it = t & 7; g = x + 8 * (t >> 3);
}

// ---------------- embedding gather
__global__ __launch_bounds__(256) void gather_kernel(
    const float* __restrict__ emb, const int* __restrict__ s1,
    const int* __restrict__ s2, float* __restrict__ h) {
  int gl = blockIdx.x;
  int g = gl >> 7, l = gl & 127;
  const int* s = (g >= 64) ? s2 : s1;
  int tok = s[l * 64 + (g & 63)];
  const float* src = emb + (size_t)tok * DDIM;
  float* dst = h + (size_t)gl * DDIM;
  for (int d = threadIdx.x; d < DDIM; d += 256) dst[d] = src[d];
}

// ---------------- adjmm: both adjacencies via 4-term split-bf16 MFMA (V.V^T, symmetric)
// u==0 blocks additionally emit the raw-h split tile images (fused hsplit).
__global__ __launch_bounds__(256) void adjmm_kernel(
    const float* __restrict__ h, const float* __restrict__ simw1,
    const float* __restrict__ simw2, unsigned char* __restrict__ Agat,
    unsigned char* __restrict__ Asag,
    unsigned short* __restrict__ hh, unsigned short* __restrict__ hl) {
  __shared__ __align__(16) unsigned short Vh[128 * 32], Vl[128 * 32];
  __shared__ float wv[320];
  int x = blockIdx.x & 7, t = blockIdx.x >> 3;
  int u = t & 1, g = x + 8 * (t >> 1);
  const float* w = u ? simw1 : simw2;
  unsigned char* A = (u ? Asag : Agat) + (size_t)g * LLN * LLN;
  int tid = threadIdx.x, wid = tid >> 6, lane = tid & 63;
  int lq = lane >> 4, lr = lane & 15;
  for (int k = tid; k < 320; k += 256) wv[k] = (k < 300) ? w[k] : 0.f;
  f32x4 acc[2][8];
  #pragma unroll
  for (int fr = 0; fr < 2; ++fr)
    #pragma unroll
    for (int nf = 0; nf < 8; ++nf) acc[fr][nf] = (f32x4){0.f, 0.f, 0.f, 0.f};
  const float* hg = h + (size_t)g * LLN * DDIM;

  for (int kc = 0; kc < 10; ++kc) {
    __syncthreads();
    {
      int m = tid >> 1, halfk = tid & 1;
      int kb = kc * 32 + halfk * 16;
      const float* hp = hg + (size_t)m * DDIM;
      float v[16];
      if (kb + 15 < 300) {
        f4 x0 = *(const f4*)(hp + kb);
        f4 x1 = *(const f4*)(hp + kb + 4);
        f4 x2 = *(const f4*)(hp + kb + 8);
        f4 x3 = *(const f4*)(hp + kb + 12);
        v[0]=x0.x; v[1]=x0.y; v[2]=x0.z; v[3]=x0.w;
        v[4]=x1.x; v[5]=x1.y; v[6]=x1.z; v[7]=x1.w;
        v[8]=x2.x; v[9]=x2.y; v[10]=x2.z; v[11]=x2.w;
        v[12]=x3.x; v[13]=x3.y; v[14]=x3.z; v[15]=x3.w;
      } else {
        #pragma unroll
        for (int e = 0; e < 16; ++e) { int k = kb + e; v[e] = (k < 300) ? hp[k] : 0.f; }
      }
      // fused hsplit: raw-h split images (u==0 writer only)
      if (u == 0) {
        unsigned short* oh = hh + (size_t)(g * 10 + kc) * 4096;
        unsigned short* ol = hl + (size_t)(g * 10 + kc) * 4096;
        #pragma unroll
        for (int g4 = 0; g4 < 4; ++g4) {
          int klocal = halfk * 16 + g4 * 4;
          int q = klocal >> 3, wb = klocal & 7;
          int idx = m * 32 + swzq(m, q) * 8 + wb;
          ushort4 hv, lv;
          hv.x = f2bf(v[g4*4+0]); lv.x = f2bf(v[g4*4+0] - bf2f(hv.x));
          hv.y = f2bf(v[g4*4+1]); lv.y = f2bf(v[g4*4+1] - bf2f(hv.y));
          hv.z = f2bf(v[g4*4+2]); lv.z = f2bf(v[g4*4+2] - bf2f(hv.z));
          hv.w = f2bf(v[g4*4+3]); lv.w = f2bf(v[g4*4+3] - bf2f(hv.w));
          *(ushort4*)&oh[idx] = hv;
          *(ushort4*)&ol[idx] = lv;
        }
      }
      #pragma unroll
      for (int e = 0; e < 16; ++e) v[e] = fmaxf(v[e] * wv[kb + e], 0.f);
      #pragma unroll
      for (int g4 = 0; g4 < 4; ++g4) {
        int klocal = halfk * 16 + g4 * 4;
        int q = klocal >> 3, wb = klocal & 7;
        int idx = m * 32 + swzq(m, q) * 8 + wb;
        ushort4 hv, lv;
        hv.x = f2bf(v[g4*4+0]); lv.x = f2bf(v[g4*4+0] - bf2f(hv.x));
        hv.y = f2bf(v[g4*4+1]); lv.y = f2bf(v[g4*4+1] - bf2f(hv.y));
        hv.z = f2bf(v[g4*4+2]); lv.z = f2bf(v[g4*4+2] - bf2f(hv.z));
        hv.w = f2bf(v[g4*4+3]); lv.w = f2bf(v[g4*4+3] - bf2f(hv.w));
        *(ushort4*)&Vh[idx] = hv;
        *(ushort4*)&Vl[idx] = lv;
      }
    }
    __syncthreads();
    #pragma unroll
    for (int fr = 0; fr < 2; ++fr) {
      int ra = wid * 32 + fr * 16 + lr;
      int ai = ra * 32 + swzq(ra, lq) * 8;
      s16x8 ah = *(const s16x8*)&Vh[ai];
      s16x8 al = *(const s16x8*)&Vl[ai];
      #pragma unroll
      for (int nf = 0; nf < 8; ++nf) {
        int rb = nf * 16 + lr;
        int bi = rb * 32 + swzq(rb, lq) * 8;
        s16x8 bh = *(const s16x8*)&Vh[bi];
        s16x8 bl = *(const s16x8*)&Vl[bi];
        acc[fr][nf] = mfma4(ah, al, bh, bl, acc[fr][nf]);
      }
    }
  }
  __syncthreads();
  unsigned char* Au8 = (unsigned char*)Vh;   // 16 KB reuse (Vh+Vl)
  #pragma unroll
  for (int fr = 0; fr < 2; ++fr) {
    #pragma unroll
    for (int nf = 0; nf < 8; ++nf) {
      int j = nf * 16 + lr;
      #pragma unroll
      for (int t2 = 0; t2 < 4; ++t2) {
        int i = wid * 32 + fr * 16 + 4 * lq + t2;
        Au8[i * 128 + j] = (acc[fr][nf][t2] >= 0.1f || i == j) ? 1 : 0;
      }
    }
  }
  __syncthreads();
  for (int c = tid; c < 1024; c += 256) {
    int r = c >> 3, q = c & 7;
    uint4 val = *(const uint4*)&Au8[r * 128 + q * 16];
    *(uint4*)&A[(size_t)r * 128 + q * 16] = val;
  }
}

// ---------------- prepW: gatW -> split bf16 tile images; sageW -> row-major split
__global__ __launch_bounds__(256) void prepw_kernel(
    const float* __restrict__ gatW, const float* __restrict__ sageW,
    unsigned short* __restrict__ gWTtH, unsigned short* __restrict__ gWTtL,
    unsigned short* __restrict__ sWTh, unsigned short* __restrict__ sWTl) {
  int idx = blockIdx.x * 256 + threadIdx.x;
  if (idx < 1280 * 320) {
    int n = idx / 320, katt = idx - (idx / 320) * 320;
    int nt = n >> 7, nl = n & 127;
    int kc = katt >> 5, klocal = katt & 31;
    int q = klocal >> 3, wb = klocal & 7;
    size_t pos = ((size_t)(nt * 10 + kc) * 128 + nl) * 32 + swzq(nl, q) * 8 + wb;
    float v = (n < 1200 && katt < 300) ? gatW[(size_t)katt * 1200 + n] : 0.f;
    unsigned short hv = f2bf(v);
    gWTtH[pos] = hv;
    gWTtL[pos] = f2bf(v - bf2f(hv));
  } else if (idx < 1280 * 320 + 320 * 320) {
    int i2 = idx - 1280 * 320;
    int n = i2 / 320, k = i2 % 320;
    float v = (n < 300 && k < 300) ? sageW[(size_t)k * 300 + n] : 0.f;
    unsigned short hv = f2bf(v);
    sWTh[i2] = hv;
    sWTl[i2] = f2bf(v - bf2f(hv));
  }
}

// ---------------- zmm: z = h @ gatW via split-bf16 MFMA; gld16 staging from tile images.
// el/er partials -> unique slots (deterministic). z stored as single bf16 (hi only).
__global__ __launch_bounds__(256) void zmm_mfma(
    const unsigned short* __restrict__ hsplH, const unsigned short* __restrict__ hsplL,
    const unsigned short* __restrict__ gWTtH, const unsigned short* __restrict__ gWTtL,
    const float* __restrict__ attn_l, const float* __restrict__ attn_r,
    unsigned short* __restrict__ zTh, float* __restrict__ part) {
  __shared__ __align__(16) unsigned short smem[128 * 136];   // 34816 B
  unsigned short* Ah = smem;
  unsigned short* Al = smem + 4096;
  unsigned short* Bh = smem + 8192;
  unsigned short* Bl = smem + 12288;
  int x = blockIdx.x & 7, tb = blockIdx.x >> 3;
  int gi = tb / 10, nt = tb - gi * 10;
  int g = x + 8 * gi;
  int n0 = nt * 128;
  int tid = threadIdx.x, w = tid >> 6, lane = tid & 63;
  int lq = lane >> 4, lr = lane & 15, wr = w >> 1, wc = w & 1;
  f32x4 acc[4][4];
  #pragma unroll
  for (int a = 0; a < 4; ++a)
    #pragma unroll
    for (int b = 0; b < 4; ++b) acc[a][b] = (f32x4){0.f, 0.f, 0.f, 0.f};

  for (int kc = 0; kc < 10; ++kc) {
    {
      const unsigned short* ah_g = hsplH + (size_t)(g * 10 + kc) * 4096;
      const unsigned short* al_g = hsplL + (size_t)(g * 10 + kc) * 4096;
      const unsigned short* bh_g = gWTtH + (size_t)(nt * 10 + kc) * 4096;
      const unsigned short* bl_g = gWTtL + (size_t)(nt * 10 + kc) * 4096;
      int o = tid * 8;
      gld16(ah_g + o, Ah + o); gld16(ah_g + o + 2048, Ah + o + 2048);
      gld16(al_g + o, Al + o); gld16(al_g + o + 2048, Al + o + 2048);
      gld16(bh_g + o, Bh + o); gld16(bh_g + o + 2048, Bh + o + 2048);
      gld16(bl_g + o, Bl + o); gld16(bl_g + o + 2048, Bl + o + 2048);
    }
    __syncthreads();   // drains vmcnt (global_load_lds) before reads
    s16x8 ah[4], alo[4];
    #pragma unroll
    for (int mf = 0; mf < 4; ++mf) {
      int row = wr * 64 + mf * 16 + lr;
      int ai = row * 32 + swzq(row, lq) * 8;
      ah[mf] = *(const s16x8*)&Ah[ai];
      alo[mf] = *(const s16x8*)&Al[ai];
    }
    #pragma unroll
    for (int nf = 0; nf < 4; ++nf) {
      int rn = wc * 64 + nf * 16 + lr;
      int bi = rn * 32 + swzq(rn, lq) * 8;
      s16x8 bhv = *(const s16x8*)&Bh[bi];
      s16x8 blv = *(const s16x8*)&Bl[bi];
      #pragma unroll
      for (int mf = 0; mf < 4; ++mf)
        acc[mf][nf] = mfma3(ah[mf], alo[mf], bhv, blv, acc[mf][nf]);
    }
    __syncthreads();
  }

  // ---- el/er partial dots -> unique (g, head, slot) slots; no atomics ----
  {
    int cbase = n0 + wc * 64;
    if (cbase < 1200) {
      int b = cbase >> 6;                 // band 0..18
      int h_base = cbase / 300;
      int fb = (h_base == 0) ? 0 : (h_base == 1) ? 5 : (h_base == 2) ? 10 : 15;
      int slot = b - fb + 1;              // 1..5
      int h_last = (cbase + 63 < 1200 ? cbase + 63 : 1199) / 300;
      bool has_alt = (h_last != h_base);
      float aLv[4], aRv[4]; int alt[4];
      #pragma unroll
      for (int nf = 0; nf < 4; ++nf) {
        int cg = cbase + nf * 16 + lr;
        bool ok = cg < 1200;
        aLv[nf] = ok ? attn_l[cg] : 0.f;
        aRv[nf] = ok ? attn_r[cg] : 0.f;
        alt[nf] = (ok && (cg / 300) != h_base) ? 1 : 0;
      }
      float* p0 = part + (((size_t)(g * 4 + h_base) * 6 + slot) * 2) * 128;
      float* p1 = part + (((size_t)(g * 4 + h_base + 1) * 6 + 0) * 2) * 128;
      #pragma unroll
      for (int mf = 0; mf < 4; ++mf) {
        #pragma unroll
        for (int t2 = 0; t2 < 4; ++t2) {
          float s0l = 0.f, s0r = 0.f, s1l = 0.f, s1r = 0.f;
          #pragma unroll
          for (int nf = 0; nf < 4; ++nf) {
            float v = acc[mf][nf][t2];
            float cl = v * aLv[nf], cr = v * aRv[nf];
            s0l += alt[nf] ? 0.f : cl; s1l += alt[nf] ? cl : 0.f;
            s0r += alt[nf] ? 0.f : cr; s1r += alt[nf] ? cr : 0.f;
          }
          #pragma unroll
          for (int mm = 1; mm < 16; mm <<= 1) {
            s0l += __shfl_xor(s0l, mm, 64);
            s0r += __shfl_xor(s0r, mm, 64);
          }
          if (has_alt) {
            #pragma unroll
            for (int mm = 1; mm < 16; mm <<= 1) {
              s1l += __shfl_xor(s1l, mm, 64);
              s1r += __shfl_xor(s1r, mm, 64);
            }
          }
          if (lr == 0) {
            int j = wr * 64 + mf * 16 + 4 * lq + t2;
            p0[j] = s0l; p0[128 + j] = s0r;
            if (has_alt) { p1[j] = s1l; p1[128 + j] = s1r; }
          }
        }
      }
    }
  }

  // ---- transposed coalesced zT store (hi only) ----
  __syncthreads();
  #pragma unroll
  for (int mf = 0; mf < 4; ++mf) {
    #pragma unroll
    for (int nf = 0; nf < 4; ++nf) {
      int cl = wc * 64 + nf * 16 + lr;
      int j0 = wr * 64 + mf * 16 + 4 * lq;
      f32x4 a = acc[mf][nf];
      ushort4 pv;
      pv.x = f2bf(a[0]); pv.y = f2bf(a[1]); pv.z = f2bf(a[2]); pv.w = f2bf(a[3]);
      *(ushort4*)&smem[cl * 136 + j0] = pv;
    }
  }
  __syncthreads();
  #pragma unroll
  for (int p = 0; p < 8; ++p) {
    int c = tid + p * 256;
    int r = c >> 4, q = c & 15;
    int cg = n0 + r;
    if (cg < 1200) {
      int head = cg / 300, d = cg - head * 300;
      uint4 val = *(const uint4*)&smem[r * 136 + q * 8];
      *(uint4*)(zTh + ((size_t)(g * 4 + head) * 300 + d) * 128 + q * 8) = val;
    }
  }
}

// ---------------- elr_lite: reduce el/er partials in fixed slot order (deterministic)
__global__ __launch_bounds__(256) void elr_lite(
    const float* __restrict__ part, float* __restrict__ el, float* __restrict__ er) {
  int g = blockIdx.x, tid = threadIdx.x;
  int j = tid & 127, side = tid >> 7;
  for (int s = 0; s < 4; ++s) {
    int s0 = (s == 0) ? 1 : 0;
    int s1e = (s == 3) ? 4 : 5;
    float v = 0.f;
    for (int sl = s0; sl <= s1e; ++sl)
      v += part[(((size_t)(g * 4 + s) * 6 + sl) * 2 + side) * 128 + j];
    float* dst = side ? er : el;
    dst[(size_t)(g * 4 + s) * 128 + j] = v;
  }
}

// ---------------- gat_fuse: fused mx/sinv + 4 GAT heads; P and z single-bf16 (1 MFMA/tile)
__global__ __launch_bounds__(256) void gat_fuse(
    const float* __restrict__ h, const unsigned char* __restrict__ Agat,
    const unsigned short* __restrict__ zTh,
    const float* __restrict__ el, const float* __restrict__ er,
    const float* __restrict__ gat_b, const float* __restrict__ headW,
    const float* __restrict__ head_b, const unsigned short* __restrict__ zerobuf,
    float* __restrict__ out) {
  __shared__ __align__(16) unsigned short Bh[320 * 32];
  __shared__ __align__(16) unsigned short Ah[32 * 32];
  __shared__ __align__(16) unsigned char Ag8[32 * 128];
  __shared__ __align__(16) float elsm[4 * 128];
  __shared__ __align__(16) float ersl[4 * 32];
  __shared__ __align__(16) float mxl[4 * 32];
  __shared__ __align__(16) float svl[4 * 32];
  __shared__ float hwred[2][32];
  __shared__ float wgts[32];
  int xb = blockIdx.x & 7, tb = blockIdx.x >> 3;
  int it = tb & 3, g = xb + 8 * (tb >> 2);
  int i0 = it * 32;
  int tid = threadIdx.x, w = tid >> 6, lane = tid & 63;
  int lq = lane >> 4, lr = lane & 15, wi = w & 1, wn = w >> 1;
  float hb = head_b[0];

  // ---- pre-pass: stage Agat tile + el/er; compute mx/sinv for own 32 rows ----
  {
    int r = tid >> 3, o = (tid & 7) * 16;
    *(uint4*)&Ag8[r * 128 + o] = *(const uint4*)(Agat + ((size_t)g * 128 + i0 + r) * 128 + o);
    elsm[tid] = el[(size_t)(g * 4) * 128 + tid];
    elsm[256 + tid] = el[(size_t)(g * 4) * 128 + 256 + tid];
    if (tid < 128) {
      int s = tid >> 5, r2 = tid & 31;
      ersl[tid] = er[(size_t)(g * 4 + s) * 128 + i0 + r2];
    }
  }
  __syncthreads();
  for (int s = 0; s < 4; ++s) {
    float el0 = elsm[s * 128 + lane], el1 = elsm[s * 128 + 64 + lane];
    for (int r = w; r < 32; r += 4) {
      int m0 = Ag8[r * 128 + lane], m1 = Ag8[r * 128 + 64 + lane];
      float eri = ersl[s * 32 + r];
      float e0 = eri + el0; e0 = e0 >= 0.f ? e0 : 0.2f * e0;
      float e1 = eri + el1; e1 = e1 >= 0.f ? e1 : 0.2f * e1;
      float x0 = m0 ? e0 : -3.0e38f;
      float x1 = m1 ? e1 : -3.0e38f;
      float m_ = wmax(fmaxf(x0, x1));
      float p0 = m0 ? __expf(e0 - m_) : 0.f;
      float p1 = m1 ? __expf(e1 - m_) : 0.f;
      float ssum = wsum(p0 + p1);
      if (lane == 0) { mxl[s * 32 + r] = m_; svl[s * 32 + r] = 1.f / ssum; }
    }
  }
  __syncthreads();

  float outacc[10][4];
  #pragma unroll
  for (int nf = 0; nf < 10; ++nf)
    #pragma unroll
    for (int t = 0; t < 4; ++t) outacc[nf][t] = 0.f;

  for (int s = 0; s < 4; ++s) {
    f32x4 acc[10];
    #pragma unroll
    for (int nf = 0; nf < 10; ++nf) acc[nf] = (f32x4){0.f, 0.f, 0.f, 0.f};
    const unsigned short* zsh = zTh + (size_t)(g * 4 + s) * 300 * 128;

    for (int kc = 0; kc < 4; ++kc) {
      int j0 = kc * 32;
      // A stage: p = mask ? exp(leaky(er_i+el_j) - mx_i) : 0 (hi only)
      {
        int m = tid >> 3, j4 = (tid & 7) * 4;
        float eri = ersl[s * 32 + m], mxi = mxl[s * 32 + m];
        const unsigned char* mrow = &Ag8[m * 128 + j0 + j4];
        uchar4 msk = *(const uchar4*)mrow;
        f4 elv = *(const f4*)&elsm[s * 128 + j0 + j4];
        float p[4];
        {
          float e = eri + elv.x; e = e >= 0.f ? e : 0.2f * e; p[0] = msk.x ? __expf(e - mxi) : 0.f;
          e = eri + elv.y; e = e >= 0.f ? e : 0.2f * e; p[1] = msk.y ? __expf(e - mxi) : 0.f;
          e = eri + elv.z; e = e >= 0.f ? e : 0.2f * e; p[2] = msk.z ? __expf(e - mxi) : 0.f;
          e = eri + elv.w; e = e >= 0.f ? e : 0.2f * e; p[3] = msk.w ? __expf(e - mxi) : 0.f;
        }
        int q = j4 >> 3, wb = j4 & 7;
        int idx = m * 32 + swzq(m, q) * 8 + wb;
        ushort4 hv;
        hv.x = f2bf(p[0]); hv.y = f2bf(p[1]); hv.z = f2bf(p[2]); hv.w = f2bf(p[3]);
        *(ushort4*)&Ah[idx] = hv;
      }
      // B stage: gld16 from pre-swizzled global source (z-hi only)
      {
        #pragma unroll
        for (int cc = 0; cc < 5; ++cc) {
          int chunk = w + cc * 4;            // 0..19
          int nb = chunk * 16;
          int n = nb + (lane >> 2);
          int q = (lane & 3) ^ ((n >> 1) & 3);
          const unsigned short* srcH = (n < 300) ? (zsh + (size_t)n * 128 + j0 + q * 8) : zerobuf;
          gld16(srcH, Bh + chunk * 512 + lane * 8);
        }
      }
      __syncthreads();
      int rowa = wi * 16 + lr;
      int ai = rowa * 32 + swzq(rowa, lq) * 8;
      s16x8 ah = *(const s16x8*)&Ah[ai];
      #pragma unroll
      for (int nf = 0; nf < 10; ++nf) {
        int rn = wn * 160 + nf * 16 + lr;
        int bi = rn * 32 + swzq(rn, lq) * 8;
        s16x8 bhv = *(const s16x8*)&Bh[bi];
        acc[nf] = __builtin_amdgcn_mfma_f32_16x16x32_bf16(ah, bhv, acc[nf], 0, 0, 0);
      }
      __syncthreads();
    }
    // epilogue for slot s
    f4 sv4 = *(const f4*)&svl[s * 32 + wi * 16 + 4 * lq];
    float svf[4] = {sv4.x, sv4.y, sv4.z, sv4.w};
    float pt[4] = {0.f, 0.f, 0.f, 0.f};
    #pragma unroll
    for (int nf = 0; nf < 10; ++nf) {
      int c = wn * 160 + nf * 16 + lr;
      bool val = c < 300;
      float gb = val ? gat_b[s * 300 + c] : 0.f;
      float hwv = val ? headW[c] : 0.f;
      #pragma unroll
      for (int t = 0; t < 4; ++t) {
        float gvv = acc[nf][t] * svf[t] + gb;
        acc[nf][t] = gvv;
        pt[t] += gvv * hwv;
      }
    }
    #pragma unroll
    for (int t = 0; t < 4; ++t) {
      #pragma unroll
      for (int mm = 1; mm < 16; mm <<= 1) pt[t] += __shfl_xor(pt[t], mm, 64);
    }
    if (lr == 0) {
      #pragma unroll
      for (int t = 0; t < 4; ++t) hwred[wn][wi * 16 + 4 * lq + t] = pt[t];
    }
    __syncthreads();
    if (tid < 32) wgts[tid] = sigm(hwred[0][tid] + hwred[1][tid] + hb);
    __syncthreads();
    #pragma unroll
    for (int nf = 0; nf < 10; ++nf) {
      #pragma unroll
      for (int t = 0; t < 4; ++t) {
        int r = wi * 16 + 4 * lq + t;
        outacc[nf][t] += wgts[r] * acc[nf][t];
      }
    }
    __syncthreads();
  }
  #pragma unroll
  for (int nf = 0; nf < 10; ++nf) {
    int c = wn * 160 + nf * 16 + lr;
    if (c < 300) {
      #pragma unroll
      for (int t = 0; t < 4; ++t) {
        int r = wi * 16 + 4 * lq + t;
        size_t o = ((size_t)(g * 128 + i0 + r)) * 300 + c;
        out[o] = h[o] + outacc[nf][t];
      }
    }
  }
}

// ---------------- neigh (fp32): n = (Asag@h + h)*dinv -> single bf16 (hi)
__global__ __launch_bounds__(256) void neigh_kernel(
    const float* __restrict__ h, const unsigned char* __restrict__ Asag,
    unsigned short* __restrict__ nh) {
  __shared__ float As[16][128];
  int g, it; xcd_decode8(blockIdx.x, g, it);
  int i0 = it * 16;
  int tid = threadIdx.x, ii = tid >> 6, lane = tid & 63;
  for (int idx = tid; idx < 16 * 128; idx += 256)
    As[idx >> 7][idx & 127] = (float)Asag[((size_t)g * 128 + i0 + (idx >> 7)) * 128 + (idx & 127)];
  __syncthreads();
  float dinv_r[4];
  #pragma unroll
  for (int r = 0; r < 4; ++r) {
    int row = ii * 4 + r;
    float s_ = As[row][lane] + As[row][64 + lane];
    s_ = wsum(s_);
    dinv_r[r] = 1.f / (s_ + 1.f);
  }
  int dq0 = lane, dq1 = lane + 64;
  bool ok1 = dq1 < 75;
  const f4 zero4 = make_float4(0.f, 0.f, 0.f, 0.f);
  const f4* h4 = (const f4*)(h + (size_t)g * LLN * DDIM);
  f4 acc0[4], acc1[4];
  #pragma unroll
  for (int r = 0; r < 4; ++r) { acc0[r] = zero4; acc1[r] = zero4; }
  for (int j = 0; j < 128; ++j) {
    float a0 = As[ii*4+0][j], a1 = As[ii*4+1][j], a2 = As[ii*4+2][j], a3 = As[ii*4+3][j];
    f4 hv0 = h4[j * 75 + dq0];
    f4 hv1 = ok1 ? h4[j * 75 + dq1] : zero4;
    FMA4(acc0[0], hv0, a0); FMA4(acc0[1], hv0, a1); FMA4(acc0[2], hv0, a2); FMA4(acc0[3], hv0, a3);
    FMA4(acc1[0], hv1, a0); FMA4(acc1[1], hv1, a1); FMA4(acc1[2], hv1, a2); FMA4(acc1[3], hv1, a3);
  }
  #pragma unroll
  for (int r = 0; r < 4; ++r) {
    int i = i0 + ii * 4 + r;
    float dv = dinv_r[r];
    f4 n0v = scale4(add4(acc0[r], h4[i * 75 + dq0]), dv);
    size_t base = (size_t)(g * 128 + i) * 320;
    ushort4 hv;
    hv.x = f2bf(n0v.x); hv.y = f2bf(n0v.y); hv.z = f2bf(n0v.z); hv.w = f2bf(n0v.w);
    *(ushort4*)&nh[base + dq0 * 4] = hv;
    if (ok1) {
      f4 n1v = scale4(add4(acc1[r], h4[i * 75 + dq1]), dv);
      hv.x = f2bf(n1v.x); hv.y = f2bf(n1v.y); hv.z = f2bf(n1v.z); hv.w = f2bf(n1v.w);
      *(ushort4*)&nh[base + dq1 * 4] = hv;
    }
    if (lane < 5) {
      ushort4 z4u = {0, 0, 0, 0};
      *(ushort4*)&nh[base + 300 + lane * 4] = z4u;
    }
  }
}

// ---------------- sage_fuse: sage = n(bf16) @ (Wh+Wl) + b; out += sigmoid(dot)*sage
__global__ __launch_bounds__(256) void sage_fuse(
    const unsigned short* __restrict__ nh,
    const unsigned short* __restrict__ sWTh, const unsigned short* __restrict__ sWTl,
    const float* __restrict__ sage_b, const float* __restrict__ headW,
    const float* __restrict__ head_b, float* __restrict__ out) {
  __shared__ __align__(16) unsigned short Bh[320 * 32], Bl[320 * 32];
  __shared__ __align__(16) unsigned short Ah[32 * 32];
  __shared__ float hwred[2][32];
  __shared__ float wgts[32];
  int m0 = blockIdx.x * 32;
  int tid = threadIdx.x, w = tid >> 6, lane = tid & 63;
  int lq = lane >> 4, lr = lane & 15, wi = w & 1, wn = w >> 1;
  float hb = head_b[0];
  f32x4 acc[10];
  #pragma unroll
  for (int nf = 0; nf < 10; ++nf) acc[nf] = (f32x4){0.f, 0.f, 0.f, 0.f};

  for (int kc = 0; kc < 10; ++kc) {
    if (tid < 128) {
      int rowm = tid >> 2, qq = tid & 3;
      int idx = rowm * 32 + swzq(rowm, qq) * 8;
      const unsigned short* src = nh + (size_t)(m0 + rowm) * 320 + kc * 32 + qq * 8;
      *(s16x8*)&Ah[idx] = *(const s16x8*)src;
    }
    {
      #pragma unroll
      for (int rep = 0; rep < 2; ++rep) {
        int n = rep == 0 ? tid : 256 + tid;
        if (rep == 1 && tid >= 64) break;
        const unsigned short* src_h = sWTh + (size_t)n * 320 + kc * 32;
        const unsigned short* src_l = sWTl + (size_t)n * 320 + kc * 32;
        #pragma unroll
        for (int q = 0; q < 4; ++q) {
          int idx = n * 32 + swzq(n, q) * 8;
          *(s16x8*)&Bh[idx] = *(const s16x8*)(src_h + q * 8);
          *(s16x8*)&Bl[idx] = *(const s16x8*)(src_l + q * 8);
        }
      }
    }
    __syncthreads();
    int rowa = wi * 16 + lr;
    int ai = rowa * 32 + swzq(rowa, lq) * 8;
    s16x8 ah = *(const s16x8*)&Ah[ai];
    #pragma unroll
    for (int nf = 0; nf < 10; ++nf) {
      int rn = wn * 160 + nf * 16 + lr;
      int bi = rn * 32 + swzq(rn, lq) * 8;
      s16x8 bhv = *(const s16x8*)&Bh[bi];
      s16x8 blv = *(const s16x8*)&Bl[bi];
      acc[nf] = __builtin_amdgcn_mfma_f32_16x16x32_bf16(ah, bhv, acc[nf], 0, 0, 0);
      acc[nf] = __builtin_amdgcn_mfma_f32_16x16x32_bf16(ah, blv, acc[nf], 0, 0, 0);
    }
    __syncthreads();
  }
  float pt[4] = {0.f, 0.f, 0.f, 0.f};
  #pragma unroll
  for (int nf = 0; nf < 10; ++nf) {
    int c = wn * 160 + nf * 16 + lr;
    bool val = c < 300;
    float sb = val ? sage_b[c] : 0.f;
    float hwv = val ? headW[c] : 0.f;
    #pragma unroll
    for (int t = 0; t < 4; ++t) {
      float gvv = acc[nf][t] + sb;
      acc[nf][t] = gvv;
      pt[t] += gvv * hwv;
    }
  }
  #pragma unroll
  for (int t = 0; t < 4; ++t) {
    #pragma unroll
    for (int mm = 1; mm < 16; mm <<= 1) pt[t] += __shfl_xor(pt[t], mm, 64);
  }
  if (lr == 0) {
    #pragma unroll
    for (int t = 0; t < 4; ++t) hwred[wn][wi * 16 + 4 * lq + t] = pt[t];
  }
  __syncthreads();
  if (tid < 32) wgts[tid] = sigm(hwred[0][tid] + hwred[1][tid] + hb);
  __syncthreads();
  #pragma unroll
  for (int nf = 0; nf < 10; ++nf) {
    int c = wn * 160 + nf * 16 + lr;
    if (c < 300) {
      #pragma unroll
      for (int t = 0; t < 4; ++t) {
        int r = wi * 16 + 4 * lq + t;
        size_t o = ((size_t)(m0 + r)) * 300 + c;
        out[o] = out[o] + wgts[r] * acc[nf][t];
      }
    }
  }
}

// ---------------- WeightAndSum pool
__global__ __launch_bounds__(256) void pool_kernel(
    const float* __restrict__ h, const float* __restrict__ poolW,
    const float* __restrict__ pool_b, float* __restrict__ gvec) {
  __shared__ float ws_[128];
  int g = blockIdx.x, tid = threadIdx.x, ii = tid >> 6, lane = tid & 63;
  const float* hg = h + (size_t)g * LLN * DDIM;
  float pb = pool_b[0];
  for (int m = 0; m < 32; ++m) {
    int l = ii * 32 + m;
    float p = 0.f;
    for (int d = lane; d < DDIM; d += 64) p += hg[l * DDIM + d] * poolW[d];
    p = wsum(p);
    if (lane == 0) ws_[l] = 1.f / (1.f + __expf(-(p + pb)));
  }
  __syncthreads();
  for (int d = tid; d < DDIM; d += 256) {
    float acc = 0.f;
    for (int l = 0; l < 128; ++l) acc += hg[l * DDIM + d] * ws_[l];
    gvec[(size_t)g * DDIM + d] = acc;
  }
}

// ---------------- pearson
__global__ __launch_bounds__(64) void pearson_kernel(
    const float* __restrict__ gvec, float* __restrict__ out) {
  int b = blockIdx.x, lane = threadIdx.x;
  const float* g1 = gvec + (size_t)b * DDIM;
  const float* g2 = gvec + (size_t)(64 + b) * DDIM;
  float v1[5], v2[5];
  float s1 = 0.f, s2 = 0.f;
  #pragma unroll
  for (int q = 0; q < 5; ++q) {
    int d = lane + 64 * q;
    v1[q] = (d < DDIM) ? g1[d] : 0.f;
    v2[q] = (d < DDIM) ? g2[d] : 0.f;
    s1 += v1[q]; s2 += v2[q];
  }
  s1 = wsum(s1); s2 = wsum(s2);
  float m1 = s1 / 300.f, m2 = s2 / 300.f;
  float a = 0.f, bb = 0.f, c = 0.f;
  #pragma unroll
  for (int q = 0; q < 5; ++q) {
    int d = lane + 64 * q;
    if (d < DDIM) {
      float x = v1[q] - m1, y = v2[q] - m2;
      a += x * y; bb += x * x; c += y * y;
    }
  }
  a = wsum(a); bb = wsum(bb); c = wsum(c);
  if (lane == 0) out[b] = 5.f * a / (sqrtf(bb) * sqrtf(c));
}

extern "C" void kernel_launch(void* const* d_in, const int* in_sizes, int n_in,
                              void* d_out, int out_size, void* d_ws, size_t ws_size,
                              hipStream_t stream) {
  (void)in_sizes; (void)n_in; (void)out_size; (void)ws_size;
  const float* emb   = (const float*)d_in[0];
  const float* simw1 = (const float*)d_in[1];
  const float* simw2 = (const float*)d_in[2];
  const float* LP[2][8];
  for (int l = 0; l < 2; ++l)
    for (int p = 0; p < 8; ++p) LP[l][p] = (const float*)d_in[3 + l * 8 + p];
  const float* poolW  = (const float*)d_in[19];
  const float* pool_b = (const float*)d_in[20];
  const int* s1 = (const int*)d_in[21];
  const int* s2 = (const int*)d_in[22];
  float* out = (float*)d_out;

  char* ws = (char*)d_ws;
  float* hA  = (float*)(ws + 0);                         // 19,660,800
  float* hB  = (float*)(ws + 19660800);                  // 19,660,800
  unsigned short* zTh = (unsigned short*)(ws + 39321600);   // 39,321,600
  unsigned short* nh = (unsigned short*)(ws + 39321600); // alias zTh (post-gat_fuse)
  unsigned char* Agat = (unsigned char*)(ws + 117964800); // 2,097,152
  unsigned char* Asag = (unsigned char*)(ws + 120061952); // 2,097,152
  float* elb  = (float*)(ws + 122159104);                // 262,144
  float* erb  = (float*)(ws + 122421248);                // 262,144
  unsigned short* zb16 = (unsigned short*)(ws + 122683392); // 64 B zero region
  unsigned short* sWTh = (unsigned short*)(ws + 123273216); // 204,800
  unsigned short* sWTl = (unsigned short*)(ws + 123478016); // 204,800
  float* gv   = (float*)(ws + 123682816);                // 153,600
  unsigned short* hsplL = (unsigned short*)(ws + 123836416); // 10,485,760 -> ends 134,322,176

  hipMemsetAsync(zb16, 0, 64, stream);   // zero pad source for gld16 tail rows
  gather_kernel<<<GG * LLN, 256, 0, stream>>>(emb, s1, s2, hA);

  float* hin = hA; float* hout = hB;
  for (int l = 0; l < 2; ++l) {
    // split images + weight tiles + el/er partials live in the (currently dead) hout region;
    // all consumed (zmm, elr_lite) before gat_fuse writes hout.
    unsigned short* hsplH = (unsigned short*)hout;                        // 10,485,760
    unsigned short* gWTtH = (unsigned short*)((char*)hout + 10485760);    //    819,200
    unsigned short* gWTtL = (unsigned short*)((char*)hout + 11304960);    //    819,200
    float*          partb = (float*)((char*)hout + 12124160);             //  3,145,728

    adjmm_kernel<<<256, 256, 0, stream>>>(hin, simw1, simw2, Agat, Asag, hsplH, hsplL);
    prepw_kernel<<<2000, 256, 0, stream>>>(LP[l][0], LP[l][4], gWTtH, gWTtL, sWTh, sWTl);
    zmm_mfma<<<1280, 256, 0, stream>>>(hsplH, hsplL, gWTtH, gWTtL,
                                       LP[l][1], LP[l][2], zTh, partb);
    elr_lite<<<GG, 256, 0, stream>>>(partb, elb, erb);
    gat_fuse<<<512, 256, 0, stream>>>(hin, Agat, zTh, elb, erb,
        LP[l][3], LP[l][6], LP[l][7], zb16, hout);
    neigh_kernel<<<1024, 256, 0, stream>>>(hin, Asag, nh);
    sage_fuse<<<512, 256, 0, stream>>>(nh, sWTh, sWTl, LP[l][5], LP[l][6], LP[l][7], hout);
    float* t = hin; hin = hout; hout = t;
  }

  pool_kernel<<<GG, 256, 0, stream>>>(hin, poolW, pool_b, gv);
  pearson_kernel<<<64, 64, 0, stream>>>(gv, out);
}

// Round 10
// 558.426 us; speedup vs baseline: 1.3769x; 1.1531x over previous
//
#include <hip/hip_runtime.h>
#include <hip/hip_bf16.h>

#define GG 128   // graphs total (2 branches x 64)
#define LLN 128
#define DDIM 300
#define NH 4

typedef float4 f4;
typedef __attribute__((ext_vector_type(4))) float f32x4;
typedef __attribute__((ext_vector_type(8))) short s16x8;

__device__ __forceinline__ float wsum(float v) {
  #pragma unroll
  for (int o = 32; o > 0; o >>= 1) v += __shfl_xor(v, o, 64);
  return v;
}
__device__ __forceinline__ float wmax(float v) {
  #pragma unroll
  for (int o = 32; o > 0; o >>= 1) v = fmaxf(v, __shfl_xor(v, o, 64));
  return v;
}
__device__ __forceinline__ f4 add4(f4 a, f4 b) {
  return make_float4(a.x+b.x, a.y+b.y, a.z+b.z, a.w+b.w);
}
__device__ __forceinline__ f4 scale4(f4 a, float s) {
  return make_float4(a.x*s, a.y*s, a.z*s, a.w*s);
}
#define FMA4(acc, v, s) { (acc).x += (s)*(v).x; (acc).y += (s)*(v).y; (acc).z += (s)*(v).z; (acc).w += (s)*(v).w; }

__device__ __forceinline__ unsigned short f2bf(float x) {
  unsigned int u = __float_as_uint(x);
  return (unsigned short)((u + 0x7fffu + ((u >> 16) & 1u)) >> 16);
}
__device__ __forceinline__ float bf2f(unsigned short b) {
  return __uint_as_float(((unsigned int)b) << 16);
}
__device__ __forceinline__ int swzq(int row, int q) { return q ^ ((row >> 1) & 3); }
__device__ __forceinline__ float sigm(float x) { return 1.f / (1.f + __expf(-x)); }

__device__ __forceinline__ f32x4 mfma4(s16x8 ah, s16x8 al, s16x8 bh, s16x8 bl, f32x4 c) {
  c = __builtin_amdgcn_mfma_f32_16x16x32_bf16(ah, bh, c, 0, 0, 0);
  c = __builtin_amdgcn_mfma_f32_16x16x32_bf16(ah, bl, c, 0, 0, 0);
  c = __builtin_amdgcn_mfma_f32_16x16x32_bf16(al, bh, c, 0, 0, 0);
  c = __builtin_amdgcn_mfma_f32_16x16x32_bf16(al, bl, c, 0, 0, 0);
  return c;
}

__device__ __forceinline__ void gld16(const void* g, void* l) {
  __builtin_amdgcn_global_load_lds(
      (const __attribute__((address_space(1))) void*)g,
      (__attribute__((address_space(3))) void*)l, 16, 0, 0);
}

__device__ __forceinline__ void xcd_decode8(int id, int& g, int& it) {
  int x = id & 7, t = id >> 3;
  it = t & 7; g = x + 8 * (t >> 3);
}

// ---------------- embedding gather
__global__ __launch_bounds__(256) void gather_kernel(
    const float* __restrict__ emb, const int* __restrict__ s1,
    const int* __restrict__ s2, float* __restrict__ h) {
  int gl = blockIdx.x;
  int g = gl >> 7, l = gl & 127;
  const int* s = (g >= 64) ? s2 : s1;
  int tok = s[l * 64 + (g & 63)];
  const float* src = emb + (size_t)tok * DDIM;
  float* dst = h + (size_t)gl * DDIM;
  for (int d = threadIdx.x; d < DDIM; d += 256) dst[d] = src[d];
}

// ---------------- adjmm: both adjacencies via 4-term split-bf16 MFMA (V.V^T, symmetric)
// u==0 blocks additionally emit the raw-h bf16-hi tile image (fused hsplit).
// Adjacency stays full-split: the >=0.1 threshold is the discrete hazard.
__global__ __launch_bounds__(256) void adjmm_kernel(
    const float* __restrict__ h, const float* __restrict__ simw1,
    const float* __restrict__ simw2, unsigned char* __restrict__ Agat,
    unsigned char* __restrict__ Asag, unsigned short* __restrict__ hh) {
  __shared__ __align__(16) unsigned short Vh[128 * 32], Vl[128 * 32];
  __shared__ float wv[320];
  int x = blockIdx.x & 7, t = blockIdx.x >> 3;
  int u = t & 1, g = x + 8 * (t >> 1);
  const float* w = u ? simw1 : simw2;
  unsigned char* A = (u ? Asag : Agat) + (size_t)g * LLN * LLN;
  int tid = threadIdx.x, wid = tid >> 6, lane = tid & 63;
  int lq = lane >> 4, lr = lane & 15;
  for (int k = tid; k < 320; k += 256) wv[k] = (k < 300) ? w[k] : 0.f;
  f32x4 acc[2][8];
  #pragma unroll
  for (int fr = 0; fr < 2; ++fr)
    #pragma unroll
    for (int nf = 0; nf < 8; ++nf) acc[fr][nf] = (f32x4){0.f, 0.f, 0.f, 0.f};
  const float* hg = h + (size_t)g * LLN * DDIM;

  for (int kc = 0; kc < 10; ++kc) {
    __syncthreads();
    {
      int m = tid >> 1, halfk = tid & 1;
      int kb = kc * 32 + halfk * 16;
      const float* hp = hg + (size_t)m * DDIM;
      float v[16];
      if (kb + 15 < 300) {
        f4 x0 = *(const f4*)(hp + kb);
        f4 x1 = *(const f4*)(hp + kb + 4);
        f4 x2 = *(const f4*)(hp + kb + 8);
        f4 x3 = *(const f4*)(hp + kb + 12);
        v[0]=x0.x; v[1]=x0.y; v[2]=x0.z; v[3]=x0.w;
        v[4]=x1.x; v[5]=x1.y; v[6]=x1.z; v[7]=x1.w;
        v[8]=x2.x; v[9]=x2.y; v[10]=x2.z; v[11]=x2.w;
        v[12]=x3.x; v[13]=x3.y; v[14]=x3.z; v[15]=x3.w;
      } else {
        #pragma unroll
        for (int e = 0; e < 16; ++e) { int k = kb + e; v[e] = (k < 300) ? hp[k] : 0.f; }
      }
      // fused hsplit: raw-h hi image (u==0 writer only)
      if (u == 0) {
        unsigned short* oh = hh + (size_t)(g * 10 + kc) * 4096;
        #pragma unroll
        for (int g4 = 0; g4 < 4; ++g4) {
          int klocal = halfk * 16 + g4 * 4;
          int q = klocal >> 3, wb = klocal & 7;
          int idx = m * 32 + swzq(m, q) * 8 + wb;
          ushort4 hv;
          hv.x = f2bf(v[g4*4+0]); hv.y = f2bf(v[g4*4+1]);
          hv.z = f2bf(v[g4*4+2]); hv.w = f2bf(v[g4*4+3]);
          *(ushort4*)&oh[idx] = hv;
        }
      }
      #pragma unroll
      for (int e = 0; e < 16; ++e) v[e] = fmaxf(v[e] * wv[kb + e], 0.f);
      #pragma unroll
      for (int g4 = 0; g4 < 4; ++g4) {
        int klocal = halfk * 16 + g4 * 4;
        int q = klocal >> 3, wb = klocal & 7;
        int idx = m * 32 + swzq(m, q) * 8 + wb;
        ushort4 hv, lv;
        hv.x = f2bf(v[g4*4+0]); lv.x = f2bf(v[g4*4+0] - bf2f(hv.x));
        hv.y = f2bf(v[g4*4+1]); lv.y = f2bf(v[g4*4+1] - bf2f(hv.y));
        hv.z = f2bf(v[g4*4+2]); lv.z = f2bf(v[g4*4+2] - bf2f(hv.z));
        hv.w = f2bf(v[g4*4+3]); lv.w = f2bf(v[g4*4+3] - bf2f(hv.w));
        *(ushort4*)&Vh[idx] = hv;
        *(ushort4*)&Vl[idx] = lv;
      }
    }
    __syncthreads();
    #pragma unroll
    for (int fr = 0; fr < 2; ++fr) {
      int ra = wid * 32 + fr * 16 + lr;
      int ai = ra * 32 + swzq(ra, lq) * 8;
      s16x8 ah = *(const s16x8*)&Vh[ai];
      s16x8 al = *(const s16x8*)&Vl[ai];
      #pragma unroll
      for (int nf = 0; nf < 8; ++nf) {
        int rb = nf * 16 + lr;
        int bi = rb * 32 + swzq(rb, lq) * 8;
        s16x8 bh = *(const s16x8*)&Vh[bi];
        s16x8 bl = *(const s16x8*)&Vl[bi];
        acc[fr][nf] = mfma4(ah, al, bh, bl, acc[fr][nf]);
      }
    }
  }
  __syncthreads();
  unsigned char* Au8 = (unsigned char*)Vh;   // 16 KB reuse (Vh+Vl)
  #pragma unroll
  for (int fr = 0; fr < 2; ++fr) {
    #pragma unroll
    for (int nf = 0; nf < 8; ++nf) {
      int j = nf * 16 + lr;
      #pragma unroll
      for (int t2 = 0; t2 < 4; ++t2) {
        int i = wid * 32 + fr * 16 + 4 * lq + t2;
        Au8[i * 128 + j] = (acc[fr][nf][t2] >= 0.1f || i == j) ? 1 : 0;
      }
    }
  }
  __syncthreads();
  for (int c = tid; c < 1024; c += 256) {
    int r = c >> 3, q = c & 7;
    uint4 val = *(const uint4*)&Au8[r * 128 + q * 16];
    *(uint4*)&A[(size_t)r * 128 + q * 16] = val;
  }
}

// ---------------- prepW: gatW -> bf16-hi tile image; sageW -> row-major bf16-hi
__global__ __launch_bounds__(256) void prepw_kernel(
    const float* __restrict__ gatW, const float* __restrict__ sageW,
    unsigned short* __restrict__ gWTtH, unsigned short* __restrict__ sWTh) {
  int idx = blockIdx.x * 256 + threadIdx.x;
  if (idx < 1280 * 320) {
    int n = idx / 320, katt = idx - (idx / 320) * 320;
    int nt = n >> 7, nl = n & 127;
    int kc = katt >> 5, klocal = katt & 31;
    int q = klocal >> 3, wb = klocal & 7;
    size_t pos = ((size_t)(nt * 10 + kc) * 128 + nl) * 32 + swzq(nl, q) * 8 + wb;
    float v = (n < 1200 && katt < 300) ? gatW[(size_t)katt * 1200 + n] : 0.f;
    gWTtH[pos] = f2bf(v);
  } else if (idx < 1280 * 320 + 320 * 320) {
    int i2 = idx - 1280 * 320;
    int n = i2 / 320, k = i2 % 320;
    float v = (n < 300 && k < 300) ? sageW[(size_t)k * 300 + n] : 0.f;
    sWTh[i2] = f2bf(v);
  }
}

// ---------------- zmm: z = h @ gatW via single-bf16 MFMA; gld16 staging from tile images.
// el/er partials -> unique slots (deterministic). z stored as bf16 (hi).
__global__ __launch_bounds__(256) void zmm_mfma(
    const unsigned short* __restrict__ hsplH,
    const unsigned short* __restrict__ gWTtH,
    const float* __restrict__ attn_l, const float* __restrict__ attn_r,
    unsigned short* __restrict__ zTh, float* __restrict__ part) {
  __shared__ __align__(16) unsigned short smem[128 * 136];   // 34816 B
  unsigned short* Ah = smem;
  unsigned short* Bh = smem + 4096;
  int x = blockIdx.x & 7, tb = blockIdx.x >> 3;
  int gi = tb / 10, nt = tb - gi * 10;
  int g = x + 8 * gi;
  int n0 = nt * 128;
  int tid = threadIdx.x, w = tid >> 6, lane = tid & 63;
  int lq = lane >> 4, lr = lane & 15, wr = w >> 1, wc = w & 1;
  f32x4 acc[4][4];
  #pragma unroll
  for (int a = 0; a < 4; ++a)
    #pragma unroll
    for (int b = 0; b < 4; ++b) acc[a][b] = (f32x4){0.f, 0.f, 0.f, 0.f};

  for (int kc = 0; kc < 10; ++kc) {
    {
      const unsigned short* ah_g = hsplH + (size_t)(g * 10 + kc) * 4096;
      const unsigned short* bh_g = gWTtH + (size_t)(nt * 10 + kc) * 4096;
      int o = tid * 8;
      gld16(ah_g + o, Ah + o); gld16(ah_g + o + 2048, Ah + o + 2048);
      gld16(bh_g + o, Bh + o); gld16(bh_g + o + 2048, Bh + o + 2048);
    }
    __syncthreads();   // drains vmcnt (global_load_lds) before reads
    s16x8 ah[4];
    #pragma unroll
    for (int mf = 0; mf < 4; ++mf) {
      int row = wr * 64 + mf * 16 + lr;
      int ai = row * 32 + swzq(row, lq) * 8;
      ah[mf] = *(const s16x8*)&Ah[ai];
    }
    #pragma unroll
    for (int nf = 0; nf < 4; ++nf) {
      int rn = wc * 64 + nf * 16 + lr;
      int bi = rn * 32 + swzq(rn, lq) * 8;
      s16x8 bhv = *(const s16x8*)&Bh[bi];
      #pragma unroll
      for (int mf = 0; mf < 4; ++mf)
        acc[mf][nf] = __builtin_amdgcn_mfma_f32_16x16x32_bf16(ah[mf], bhv, acc[mf][nf], 0, 0, 0);
    }
    __syncthreads();
  }

  // ---- el/er partial dots -> unique (g, head, slot) slots; no atomics ----
  {
    int cbase = n0 + wc * 64;
    if (cbase < 1200) {
      int b = cbase >> 6;                 // band 0..18
      int h_base = cbase / 300;
      int fb = (h_base == 0) ? 0 : (h_base == 1) ? 5 : (h_base == 2) ? 10 : 15;
      int slot = b - fb + 1;              // 1..5
      int h_last = (cbase + 63 < 1200 ? cbase + 63 : 1199) / 300;
      bool has_alt = (h_last != h_base);
      float aLv[4], aRv[4]; int alt[4];
      #pragma unroll
      for (int nf = 0; nf < 4; ++nf) {
        int cg = cbase + nf * 16 + lr;
        bool ok = cg < 1200;
        aLv[nf] = ok ? attn_l[cg] : 0.f;
        aRv[nf] = ok ? attn_r[cg] : 0.f;
        alt[nf] = (ok && (cg / 300) != h_base) ? 1 : 0;
      }
      float* p0 = part + (((size_t)(g * 4 + h_base) * 6 + slot) * 2) * 128;
      float* p1 = part + (((size_t)(g * 4 + h_base + 1) * 6 + 0) * 2) * 128;
      #pragma unroll
      for (int mf = 0; mf < 4; ++mf) {
        #pragma unroll
        for (int t2 = 0; t2 < 4; ++t2) {
          float s0l = 0.f, s0r = 0.f, s1l = 0.f, s1r = 0.f;
          #pragma unroll
          for (int nf = 0; nf < 4; ++nf) {
            float v = acc[mf][nf][t2];
            float cl = v * aLv[nf], cr = v * aRv[nf];
            s0l += alt[nf] ? 0.f : cl; s1l += alt[nf] ? cl : 0.f;
            s0r += alt[nf] ? 0.f : cr; s1r += alt[nf] ? cr : 0.f;
          }
          #pragma unroll
          for (int mm = 1; mm < 16; mm <<= 1) {
            s0l += __shfl_xor(s0l, mm, 64);
            s0r += __shfl_xor(s0r, mm, 64);
          }
          if (has_alt) {
            #pragma unroll
            for (int mm = 1; mm < 16; mm <<= 1) {
              s1l += __shfl_xor(s1l, mm, 64);
              s1r += __shfl_xor(s1r, mm, 64);
            }
          }
          if (lr == 0) {
            int j = wr * 64 + mf * 16 + 4 * lq + t2;
            p0[j] = s0l; p0[128 + j] = s0r;
            if (has_alt) { p1[j] = s1l; p1[128 + j] = s1r; }
          }
        }
      }
    }
  }

  // ---- transposed coalesced zT store (hi only) ----
  __syncthreads();
  #pragma unroll
  for (int mf = 0; mf < 4; ++mf) {
    #pragma unroll
    for (int nf = 0; nf < 4; ++nf) {
      int cl = wc * 64 + nf * 16 + lr;
      int j0 = wr * 64 + mf * 16 + 4 * lq;
      f32x4 a = acc[mf][nf];
      ushort4 pv;
      pv.x = f2bf(a[0]); pv.y = f2bf(a[1]); pv.z = f2bf(a[2]); pv.w = f2bf(a[3]);
      *(ushort4*)&smem[cl * 136 + j0] = pv;
    }
  }
  __syncthreads();
  #pragma unroll
  for (int p = 0; p < 8; ++p) {
    int c = tid + p * 256;
    int r = c >> 4, q = c & 15;
    int cg = n0 + r;
    if (cg < 1200) {
      int head = cg / 300, d = cg - head * 300;
      uint4 val = *(const uint4*)&smem[r * 136 + q * 8];
      *(uint4*)(zTh + ((size_t)(g * 4 + head) * 300 + d) * 128 + q * 8) = val;
    }
  }
}

// ---------------- elr_lite: reduce el/er partials in fixed slot order (deterministic)
__global__ __launch_bounds__(256) void elr_lite(
    const float* __restrict__ part, float* __restrict__ el, float* __restrict__ er) {
  int g = blockIdx.x, tid = threadIdx.x;
  int j = tid & 127, side = tid >> 7;
  for (int s = 0; s < 4; ++s) {
    int s0 = (s == 0) ? 1 : 0;
    int s1e = (s == 3) ? 4 : 5;
    float v = 0.f;
    for (int sl = s0; sl <= s1e; ++sl)
      v += part[(((size_t)(g * 4 + s) * 6 + sl) * 2 + side) * 128 + j];
    float* dst = side ? er : el;
    dst[(size_t)(g * 4 + s) * 128 + j] = v;
  }
}

// ---------------- gat_fuse: fused mx/sinv + 4 GAT heads; P and z single-bf16 (1 MFMA/tile)
__global__ __launch_bounds__(256) void gat_fuse(
    const float* __restrict__ h, const unsigned char* __restrict__ Agat,
    const unsigned short* __restrict__ zTh,
    const float* __restrict__ el, const float* __restrict__ er,
    const float* __restrict__ gat_b, const float* __restrict__ headW,
    const float* __restrict__ head_b, const unsigned short* __restrict__ zerobuf,
    float* __restrict__ out) {
  __shared__ __align__(16) unsigned short Bh[320 * 32];
  __shared__ __align__(16) unsigned short Ah[32 * 32];
  __shared__ __align__(16) unsigned char Ag8[32 * 128];
  __shared__ __align__(16) float elsm[4 * 128];
  __shared__ __align__(16) float ersl[4 * 32];
  __shared__ __align__(16) float mxl[4 * 32];
  __shared__ __align__(16) float svl[4 * 32];
  __shared__ float hwred[2][32];
  __shared__ float wgts[32];
  int xb = blockIdx.x & 7, tb = blockIdx.x >> 3;
  int it = tb & 3, g = xb + 8 * (tb >> 2);
  int i0 = it * 32;
  int tid = threadIdx.x, w = tid >> 6, lane = tid & 63;
  int lq = lane >> 4, lr = lane & 15, wi = w & 1, wn = w >> 1;
  float hb = head_b[0];

  // ---- pre-pass: stage Agat tile + el/er; compute mx/sinv for own 32 rows ----
  {
    int r = tid >> 3, o = (tid & 7) * 16;
    *(uint4*)&Ag8[r * 128 + o] = *(const uint4*)(Agat + ((size_t)g * 128 + i0 + r) * 128 + o);
    elsm[tid] = el[(size_t)(g * 4) * 128 + tid];
    elsm[256 + tid] = el[(size_t)(g * 4) * 128 + 256 + tid];
    if (tid < 128) {
      int s = tid >> 5, r2 = tid & 31;
      ersl[tid] = er[(size_t)(g * 4 + s) * 128 + i0 + r2];
    }
  }
  __syncthreads();
  for (int s = 0; s < 4; ++s) {
    float el0 = elsm[s * 128 + lane], el1 = elsm[s * 128 + 64 + lane];
    for (int r = w; r < 32; r += 4) {
      int m0 = Ag8[r * 128 + lane], m1 = Ag8[r * 128 + 64 + lane];
      float eri = ersl[s * 32 + r];
      float e0 = eri + el0; e0 = e0 >= 0.f ? e0 : 0.2f * e0;
      float e1 = eri + el1; e1 = e1 >= 0.f ? e1 : 0.2f * e1;
      float x0 = m0 ? e0 : -3.0e38f;
      float x1 = m1 ? e1 : -3.0e38f;
      float m_ = wmax(fmaxf(x0, x1));
      float p0 = m0 ? __expf(e0 - m_) : 0.f;
      float p1 = m1 ? __expf(e1 - m_) : 0.f;
      float ssum = wsum(p0 + p1);
      if (lane == 0) { mxl[s * 32 + r] = m_; svl[s * 32 + r] = 1.f / ssum; }
    }
  }
  __syncthreads();

  float outacc[10][4];
  #pragma unroll
  for (int nf = 0; nf < 10; ++nf)
    #pragma unroll
    for (int t = 0; t < 4; ++t) outacc[nf][t] = 0.f;

  for (int s = 0; s < 4; ++s) {
    f32x4 acc[10];
    #pragma unroll
    for (int nf = 0; nf < 10; ++nf) acc[nf] = (f32x4){0.f, 0.f, 0.f, 0.f};
    const unsigned short* zsh = zTh + (size_t)(g * 4 + s) * 300 * 128;

    for (int kc = 0; kc < 4; ++kc) {
      int j0 = kc * 32;
      // A stage: p = mask ? exp(leaky(er_i+el_j) - mx_i) : 0 (hi only)
      {
        int m = tid >> 3, j4 = (tid & 7) * 4;
        float eri = ersl[s * 32 + m], mxi = mxl[s * 32 + m];
        const unsigned char* mrow = &Ag8[m * 128 + j0 + j4];
        uchar4 msk = *(const uchar4*)mrow;
        f4 elv = *(const f4*)&elsm[s * 128 + j0 + j4];
        float p[4];
        {
          float e = eri + elv.x; e = e >= 0.f ? e : 0.2f * e; p[0] = msk.x ? __expf(e - mxi) : 0.f;
          e = eri + elv.y; e = e >= 0.f ? e : 0.2f * e; p[1] = msk.y ? __expf(e - mxi) : 0.f;
          e = eri + elv.z; e = e >= 0.f ? e : 0.2f * e; p[2] = msk.z ? __expf(e - mxi) : 0.f;
          e = eri + elv.w; e = e >= 0.f ? e : 0.2f * e; p[3] = msk.w ? __expf(e - mxi) : 0.f;
        }
        int q = j4 >> 3, wb = j4 & 7;
        int idx = m * 32 + swzq(m, q) * 8 + wb;
        ushort4 hv;
        hv.x = f2bf(p[0]); hv.y = f2bf(p[1]); hv.z = f2bf(p[2]); hv.w = f2bf(p[3]);
        *(ushort4*)&Ah[idx] = hv;
      }
      // B stage: gld16 from pre-swizzled global source (z-hi only)
      {
        #pragma unroll
        for (int cc = 0; cc < 5; ++cc) {
          int chunk = w + cc * 4;            // 0..19
          int nb = chunk * 16;
          int n = nb + (lane >> 2);
          int q = (lane & 3) ^ ((n >> 1) & 3);
          const unsigned short* srcH = (n < 300) ? (zsh + (size_t)n * 128 + j0 + q * 8) : zerobuf;
          gld16(srcH, Bh + chunk * 512 + lane * 8);
        }
      }
      __syncthreads();
      int rowa = wi * 16 + lr;
      int ai = rowa * 32 + swzq(rowa, lq) * 8;
      s16x8 ah = *(const s16x8*)&Ah[ai];
      #pragma unroll
      for (int nf = 0; nf < 10; ++nf) {
        int rn = wn * 160 + nf * 16 + lr;
        int bi = rn * 32 + swzq(rn, lq) * 8;
        s16x8 bhv = *(const s16x8*)&Bh[bi];
        acc[nf] = __builtin_amdgcn_mfma_f32_16x16x32_bf16(ah, bhv, acc[nf], 0, 0, 0);
      }
      __syncthreads();
    }
    // epilogue for slot s
    f4 sv4 = *(const f4*)&svl[s * 32 + wi * 16 + 4 * lq];
    float svf[4] = {sv4.x, sv4.y, sv4.z, sv4.w};
    float pt[4] = {0.f, 0.f, 0.f, 0.f};
    #pragma unroll
    for (int nf = 0; nf < 10; ++nf) {
      int c = wn * 160 + nf * 16 + lr;
      bool val = c < 300;
      float gb = val ? gat_b[s * 300 + c] : 0.f;
      float hwv = val ? headW[c] : 0.f;
      #pragma unroll
      for (int t = 0; t < 4; ++t) {
        float gvv = acc[nf][t] * svf[t] + gb;
        acc[nf][t] = gvv;
        pt[t] += gvv * hwv;
      }
    }
    #pragma unroll
    for (int t = 0; t < 4; ++t) {
      #pragma unroll
      for (int mm = 1; mm < 16; mm <<= 1) pt[t] += __shfl_xor(pt[t], mm, 64);
    }
    if (lr == 0) {
      #pragma unroll
      for (int t = 0; t < 4; ++t) hwred[wn][wi * 16 + 4 * lq + t] = pt[t];
    }
    __syncthreads();
    if (tid < 32) wgts[tid] = sigm(hwred[0][tid] + hwred[1][tid] + hb);
    __syncthreads();
    #pragma unroll
    for (int nf = 0; nf < 10; ++nf) {
      #pragma unroll
      for (int t = 0; t < 4; ++t) {
        int r = wi * 16 + 4 * lq + t;
        outacc[nf][t] += wgts[r] * acc[nf][t];
      }
    }
    __syncthreads();
  }
  #pragma unroll
  for (int nf = 0; nf < 10; ++nf) {
    int c = wn * 160 + nf * 16 + lr;
    if (c < 300) {
      #pragma unroll
      for (int t = 0; t < 4; ++t) {
        int r = wi * 16 + 4 * lq + t;
        size_t o = ((size_t)(g * 128 + i0 + r)) * 300 + c;
        out[o] = h[o] + outacc[nf][t];
      }
    }
  }
}

// ---------------- neigh (fp32): n = (Asag@h + h)*dinv -> single bf16 (hi)
__global__ __launch_bounds__(256) void neigh_kernel(
    const float* __restrict__ h, const unsigned char* __restrict__ Asag,
    unsigned short* __restrict__ nh) {
  __shared__ float As[16][128];
  int g, it; xcd_decode8(blockIdx.x, g, it);
  int i0 = it * 16;
  int tid = threadIdx.x, ii = tid >> 6, lane = tid & 63;
  for (int idx = tid; idx < 16 * 128; idx += 256)
    As[idx >> 7][idx & 127] = (float)Asag[((size_t)g * 128 + i0 + (idx >> 7)) * 128 + (idx & 127)];
  __syncthreads();
  float dinv_r[4];
  #pragma unroll
  for (int r = 0; r < 4; ++r) {
    int row = ii * 4 + r;
    float s_ = As[row][lane] + As[row][64 + lane];
    s_ = wsum(s_);
    dinv_r[r] = 1.f / (s_ + 1.f);
  }
  int dq0 = lane, dq1 = lane + 64;
  bool ok1 = dq1 < 75;
  const f4 zero4 = make_float4(0.f, 0.f, 0.f, 0.f);
  const f4* h4 = (const f4*)(h + (size_t)g * LLN * DDIM);
  f4 acc0[4], acc1[4];
  #pragma unroll
  for (int r = 0; r < 4; ++r) { acc0[r] = zero4; acc1[r] = zero4; }
  for (int j = 0; j < 128; ++j) {
    float a0 = As[ii*4+0][j], a1 = As[ii*4+1][j], a2 = As[ii*4+2][j], a3 = As[ii*4+3][j];
    f4 hv0 = h4[j * 75 + dq0];
    f4 hv1 = ok1 ? h4[j * 75 + dq1] : zero4;
    FMA4(acc0[0], hv0, a0); FMA4(acc0[1], hv0, a1); FMA4(acc0[2], hv0, a2); FMA4(acc0[3], hv0, a3);
    FMA4(acc1[0], hv1, a0); FMA4(acc1[1], hv1, a1); FMA4(acc1[2], hv1, a2); FMA4(acc1[3], hv1, a3);
  }
  #pragma unroll
  for (int r = 0; r < 4; ++r) {
    int i = i0 + ii * 4 + r;
    float dv = dinv_r[r];
    f4 n0v = scale4(add4(acc0[r], h4[i * 75 + dq0]), dv);
    size_t base = (size_t)(g * 128 + i) * 320;
    ushort4 hv;
    hv.x = f2bf(n0v.x); hv.y = f2bf(n0v.y); hv.z = f2bf(n0v.z); hv.w = f2bf(n0v.w);
    *(ushort4*)&nh[base + dq0 * 4] = hv;
    if (ok1) {
      f4 n1v = scale4(add4(acc1[r], h4[i * 75 + dq1]), dv);
      hv.x = f2bf(n1v.x); hv.y = f2bf(n1v.y); hv.z = f2bf(n1v.z); hv.w = f2bf(n1v.w);
      *(ushort4*)&nh[base + dq1 * 4] = hv;
    }
    if (lane < 5) {
      ushort4 z4u = {0, 0, 0, 0};
      *(ushort4*)&nh[base + 300 + lane * 4] = z4u;
    }
  }
}

// ---------------- sage_fuse: sage = n(bf16) @ W(bf16) + b; out += sigmoid(dot)*sage
__global__ __launch_bounds__(256) void sage_fuse(
    const unsigned short* __restrict__ nh,
    const unsigned short* __restrict__ sWTh,
    const float* __restrict__ sage_b, const float* __restrict__ headW,
    const float* __restrict__ head_b, float* __restrict__ out) {
  __shared__ __align__(16) unsigned short Bh[320 * 32];
  __shared__ __align__(16) unsigned short Ah[32 * 32];
  __shared__ float hwred[2][32];
  __shared__ float wgts[32];
  int m0 = blockIdx.x * 32;
  int tid = threadIdx.x, w = tid >> 6, lane = tid & 63;
  int lq = lane >> 4, lr = lane & 15, wi = w & 1, wn = w >> 1;
  float hb = head_b[0];
  f32x4 acc[10];
  #pragma unroll
  for (int nf = 0; nf < 10; ++nf) acc[nf] = (f32x4){0.f, 0.f, 0.f, 0.f};

  for (int kc = 0; kc < 10; ++kc) {
    if (tid < 128) {
      int rowm = tid >> 2, qq = tid & 3;
      int idx = rowm * 32 + swzq(rowm, qq) * 8;
      const unsigned short* src = nh + (size_t)(m0 + rowm) * 320 + kc * 32 + qq * 8;
      *(s16x8*)&Ah[idx] = *(const s16x8*)src;
    }
    {
      #pragma unroll
      for (int rep = 0; rep < 2; ++rep) {
        int n = rep == 0 ? tid : 256 + tid;
        if (rep == 1 && tid >= 64) break;
        const unsigned short* src_h = sWTh + (size_t)n * 320 + kc * 32;
        #pragma unroll
        for (int q = 0; q < 4; ++q) {
          int idx = n * 32 + swzq(n, q) * 8;
          *(s16x8*)&Bh[idx] = *(const s16x8*)(src_h + q * 8);
        }
      }
    }
    __syncthreads();
    int rowa = wi * 16 + lr;
    int ai = rowa * 32 + swzq(rowa, lq) * 8;
    s16x8 ah = *(const s16x8*)&Ah[ai];
    #pragma unroll
    for (int nf = 0; nf < 10; ++nf) {
      int rn = wn * 160 + nf * 16 + lr;
      int bi = rn * 32 + swzq(rn, lq) * 8;
      s16x8 bhv = *(const s16x8*)&Bh[bi];
      acc[nf] = __builtin_amdgcn_mfma_f32_16x16x32_bf16(ah, bhv, acc[nf], 0, 0, 0);
    }
    __syncthreads();
  }
  float pt[4] = {0.f, 0.f, 0.f, 0.f};
  #pragma unroll
  for (int nf = 0; nf < 10; ++nf) {
    int c = wn * 160 + nf * 16 + lr;
    bool val = c < 300;
    float sb = val ? sage_b[c] : 0.f;
    float hwv = val ? headW[c] : 0.f;
    #pragma unroll
    for (int t = 0; t < 4; ++t) {
      float gvv = acc[nf][t] + sb;
      acc[nf][t] = gvv;
      pt[t] += gvv * hwv;
    }
  }
  #pragma unroll
  for (int t = 0; t < 4; ++t) {
    #pragma unroll
    for (int mm = 1; mm < 16; mm <<= 1) pt[t] += __shfl_xor(pt[t], mm, 64);
  }
  if (lr == 0) {
    #pragma unroll
    for (int t = 0; t < 4; ++t) hwred[wn][wi * 16 + 4 * lq + t] = pt[t];
  }
  __syncthreads();
  if (tid < 32) wgts[tid] = sigm(hwred[0][tid] + hwred[1][tid] + hb);
  __syncthreads();
  #pragma unroll
  for (int nf = 0; nf < 10; ++nf) {
    int c = wn * 160 + nf * 16 + lr;
    if (c < 300) {
      #pragma unroll
      for (int t = 0; t < 4; ++t) {
        int r = wi * 16 + 4 * lq + t;
        size_t o = ((size_t)(m0 + r)) * 300 + c;
        out[o] = out[o] + wgts[r] * acc[nf][t];
      }
    }
  }
}

// ---------------- WeightAndSum pool
__global__ __launch_bounds__(256) void pool_kernel(
    const float* __restrict__ h, const float* __restrict__ poolW,
    const float* __restrict__ pool_b, float* __restrict__ gvec) {
  __shared__ float ws_[128];
  int g = blockIdx.x, tid = threadIdx.x, ii = tid >> 6, lane = tid & 63;
  const float* hg = h + (size_t)g * LLN * DDIM;
  float pb = pool_b[0];
  for (int m = 0; m < 32; ++m) {
    int l = ii * 32 + m;
    float p = 0.f;
    for (int d = lane; d < DDIM; d += 64) p += hg[l * DDIM + d] * poolW[d];
    p = wsum(p);
    if (lane == 0) ws_[l] = 1.f / (1.f + __expf(-(p + pb)));
  }
  __syncthreads();
  for (int d = tid; d < DDIM; d += 256) {
    float acc = 0.f;
    for (int l = 0; l < 128; ++l) acc += hg[l * DDIM + d] * ws_[l];
    gvec[(size_t)g * DDIM + d] = acc;
  }
}

// ---------------- pearson
__global__ __launch_bounds__(64) void pearson_kernel(
    const float* __restrict__ gvec, float* __restrict__ out) {
  int b = blockIdx.x, lane = threadIdx.x;
  const float* g1 = gvec + (size_t)b * DDIM;
  const float* g2 = gvec + (size_t)(64 + b) * DDIM;
  float v1[5], v2[5];
  float s1 = 0.f, s2 = 0.f;
  #pragma unroll
  for (int q = 0; q < 5; ++q) {
    int d = lane + 64 * q;
    v1[q] = (d < DDIM) ? g1[d] : 0.f;
    v2[q] = (d < DDIM) ? g2[d] : 0.f;
    s1 += v1[q]; s2 += v2[q];
  }
  s1 = wsum(s1); s2 = wsum(s2);
  float m1 = s1 / 300.f, m2 = s2 / 300.f;
  float a = 0.f, bb = 0.f, c = 0.f;
  #pragma unroll
  for (int q = 0; q < 5; ++q) {
    int d = lane + 64 * q;
    if (d < DDIM) {
      float x = v1[q] - m1, y = v2[q] - m2;
      a += x * y; bb += x * x; c += y * y;
    }
  }
  a = wsum(a); bb = wsum(bb); c = wsum(c);
  if (lane == 0) out[b] = 5.f * a / (sqrtf(bb) * sqrtf(c));
}

extern "C" void kernel_launch(void* const* d_in, const int* in_sizes, int n_in,
                              void* d_out, int out_size, void* d_ws, size_t ws_size,
                              hipStream_t stream) {
  (void)in_sizes; (void)n_in; (void)out_size; (void)ws_size;
  const float* emb   = (const float*)d_in[0];
  const float* simw1 = (const float*)d_in[1];
  const float* simw2 = (const float*)d_in[2];
  const float* LP[2][8];
  for (int l = 0; l < 2; ++l)
    for (int p = 0; p < 8; ++p) LP[l][p] = (const float*)d_in[3 + l * 8 + p];
  const float* poolW  = (const float*)d_in[19];
  const float* pool_b = (const float*)d_in[20];
  const int* s1 = (const int*)d_in[21];
  const int* s2 = (const int*)d_in[22];
  float* out = (float*)d_out;

  char* ws = (char*)d_ws;
  float* hA  = (float*)(ws + 0);                         // 19,660,800
  float* hB  = (float*)(ws + 19660800);                  // 19,660,800
  unsigned short* zTh = (unsigned short*)(ws + 39321600);   // 39,321,600
  unsigned short* nh = (unsigned short*)(ws + 39321600); // alias zTh (post-gat_fuse)
  unsigned char* Agat = (unsigned char*)(ws + 117964800); // 2,097,152
  unsigned char* Asag = (unsigned char*)(ws + 120061952); // 2,097,152
  float* elb  = (float*)(ws + 122159104);                // 262,144
  float* erb  = (float*)(ws + 122421248);                // 262,144
  unsigned short* zb16 = (unsigned short*)(ws + 122683392); // 64 B zero region
  unsigned short* sWTh = (unsigned short*)(ws + 123273216); // 204,800
  float* gv   = (float*)(ws + 123682816);                // 153,600

  hipMemsetAsync(zb16, 0, 64, stream);   // zero pad source for gld16 tail rows
  gather_kernel<<<GG * LLN, 256, 0, stream>>>(emb, s1, s2, hA);

  float* hin = hA; float* hout = hB;
  for (int l = 0; l < 2; ++l) {
    // hi image + weight tiles + el/er partials live in the (currently dead) hout region;
    // all consumed (zmm, elr_lite) before gat_fuse writes hout.
    unsigned short* hsplH = (unsigned short*)hout;                        // 10,485,760
    unsigned short* gWTtH = (unsigned short*)((char*)hout + 10485760);    //    819,200
    float*          partb = (float*)((char*)hout + 11304960);             //  3,145,728 -> 14,450,688 < 19.6MB

    adjmm_kernel<<<256, 256, 0, stream>>>(hin, simw1, simw2, Agat, Asag, hsplH);
    prepw_kernel<<<2000, 256, 0, stream>>>(LP[l][0], LP[l][4], gWTtH, sWTh);
    zmm_mfma<<<1280, 256, 0, stream>>>(hsplH, gWTtH, LP[l][1], LP[l][2], zTh, partb);
    elr_lite<<<GG, 256, 0, stream>>>(partb, elb, erb);
    gat_fuse<<<512, 256, 0, stream>>>(hin, Agat, zTh, elb, erb,
        LP[l][3], LP[l][6], LP[l][7], zb16, hout);
    neigh_kernel<<<1024, 256, 0, stream>>>(hin, Asag, nh);
    sage_fuse<<<512, 256, 0, stream>>>(nh, sWTh, LP[l][5], LP[l][6], LP[l][7], hout);
    float* t = hin; hin = hout; hout = t;
  }

  pool_kernel<<<GG, 256, 0, stream>>>(hin, poolW, pool_b, gv);
  pearson_kernel<<<64, 64, 0, stream>>>(gv, out);
}

// Round 11
// 414.954 us; speedup vs baseline: 1.8529x; 1.3458x over previous
//
#include <hip/hip_runtime.h>
#include <hip/hip_bf16.h>

#define GG 128   // graphs total (2 branches x 64)
#define LLN 128
#define DDIM 300
#define NH 4

typedef float4 f4;
typedef __attribute__((ext_vector_type(4))) float f32x4;
typedef __attribute__((ext_vector_type(8))) short s16x8;

__device__ __forceinline__ float wsum(float v) {
  #pragma unroll
  for (int o = 32; o > 0; o >>= 1) v += __shfl_xor(v, o, 64);
  return v;
}
__device__ __forceinline__ float wmax(float v) {
  #pragma unroll
  for (int o = 32; o > 0; o >>= 1) v = fmaxf(v, __shfl_xor(v, o, 64));
  return v;
}
__device__ __forceinline__ f4 add4(f4 a, f4 b) {
  return make_float4(a.x+b.x, a.y+b.y, a.z+b.z, a.w+b.w);
}
__device__ __forceinline__ unsigned short f2bf(float x) {
  unsigned int u = __float_as_uint(x);
  return (unsigned short)((u + 0x7fffu + ((u >> 16) & 1u)) >> 16);
}
__device__ __forceinline__ float bf2f(unsigned short b) {
  return __uint_as_float(((unsigned int)b) << 16);
}
__device__ __forceinline__ int swzq(int row, int q) { return q ^ ((row >> 1) & 3); }
__device__ __forceinline__ float sigm(float x) { return 1.f / (1.f + __expf(-x)); }

__device__ __forceinline__ f32x4 mfma4(s16x8 ah, s16x8 al, s16x8 bh, s16x8 bl, f32x4 c) {
  c = __builtin_amdgcn_mfma_f32_16x16x32_bf16(ah, bh, c, 0, 0, 0);
  c = __builtin_amdgcn_mfma_f32_16x16x32_bf16(ah, bl, c, 0, 0, 0);
  c = __builtin_amdgcn_mfma_f32_16x16x32_bf16(al, bh, c, 0, 0, 0);
  c = __builtin_amdgcn_mfma_f32_16x16x32_bf16(al, bl, c, 0, 0, 0);
  return c;
}

__device__ __forceinline__ void gld16(const void* g, void* l) {
  __builtin_amdgcn_global_load_lds(
      (const __attribute__((address_space(1))) void*)g,
      (__attribute__((address_space(3))) void*)l, 16, 0, 0);
}

// ---------------- embedding gather
__global__ __launch_bounds__(256) void gather_kernel(
    const float* __restrict__ emb, const int* __restrict__ s1,
    const int* __restrict__ s2, float* __restrict__ h) {
  int gl = blockIdx.x;
  int g = gl >> 7, l = gl & 127;
  const int* s = (g >= 64) ? s2 : s1;
  int tok = s[l * 64 + (g & 63)];
  const float* src = emb + (size_t)tok * DDIM;
  float* dst = h + (size_t)gl * DDIM;
  for (int d = threadIdx.x; d < DDIM; d += 256) dst[d] = src[d];
}

// ---------------- adjmm: both adjacencies via 4-term split-bf16 MFMA (V.V^T, symmetric)
// u==0 blocks additionally emit the raw-h bf16-hi tile image (fused hsplit).
__global__ __launch_bounds__(256) void adjmm_kernel(
    const float* __restrict__ h, const float* __restrict__ simw1,
    const float* __restrict__ simw2, unsigned char* __restrict__ Agat,
    unsigned char* __restrict__ Asag, unsigned short* __restrict__ hh) {
  __shared__ __align__(16) unsigned short Vh[128 * 32], Vl[128 * 32];
  __shared__ float wv[320];
  int x = blockIdx.x & 7, t = blockIdx.x >> 3;
  int u = t & 1, g = x + 8 * (t >> 1);
  const float* w = u ? simw1 : simw2;
  unsigned char* A = (u ? Asag : Agat) + (size_t)g * LLN * LLN;
  int tid = threadIdx.x, wid = tid >> 6, lane = tid & 63;
  int lq = lane >> 4, lr = lane & 15;
  for (int k = tid; k < 320; k += 256) wv[k] = (k < 300) ? w[k] : 0.f;
  f32x4 acc[2][8];
  #pragma unroll
  for (int fr = 0; fr < 2; ++fr)
    #pragma unroll
    for (int nf = 0; nf < 8; ++nf) acc[fr][nf] = (f32x4){0.f, 0.f, 0.f, 0.f};
  const float* hg = h + (size_t)g * LLN * DDIM;

  for (int kc = 0; kc < 10; ++kc) {
    __syncthreads();
    {
      int m = tid >> 1, halfk = tid & 1;
      int kb = kc * 32 + halfk * 16;
      const float* hp = hg + (size_t)m * DDIM;
      float v[16];
      if (kb + 15 < 300) {
        f4 x0 = *(const f4*)(hp + kb);
        f4 x1 = *(const f4*)(hp + kb + 4);
        f4 x2 = *(const f4*)(hp + kb + 8);
        f4 x3 = *(const f4*)(hp + kb + 12);
        v[0]=x0.x; v[1]=x0.y; v[2]=x0.z; v[3]=x0.w;
        v[4]=x1.x; v[5]=x1.y; v[6]=x1.z; v[7]=x1.w;
        v[8]=x2.x; v[9]=x2.y; v[10]=x2.z; v[11]=x2.w;
        v[12]=x3.x; v[13]=x3.y; v[14]=x3.z; v[15]=x3.w;
      } else {
        #pragma unroll
        for (int e = 0; e < 16; ++e) { int k = kb + e; v[e] = (k < 300) ? hp[k] : 0.f; }
      }
      if (u == 0) {
        unsigned short* oh = hh + (size_t)(g * 10 + kc) * 4096;
        #pragma unroll
        for (int g4 = 0; g4 < 4; ++g4) {
          int klocal = halfk * 16 + g4 * 4;
          int q = klocal >> 3, wb = klocal & 7;
          int idx = m * 32 + swzq(m, q) * 8 + wb;
          ushort4 hv;
          hv.x = f2bf(v[g4*4+0]); hv.y = f2bf(v[g4*4+1]);
          hv.z = f2bf(v[g4*4+2]); hv.w = f2bf(v[g4*4+3]);
          *(ushort4*)&oh[idx] = hv;
        }
      }
      #pragma unroll
      for (int e = 0; e < 16; ++e) v[e] = fmaxf(v[e] * wv[kb + e], 0.f);
      #pragma unroll
      for (int g4 = 0; g4 < 4; ++g4) {
        int klocal = halfk * 16 + g4 * 4;
        int q = klocal >> 3, wb = klocal & 7;
        int idx = m * 32 + swzq(m, q) * 8 + wb;
        ushort4 hv, lv;
        hv.x = f2bf(v[g4*4+0]); lv.x = f2bf(v[g4*4+0] - bf2f(hv.x));
        hv.y = f2bf(v[g4*4+1]); lv.y = f2bf(v[g4*4+1] - bf2f(hv.y));
        hv.z = f2bf(v[g4*4+2]); lv.z = f2bf(v[g4*4+2] - bf2f(hv.z));
        hv.w = f2bf(v[g4*4+3]); lv.w = f2bf(v[g4*4+3] - bf2f(hv.w));
        *(ushort4*)&Vh[idx] = hv;
        *(ushort4*)&Vl[idx] = lv;
      }
    }
    __syncthreads();
    #pragma unroll
    for (int fr = 0; fr < 2; ++fr) {
      int ra = wid * 32 + fr * 16 + lr;
      int ai = ra * 32 + swzq(ra, lq) * 8;
      s16x8 ah = *(const s16x8*)&Vh[ai];
      s16x8 al = *(const s16x8*)&Vl[ai];
      #pragma unroll
      for (int nf = 0; nf < 8; ++nf) {
        int rb = nf * 16 + lr;
        int bi = rb * 32 + swzq(rb, lq) * 8;
        s16x8 bh = *(const s16x8*)&Vh[bi];
        s16x8 bl = *(const s16x8*)&Vl[bi];
        acc[fr][nf] = mfma4(ah, al, bh, bl, acc[fr][nf]);
      }
    }
  }
  __syncthreads();
  unsigned char* Au8 = (unsigned char*)Vh;   // 16 KB reuse (Vh+Vl)
  #pragma unroll
  for (int fr = 0; fr < 2; ++fr) {
    #pragma unroll
    for (int nf = 0; nf < 8; ++nf) {
      int j = nf * 16 + lr;
      #pragma unroll
      for (int t2 = 0; t2 < 4; ++t2) {
        int i = wid * 32 + fr * 16 + 4 * lq + t2;
        Au8[i * 128 + j] = (acc[fr][nf][t2] >= 0.1f || i == j) ? 1 : 0;
      }
    }
  }
  __syncthreads();
  for (int c = tid; c < 1024; c += 256) {
    int r = c >> 3, q = c & 7;
    uint4 val = *(const uint4*)&Au8[r * 128 + q * 16];
    *(uint4*)&A[(size_t)r * 128 + q * 16] = val;
  }
}

// ---------------- prepW: gatW -> bf16-hi tile image (10 tiles); sageW -> bf16-hi tile image (3 tiles)
__global__ __launch_bounds__(256) void prepw_kernel(
    const float* __restrict__ gatW, const float* __restrict__ sageW,
    unsigned short* __restrict__ gWTtH, unsigned short* __restrict__ sWTt) {
  int idx = blockIdx.x * 256 + threadIdx.x;
  if (idx < 1280 * 320) {
    int n = idx / 320, katt = idx - (idx / 320) * 320;
    int nt = n >> 7, nl = n & 127;
    int kc = katt >> 5, klocal = katt & 31;
    int q = klocal >> 3, wb = klocal & 7;
    size_t pos = ((size_t)(nt * 10 + kc) * 128 + nl) * 32 + swzq(nl, q) * 8 + wb;
    float v = (n < 1200 && katt < 300) ? gatW[(size_t)katt * 1200 + n] : 0.f;
    gWTtH[pos] = f2bf(v);
  } else if (idx < 1280 * 320 + 384 * 320) {
    int i2 = idx - 1280 * 320;
    int n = i2 / 320, k = i2 % 320;
    int nt2 = n >> 7, nl = n & 127;
    int kc = k >> 5, klocal = k & 31;
    int q = klocal >> 3, wb = klocal & 7;
    size_t pos = ((size_t)(nt2 * 10 + kc) * 128 + nl) * 32 + swzq(nl, q) * 8 + wb;
    float v = (n < 300 && k < 300) ? sageW[(size_t)k * 300 + n] : 0.f;
    sWTt[pos] = f2bf(v);
  }
}

// ---------------- zmm: [z | hW] = h @ [gatW | sageW] via bf16 MFMA; gld16 staging.
// nt 0..9: gat tiles (el/er partials + zT store); nt 10..12: sage tiles -> hWT store.
__global__ __launch_bounds__(256) void zmm_mfma(
    const unsigned short* __restrict__ hsplH,
    const unsigned short* __restrict__ gWTtH,
    const unsigned short* __restrict__ sWTt,
    const float* __restrict__ attn_l, const float* __restrict__ attn_r,
    unsigned short* __restrict__ zTh, unsigned short* __restrict__ hWT,
    float* __restrict__ part) {
  __shared__ __align__(16) unsigned short smem[128 * 136];   // 34816 B
  unsigned short* Ah = smem;
  unsigned short* Bh = smem + 4096;
  int x = blockIdx.x & 7, tb = blockIdx.x >> 3;
  int gi = tb / 13, nt = tb - gi * 13;
  int g = x + 8 * gi;
  bool isz = nt < 10;
  int n0 = nt * 128;
  int tid = threadIdx.x, w = tid >> 6, lane = tid & 63;
  int lq = lane >> 4, lr = lane & 15, wr = w >> 1, wc = w & 1;
  f32x4 acc[4][4];
  #pragma unroll
  for (int a = 0; a < 4; ++a)
    #pragma unroll
    for (int b = 0; b < 4; ++b) acc[a][b] = (f32x4){0.f, 0.f, 0.f, 0.f};

  for (int kc = 0; kc < 10; ++kc) {
    {
      const unsigned short* ah_g = hsplH + (size_t)(g * 10 + kc) * 4096;
      const unsigned short* bh_g = isz ? (gWTtH + (size_t)(nt * 10 + kc) * 4096)
                                       : (sWTt + (size_t)((nt - 10) * 10 + kc) * 4096);
      int o = tid * 8;
      gld16(ah_g + o, Ah + o); gld16(ah_g + o + 2048, Ah + o + 2048);
      gld16(bh_g + o, Bh + o); gld16(bh_g + o + 2048, Bh + o + 2048);
    }
    __syncthreads();   // drains vmcnt (global_load_lds) before reads
    s16x8 ah[4];
    #pragma unroll
    for (int mf = 0; mf < 4; ++mf) {
      int row = wr * 64 + mf * 16 + lr;
      int ai = row * 32 + swzq(row, lq) * 8;
      ah[mf] = *(const s16x8*)&Ah[ai];
    }
    #pragma unroll
    for (int nf = 0; nf < 4; ++nf) {
      int rn = wc * 64 + nf * 16 + lr;
      int bi = rn * 32 + swzq(rn, lq) * 8;
      s16x8 bhv = *(const s16x8*)&Bh[bi];
      #pragma unroll
      for (int mf = 0; mf < 4; ++mf)
        acc[mf][nf] = __builtin_amdgcn_mfma_f32_16x16x32_bf16(ah[mf], bhv, acc[mf][nf], 0, 0, 0);
    }
    __syncthreads();
  }

  // ---- el/er partial dots (gat tiles only) -> unique slots; no atomics ----
  if (isz) {
    int cbase = n0 + wc * 64;
    if (cbase < 1200) {
      int b = cbase >> 6;                 // band 0..18
      int h_base = cbase / 300;
      int fb = (h_base == 0) ? 0 : (h_base == 1) ? 5 : (h_base == 2) ? 10 : 15;
      int slot = b - fb + 1;              // 1..5
      int h_last = (cbase + 63 < 1200 ? cbase + 63 : 1199) / 300;
      bool has_alt = (h_last != h_base);
      float aLv[4], aRv[4]; int alt[4];
      #pragma unroll
      for (int nf = 0; nf < 4; ++nf) {
        int cg = cbase + nf * 16 + lr;
        bool ok = cg < 1200;
        aLv[nf] = ok ? attn_l[cg] : 0.f;
        aRv[nf] = ok ? attn_r[cg] : 0.f;
        alt[nf] = (ok && (cg / 300) != h_base) ? 1 : 0;
      }
      float* p0 = part + (((size_t)(g * 4 + h_base) * 6 + slot) * 2) * 128;
      float* p1 = part + (((size_t)(g * 4 + h_base + 1) * 6 + 0) * 2) * 128;
      #pragma unroll
      for (int mf = 0; mf < 4; ++mf) {
        #pragma unroll
        for (int t2 = 0; t2 < 4; ++t2) {
          float s0l = 0.f, s0r = 0.f, s1l = 0.f, s1r = 0.f;
          #pragma unroll
          for (int nf = 0; nf < 4; ++nf) {
            float v = acc[mf][nf][t2];
            float cl = v * aLv[nf], cr = v * aRv[nf];
            s0l += alt[nf] ? 0.f : cl; s1l += alt[nf] ? cl : 0.f;
            s0r += alt[nf] ? 0.f : cr; s1r += alt[nf] ? cr : 0.f;
          }
          #pragma unroll
          for (int mm = 1; mm < 16; mm <<= 1) {
            s0l += __shfl_xor(s0l, mm, 64);
            s0r += __shfl_xor(s0r, mm, 64);
          }
          if (has_alt) {
            #pragma unroll
            for (int mm = 1; mm < 16; mm <<= 1) {
              s1l += __shfl_xor(s1l, mm, 64);
              s1r += __shfl_xor(s1r, mm, 64);
            }
          }
          if (lr == 0) {
            int j = wr * 64 + mf * 16 + 4 * lq + t2;
            p0[j] = s0l; p0[128 + j] = s0r;
            if (has_alt) { p1[j] = s1l; p1[128 + j] = s1r; }
          }
        }
      }
    }
  }

  // ---- transposed coalesced store ----
  __syncthreads();
  #pragma unroll
  for (int mf = 0; mf < 4; ++mf) {
    #pragma unroll
    for (int nf = 0; nf < 4; ++nf) {
      int cl = wc * 64 + nf * 16 + lr;
      int j0 = wr * 64 + mf * 16 + 4 * lq;
      f32x4 a = acc[mf][nf];
      ushort4 pv;
      pv.x = f2bf(a[0]); pv.y = f2bf(a[1]); pv.z = f2bf(a[2]); pv.w = f2bf(a[3]);
      *(ushort4*)&smem[cl * 136 + j0] = pv;
    }
  }
  __syncthreads();
  if (isz) {
    #pragma unroll
    for (int p = 0; p < 8; ++p) {
      int c = tid + p * 256;
      int r = c >> 4, q = c & 15;
      int cg = n0 + r;
      if (cg < 1200) {
        int head = cg / 300, d = cg - head * 300;
        uint4 val = *(const uint4*)&smem[r * 136 + q * 8];
        *(uint4*)(zTh + ((size_t)(g * 4 + head) * 300 + d) * 128 + q * 8) = val;
      }
    }
  } else {
    int c0 = (nt - 10) * 128;
    #pragma unroll
    for (int p = 0; p < 8; ++p) {
      int c = tid + p * 256;
      int r = c >> 4, q = c & 15;
      uint4 val = *(const uint4*)&smem[r * 136 + q * 8];
      *(uint4*)(hWT + ((size_t)g * 384 + c0 + r) * 128 + q * 8) = val;
    }
  }
}

// ---------------- elr_lite: reduce el/er partials in fixed slot order (deterministic)
__global__ __launch_bounds__(256) void elr_lite(
    const float* __restrict__ part, float* __restrict__ el, float* __restrict__ er) {
  int g = blockIdx.x, tid = threadIdx.x;
  int j = tid & 127, side = tid >> 7;
  for (int s = 0; s < 4; ++s) {
    int s0 = (s == 0) ? 1 : 0;
    int s1e = (s == 3) ? 4 : 5;
    float v = 0.f;
    for (int sl = s0; sl <= s1e; ++sl)
      v += part[(((size_t)(g * 4 + s) * 6 + sl) * 2 + side) * 128 + j];
    float* dst = side ? er : el;
    dst[(size_t)(g * 4 + s) * 128 + j] = v;
  }
}

// ---------------- gat_fuse: fused mx/sinv + 4 GAT heads; P and z single-bf16 (1 MFMA/tile)
__global__ __launch_bounds__(256) void gat_fuse(
    const float* __restrict__ h, const unsigned char* __restrict__ Agat,
    const unsigned short* __restrict__ zTh,
    const float* __restrict__ el, const float* __restrict__ er,
    const float* __restrict__ gat_b, const float* __restrict__ headW,
    const float* __restrict__ head_b, const unsigned short* __restrict__ zerobuf,
    float* __restrict__ out) {
  __shared__ __align__(16) unsigned short Bh[320 * 32];
  __shared__ __align__(16) unsigned short Ah[32 * 32];
  __shared__ __align__(16) unsigned char Ag8[32 * 128];
  __shared__ __align__(16) float elsm[4 * 128];
  __shared__ __align__(16) float ersl[4 * 32];
  __shared__ __align__(16) float mxl[4 * 32];
  __shared__ __align__(16) float svl[4 * 32];
  __shared__ float hwred[2][32];
  __shared__ float wgts[32];
  int xb = blockIdx.x & 7, tb = blockIdx.x >> 3;
  int it = tb & 3, g = xb + 8 * (tb >> 2);
  int i0 = it * 32;
  int tid = threadIdx.x, w = tid >> 6, lane = tid & 63;
  int lq = lane >> 4, lr = lane & 15, wi = w & 1, wn = w >> 1;
  float hb = head_b[0];

  {
    int r = tid >> 3, o = (tid & 7) * 16;
    *(uint4*)&Ag8[r * 128 + o] = *(const uint4*)(Agat + ((size_t)g * 128 + i0 + r) * 128 + o);
    elsm[tid] = el[(size_t)(g * 4) * 128 + tid];
    elsm[256 + tid] = el[(size_t)(g * 4) * 128 + 256 + tid];
    if (tid < 128) {
      int s = tid >> 5, r2 = tid & 31;
      ersl[tid] = er[(size_t)(g * 4 + s) * 128 + i0 + r2];
    }
  }
  __syncthreads();
  for (int s = 0; s < 4; ++s) {
    float el0 = elsm[s * 128 + lane], el1 = elsm[s * 128 + 64 + lane];
    for (int r = w; r < 32; r += 4) {
      int m0 = Ag8[r * 128 + lane], m1 = Ag8[r * 128 + 64 + lane];
      float eri = ersl[s * 32 + r];
      float e0 = eri + el0; e0 = e0 >= 0.f ? e0 : 0.2f * e0;
      float e1 = eri + el1; e1 = e1 >= 0.f ? e1 : 0.2f * e1;
      float x0 = m0 ? e0 : -3.0e38f;
      float x1 = m1 ? e1 : -3.0e38f;
      float m_ = wmax(fmaxf(x0, x1));
      float p0 = m0 ? __expf(e0 - m_) : 0.f;
      float p1 = m1 ? __expf(e1 - m_) : 0.f;
      float ssum = wsum(p0 + p1);
      if (lane == 0) { mxl[s * 32 + r] = m_; svl[s * 32 + r] = 1.f / ssum; }
    }
  }
  __syncthreads();

  float outacc[10][4];
  #pragma unroll
  for (int nf = 0; nf < 10; ++nf)
    #pragma unroll
    for (int t = 0; t < 4; ++t) outacc[nf][t] = 0.f;

  for (int s = 0; s < 4; ++s) {
    f32x4 acc[10];
    #pragma unroll
    for (int nf = 0; nf < 10; ++nf) acc[nf] = (f32x4){0.f, 0.f, 0.f, 0.f};
    const unsigned short* zsh = zTh + (size_t)(g * 4 + s) * 300 * 128;

    for (int kc = 0; kc < 4; ++kc) {
      int j0 = kc * 32;
      {
        int m = tid >> 3, j4 = (tid & 7) * 4;
        float eri = ersl[s * 32 + m], mxi = mxl[s * 32 + m];
        const unsigned char* mrow = &Ag8[m * 128 + j0 + j4];
        uchar4 msk = *(const uchar4*)mrow;
        f4 elv = *(const f4*)&elsm[s * 128 + j0 + j4];
        float p[4];
        {
          float e = eri + elv.x; e = e >= 0.f ? e : 0.2f * e; p[0] = msk.x ? __expf(e - mxi) : 0.f;
          e = eri + elv.y; e = e >= 0.f ? e : 0.2f * e; p[1] = msk.y ? __expf(e - mxi) : 0.f;
          e = eri + elv.z; e = e >= 0.f ? e : 0.2f * e; p[2] = msk.z ? __expf(e - mxi) : 0.f;
          e = eri + elv.w; e = e >= 0.f ? e : 0.2f * e; p[3] = msk.w ? __expf(e - mxi) : 0.f;
        }
        int q = j4 >> 3, wb = j4 & 7;
        int idx = m * 32 + swzq(m, q) * 8 + wb;
        ushort4 hv;
        hv.x = f2bf(p[0]); hv.y = f2bf(p[1]); hv.z = f2bf(p[2]); hv.w = f2bf(p[3]);
        *(ushort4*)&Ah[idx] = hv;
      }
      {
        #pragma unroll
        for (int cc = 0; cc < 5; ++cc) {
          int chunk = w + cc * 4;            // 0..19
          int nb = chunk * 16;
          int n = nb + (lane >> 2);
          int q = (lane & 3) ^ ((n >> 1) & 3);
          const unsigned short* srcH = (n < 300) ? (zsh + (size_t)n * 128 + j0 + q * 8) : zerobuf;
          gld16(srcH, Bh + chunk * 512 + lane * 8);
        }
      }
      __syncthreads();
      int rowa = wi * 16 + lr;
      int ai = rowa * 32 + swzq(rowa, lq) * 8;
      s16x8 ah = *(const s16x8*)&Ah[ai];
      #pragma unroll
      for (int nf = 0; nf < 10; ++nf) {
        int rn = wn * 160 + nf * 16 + lr;
        int bi = rn * 32 + swzq(rn, lq) * 8;
        s16x8 bhv = *(const s16x8*)&Bh[bi];
        acc[nf] = __builtin_amdgcn_mfma_f32_16x16x32_bf16(ah, bhv, acc[nf], 0, 0, 0);
      }
      __syncthreads();
    }
    f4 sv4 = *(const f4*)&svl[s * 32 + wi * 16 + 4 * lq];
    float svf[4] = {sv4.x, sv4.y, sv4.z, sv4.w};
    float pt[4] = {0.f, 0.f, 0.f, 0.f};
    #pragma unroll
    for (int nf = 0; nf < 10; ++nf) {
      int c = wn * 160 + nf * 16 + lr;
      bool val = c < 300;
      float gb = val ? gat_b[s * 300 + c] : 0.f;
      float hwv = val ? headW[c] : 0.f;
      #pragma unroll
      for (int t = 0; t < 4; ++t) {
        float gvv = acc[nf][t] * svf[t] + gb;
        acc[nf][t] = gvv;
        pt[t] += gvv * hwv;
      }
    }
    #pragma unroll
    for (int t = 0; t < 4; ++t) {
      #pragma unroll
      for (int mm = 1; mm < 16; mm <<= 1) pt[t] += __shfl_xor(pt[t], mm, 64);
    }
    if (lr == 0) {
      #pragma unroll
      for (int t = 0; t < 4; ++t) hwred[wn][wi * 16 + 4 * lq + t] = pt[t];
    }
    __syncthreads();
    if (tid < 32) wgts[tid] = sigm(hwred[0][tid] + hwred[1][tid] + hb);
    __syncthreads();
    #pragma unroll
    for (int nf = 0; nf < 10; ++nf) {
      #pragma unroll
      for (int t = 0; t < 4; ++t) {
        int r = wi * 16 + 4 * lq + t;
        outacc[nf][t] += wgts[r] * acc[nf][t];
      }
    }
    __syncthreads();
  }
  #pragma unroll
  for (int nf = 0; nf < 10; ++nf) {
    int c = wn * 160 + nf * 16 + lr;
    if (c < 300) {
      #pragma unroll
      for (int t = 0; t < 4; ++t) {
        int r = wi * 16 + 4 * lq + t;
        size_t o = ((size_t)(g * 128 + i0 + r)) * 300 + c;
        out[o] = h[o] + outacc[nf][t];
      }
    }
  }
}

// ---------------- sage_agg: S = dinv * (A2 @ hW) + b (A2 = Asag with diag 2, symmetric);
// out += sigmoid(S . headW + hb) * S.   MFMA: A2 bf16 exact, hWT bf16-hi B-operand.
__global__ __launch_bounds__(256) void sage_agg(
    const unsigned char* __restrict__ Asag, const unsigned short* __restrict__ hWT,
    const float* __restrict__ sage_b, const float* __restrict__ headW,
    const float* __restrict__ head_b, float* __restrict__ out) {
  __shared__ __align__(16) unsigned char Au8[64 * 128];   // 8 KB
  __shared__ __align__(16) unsigned short Abf[64 * 32];   // 4 KB
  __shared__ __align__(16) unsigned short Bh[320 * 32];   // 20 KB
  __shared__ float dinvL[64];
  int x = blockIdx.x & 7, t = blockIdx.x >> 3;
  int half = t & 1, g = x + 8 * (t >> 1);
  int i0 = half * 64;
  int tid = threadIdx.x, w = tid >> 6, lane = tid & 63;
  int lq = lane >> 4, lr = lane & 15;
  float hb = head_b[0];

  // stage Asag rows i0..i0+63
  for (int c = tid; c < 512; c += 256) {
    int r = c >> 3, q = c & 7;
    *(uint4*)&Au8[r * 128 + q * 16] =
        *(const uint4*)(Asag + ((size_t)g * 128 + i0 + r) * 128 + q * 16);
  }
  __syncthreads();
  // dinv per row (wave w owns rows w*16..+15)
  for (int r = 0; r < 16; ++r) {
    int row = w * 16 + r;
    float s_ = (float)(Au8[row * 128 + lane] + Au8[row * 128 + 64 + lane]);
    s_ = wsum(s_);
    if (lane == 0) dinvL[row] = 1.f / (s_ + 1.f);
  }
  __syncthreads();

  f32x4 acc[20];
  #pragma unroll
  for (int nf = 0; nf < 20; ++nf) acc[nf] = (f32x4){0.f, 0.f, 0.f, 0.f};

  for (int kc = 0; kc < 4; ++kc) {
    int j0 = kc * 32;
    // A2 stage: u8 -> bf16, diagonal = 2
    {
      int m = tid >> 2, q = tid & 3;
      int kk0 = q * 8;
      s16x8 av;
      #pragma unroll
      for (int e = 0; e < 8; ++e) {
        int jg = j0 + kk0 + e;
        float vv = Au8[m * 128 + jg] ? 1.f : 0.f;
        if (i0 + m == jg) vv = 2.f;
        av[e] = (short)f2bf(vv);
      }
      *(s16x8*)&Abf[m * 32 + swzq(m, q) * 8] = av;
    }
    // B stage: gld16 from pre-swizzled hWT (rows 0..319 all valid; >=300 are zeros)
    {
      #pragma unroll
      for (int cc = 0; cc < 5; ++cc) {
        int chunk = w + cc * 4;            // 0..19
        int n = chunk * 16 + (lane >> 2);
        int q = (lane & 3) ^ ((n >> 1) & 3);
        const unsigned short* src = hWT + ((size_t)g * 384 + n) * 128 + j0 + q * 8;
        gld16(src, Bh + chunk * 512 + lane * 8);
      }
    }
    __syncthreads();
    int ma = w * 16 + lr;
    int ai = ma * 32 + swzq(ma, lq) * 8;
    s16x8 ah = *(const s16x8*)&Abf[ai];
    #pragma unroll
    for (int nf = 0; nf < 20; ++nf) {
      int rn = nf * 16 + lr;
      int bi = rn * 32 + swzq(rn, lq) * 8;
      s16x8 bhv = *(const s16x8*)&Bh[bi];
      acc[nf] = __builtin_amdgcn_mfma_f32_16x16x32_bf16(ah, bhv, acc[nf], 0, 0, 0);
    }
    __syncthreads();
  }

  // epilogue: S = acc*dinv + b; wgt = sigm(S.headW + hb); out += wgt*S
  float dv[4];
  #pragma unroll
  for (int t2 = 0; t2 < 4; ++t2) dv[t2] = dinvL[w * 16 + 4 * lq + t2];
  float pt[4] = {0.f, 0.f, 0.f, 0.f};
  #pragma unroll
  for (int nf = 0; nf < 20; ++nf) {
    int c = nf * 16 + lr;
    bool val = c < 300;
    float sb = val ? sage_b[c] : 0.f;
    float hwv = val ? headW[c] : 0.f;
    #pragma unroll
    for (int t2 = 0; t2 < 4; ++t2) {
      float S = acc[nf][t2] * dv[t2] + sb;
      acc[nf][t2] = S;
      pt[t2] += S * hwv;
    }
  }
  #pragma unroll
  for (int t2 = 0; t2 < 4; ++t2) {
    #pragma unroll
    for (int mm = 1; mm < 16; mm <<= 1) pt[t2] += __shfl_xor(pt[t2], mm, 64);
    pt[t2] = sigm(pt[t2] + hb);
  }
  #pragma unroll
  for (int nf = 0; nf < 20; ++nf) {
    int c = nf * 16 + lr;
    if (c < 300) {
      #pragma unroll
      for (int t2 = 0; t2 < 4; ++t2) {
        int i = i0 + w * 16 + 4 * lq + t2;
        size_t o = ((size_t)(g * 128 + i)) * 300 + c;
        out[o] = out[o] + pt[t2] * acc[nf][t2];
      }
    }
  }
}

// ---------------- WeightAndSum pool
__global__ __launch_bounds__(256) void pool_kernel(
    const float* __restrict__ h, const float* __restrict__ poolW,
    const float* __restrict__ pool_b, float* __restrict__ gvec) {
  __shared__ float ws_[128];
  int g = blockIdx.x, tid = threadIdx.x, ii = tid >> 6, lane = tid & 63;
  const float* hg = h + (size_t)g * LLN * DDIM;
  float pb = pool_b[0];
  for (int m = 0; m < 32; ++m) {
    int l = ii * 32 + m;
    float p = 0.f;
    for (int d = lane; d < DDIM; d += 64) p += hg[l * DDIM + d] * poolW[d];
    p = wsum(p);
    if (lane == 0) ws_[l] = 1.f / (1.f + __expf(-(p + pb)));
  }
  __syncthreads();
  for (int d = tid; d < DDIM; d += 256) {
    float acc = 0.f;
    for (int l = 0; l < 128; ++l) acc += hg[l * DDIM + d] * ws_[l];
    gvec[(size_t)g * DDIM + d] = acc;
  }
}

// ---------------- pearson
__global__ __launch_bounds__(64) void pearson_kernel(
    const float* __restrict__ gvec, float* __restrict__ out) {
  int b = blockIdx.x, lane = threadIdx.x;
  const float* g1 = gvec + (size_t)b * DDIM;
  const float* g2 = gvec + (size_t)(64 + b) * DDIM;
  float v1[5], v2[5];
  float s1 = 0.f, s2 = 0.f;
  #pragma unroll
  for (int q = 0; q < 5; ++q) {
    int d = lane + 64 * q;
    v1[q] = (d < DDIM) ? g1[d] : 0.f;
    v2[q] = (d < DDIM) ? g2[d] : 0.f;
    s1 += v1[q]; s2 += v2[q];
  }
  s1 = wsum(s1); s2 = wsum(s2);
  float m1 = s1 / 300.f, m2 = s2 / 300.f;
  float a = 0.f, bb = 0.f, c = 0.f;
  #pragma unroll
  for (int q = 0; q < 5; ++q) {
    int d = lane + 64 * q;
    if (d < DDIM) {
      float x = v1[q] - m1, y = v2[q] - m2;
      a += x * y; bb += x * x; c += y * y;
    }
  }
  a = wsum(a); bb = wsum(bb); c = wsum(c);
  if (lane == 0) out[b] = 5.f * a / (sqrtf(bb) * sqrtf(c));
}

extern "C" void kernel_launch(void* const* d_in, const int* in_sizes, int n_in,
                              void* d_out, int out_size, void* d_ws, size_t ws_size,
                              hipStream_t stream) {
  (void)in_sizes; (void)n_in; (void)out_size; (void)ws_size;
  const float* emb   = (const float*)d_in[0];
  const float* simw1 = (const float*)d_in[1];
  const float* simw2 = (const float*)d_in[2];
  const float* LP[2][8];
  for (int l = 0; l < 2; ++l)
    for (int p = 0; p < 8; ++p) LP[l][p] = (const float*)d_in[3 + l * 8 + p];
  const float* poolW  = (const float*)d_in[19];
  const float* pool_b = (const float*)d_in[20];
  const int* s1 = (const int*)d_in[21];
  const int* s2 = (const int*)d_in[22];
  float* out = (float*)d_out;

  char* ws = (char*)d_ws;
  float* hA  = (float*)(ws + 0);                         // 19,660,800
  float* hB  = (float*)(ws + 19660800);                  // 19,660,800
  unsigned short* zTh = (unsigned short*)(ws + 39321600);   // 39,321,600
  unsigned short* hWT = (unsigned short*)(ws + 78643200);   // 12,582,912
  unsigned char* Agat = (unsigned char*)(ws + 117964800); // 2,097,152
  unsigned char* Asag = (unsigned char*)(ws + 120061952); // 2,097,152
  float* elb  = (float*)(ws + 122159104);                // 262,144
  float* erb  = (float*)(ws + 122421248);                // 262,144
  unsigned short* zb16 = (unsigned short*)(ws + 122683392); // 64 B zero region
  unsigned short* sWTt = (unsigned short*)(ws + 123273216); // 245,760
  float* gv   = (float*)(ws + 123682816);                // 153,600

  hipMemsetAsync(zb16, 0, 64, stream);   // zero pad source for gld16 tail rows
  gather_kernel<<<GG * LLN, 256, 0, stream>>>(emb, s1, s2, hA);

  float* hin = hA; float* hout = hB;
  for (int l = 0; l < 2; ++l) {
    // hi image + gat weight tiles + el/er partials live in the (currently dead) hout region;
    // all consumed (zmm, elr_lite) before gat_fuse writes hout.
    unsigned short* hsplH = (unsigned short*)hout;                        // 10,485,760
    unsigned short* gWTtH = (unsigned short*)((char*)hout + 10485760);    //    819,200
    float*          partb = (float*)((char*)hout + 11304960);             //  3,145,728

    adjmm_kernel<<<256, 256, 0, stream>>>(hin, simw1, simw2, Agat, Asag, hsplH);
    prepw_kernel<<<2080, 256, 0, stream>>>(LP[l][0], LP[l][4], gWTtH, sWTt);
    zmm_mfma<<<1664, 256, 0, stream>>>(hsplH, gWTtH, sWTt, LP[l][1], LP[l][2],
                                       zTh, hWT, partb);
    elr_lite<<<GG, 256, 0, stream>>>(partb, elb, erb);
    gat_fuse<<<512, 256, 0, stream>>>(hin, Agat, zTh, elb, erb,
        LP[l][3], LP[l][6], LP[l][7], zb16, hout);
    sage_agg<<<256, 256, 0, stream>>>(Asag, hWT, LP[l][5], LP[l][6], LP[l][7], hout);
    float* t = hin; hin = hout; hout = t;
  }

  pool_kernel<<<GG, 256, 0, stream>>>(hin, poolW, pool_b, gv);
  pearson_kernel<<<64, 64, 0, stream>>>(gv, out);
}